// Round 1
// baseline (571.062 us; speedup 1.0000x reference)
//
#include <hip/hip_runtime.h>
#include <math.h>

#define N_NODES 50000
#define N_EDGES 800000
#define DIN 128
#define DHID 128   /* H*HID */
#define NH 4
#define HID 32
#define DOUT 40

static __device__ __forceinline__ float lrelu(float x) { return x > 0.f ? x : 0.2f * x; }

// ---------------- CSR build ----------------
__global__ void count_kernel(const int* __restrict__ dstv, int* __restrict__ counts) {
    int i = blockIdx.x * blockDim.x + threadIdx.x;
    if (i < N_EDGES) atomicAdd(&counts[dstv[i]], 1);
}

__global__ __launch_bounds__(1024) void scan_kernel(const int* __restrict__ counts, int* __restrict__ row_ptr) {
    __shared__ int wsums[16];
    __shared__ int woff[17];
    __shared__ int carry_s;
    int t = threadIdx.x;
    int lane = t & 63, wid = t >> 6;
    if (t == 0) carry_s = 0;
    __syncthreads();
    for (int base = 0; base < N_NODES; base += 8192) {
        int c = carry_s;
        int i0 = base + t * 8;
        int vals[8];
        int local = 0;
#pragma unroll
        for (int k = 0; k < 8; k++) {
            int i = i0 + k;
            int v = (i < N_NODES) ? counts[i] : 0;
            vals[k] = local;
            local += v;
        }
        int ws = local;
#pragma unroll
        for (int off = 1; off < 64; off <<= 1) {
            int v = __shfl_up(ws, off);
            if (lane >= off) ws += v;
        }
        if (lane == 63) wsums[wid] = ws;
        __syncthreads();
        if (t < 16) {
            int v = wsums[t];
            int s = v;
#pragma unroll
            for (int off = 1; off < 16; off <<= 1) {
                int u = __shfl_up(s, off);
                if (t >= off) s += u;
            }
            woff[t] = s - v;
            if (t == 15) woff[16] = s;
        }
        __syncthreads();
        int texcl = c + woff[wid] + (ws - local);
#pragma unroll
        for (int k = 0; k < 8; k++) {
            int i = i0 + k;
            if (i < N_NODES) row_ptr[i] = texcl + vals[k];
        }
        __syncthreads();
        if (t == 0) carry_s = c + woff[16];
        __syncthreads();
    }
    if (t == 0) row_ptr[N_NODES] = carry_s;
}

__global__ void copy_cursor_kernel(const int* __restrict__ rp, int* __restrict__ cursor) {
    int i = blockIdx.x * blockDim.x + threadIdx.x;
    if (i < N_NODES) cursor[i] = rp[i];
}

__global__ void scatter_kernel(const int* __restrict__ srcv, const int* __restrict__ dstv,
                               int* __restrict__ cursor, int* __restrict__ csr_src) {
    int i = blockIdx.x * blockDim.x + threadIdx.x;
    if (i < N_EDGES) {
        int v = dstv[i];
        int pos = atomicAdd(&cursor[v], 1);
        csr_src[pos] = srcv[i];
    }
}

// ---------------- transforms (x @ W) + attention logit epilogue ----------------
// one wave per 8 rows; lane L computes cols L and L+64
__global__ __launch_bounds__(256) void transform128_kernel(
    const float* __restrict__ X, const float* __restrict__ W,
    const float* __restrict__ a_src, const float* __restrict__ a_dst,
    float* __restrict__ Hout, float* __restrict__ als, float* __restrict__ ald) {
    int wid = (blockIdx.x * blockDim.x + threadIdx.x) >> 6;
    wid = __builtin_amdgcn_readfirstlane(wid);
    int lane = threadIdx.x & 63;
    int i0 = wid * 8;
    if (i0 >= N_NODES) return;
    float acc0[8], acc1[8];
#pragma unroll
    for (int r = 0; r < 8; r++) { acc0[r] = 0.f; acc1[r] = 0.f; }
    const float* xrow = X + (size_t)i0 * DIN;
    for (int k = 0; k < DIN; k++) {
        float w0 = W[k * DHID + lane];
        float w1 = W[k * DHID + 64 + lane];
#pragma unroll
        for (int r = 0; r < 8; r++) {
            float xk = xrow[r * DIN + k];
            acc0[r] = fmaf(xk, w0, acc0[r]);
            acc1[r] = fmaf(xk, w1, acc1[r]);
        }
    }
    int h0 = lane >> 5;  // head of col `lane` (0/1); col lane+64 -> head 2+h0
    int d0 = lane & 31;
    float as0v = a_src[h0 * HID + d0];
    float as1v = a_src[(2 + h0) * HID + d0];
    float ad0v = a_dst[h0 * HID + d0];
    float ad1v = a_dst[(2 + h0) * HID + d0];
#pragma unroll
    for (int r = 0; r < 8; r++) {
        int i = i0 + r;
        Hout[(size_t)i * DHID + lane] = acc0[r];
        Hout[(size_t)i * DHID + 64 + lane] = acc1[r];
        float ps0 = acc0[r] * as0v;
        float ps1 = acc1[r] * as1v;
        float pd0 = acc0[r] * ad0v;
        float pd1 = acc1[r] * ad1v;
#pragma unroll
        for (int off = 1; off < 32; off <<= 1) {
            ps0 += __shfl_xor(ps0, off);
            ps1 += __shfl_xor(ps1, off);
            pd0 += __shfl_xor(pd0, off);
            pd1 += __shfl_xor(pd1, off);
        }
        if (d0 == 0) {  // lanes 0 and 32
            als[i * NH + h0] = ps0;
            als[i * NH + 2 + h0] = ps1;
            ald[i * NH + h0] = pd0;
            ald[i * NH + 2 + h0] = pd1;
        }
    }
}

__global__ __launch_bounds__(256) void transform40_kernel(
    const float* __restrict__ X, const float* __restrict__ W,
    const float* __restrict__ a_src, const float* __restrict__ a_dst,
    float* __restrict__ Hout, float* __restrict__ als, float* __restrict__ ald) {
    int wid = (blockIdx.x * blockDim.x + threadIdx.x) >> 6;
    wid = __builtin_amdgcn_readfirstlane(wid);
    int lane = threadIdx.x & 63;
    int i0 = wid * 8;
    if (i0 >= N_NODES) return;
    bool act = lane < DOUT;
    float acc[8];
#pragma unroll
    for (int r = 0; r < 8; r++) acc[r] = 0.f;
    const float* xrow = X + (size_t)i0 * DHID;
    for (int k = 0; k < DHID; k++) {
        float w = act ? W[k * DOUT + lane] : 0.f;
#pragma unroll
        for (int r = 0; r < 8; r++) {
            acc[r] = fmaf(xrow[r * DHID + k], w, acc[r]);
        }
    }
    float asv = act ? a_src[lane] : 0.f;
    float adv = act ? a_dst[lane] : 0.f;
#pragma unroll
    for (int r = 0; r < 8; r++) {
        int i = i0 + r;
        if (act) Hout[(size_t)i * DOUT + lane] = acc[r];
        float ps = acc[r] * asv;
        float pd = acc[r] * adv;
#pragma unroll
        for (int off = 1; off < 64; off <<= 1) {
            ps += __shfl_xor(ps, off);
            pd += __shfl_xor(pd, off);
        }
        if (lane == 0) {
            als[i] = ps;
            ald[i] = pd;
        }
    }
}

// ---------------- aggregation: one wave per destination node ----------------
__global__ __launch_bounds__(256) void agg128_kernel(
    const int* __restrict__ row_ptr, const int* __restrict__ csr_src,
    const float* __restrict__ Ht, const float* __restrict__ als, const float* __restrict__ ald,
    const float* __restrict__ bias, float* __restrict__ out) {
    int v = (blockIdx.x * blockDim.x + threadIdx.x) >> 6;
    v = __builtin_amdgcn_readfirstlane(v);
    int lane = threadIdx.x & 63;
    if (v >= N_NODES) return;
    int beg = row_ptr[v], end = row_ptr[v + 1];
    float4 ad4 = *(const float4*)(ald + (size_t)v * 4);
    // phase 1: per-head max of e
    float m0 = -1e30f, m1 = -1e30f, m2 = -1e30f, m3 = -1e30f;
    for (int j = beg + lane; j < end; j += 64) {
        int u = csr_src[j];
        float4 s4 = *(const float4*)(als + (size_t)u * 4);
        m0 = fmaxf(m0, lrelu(s4.x + ad4.x));
        m1 = fmaxf(m1, lrelu(s4.y + ad4.y));
        m2 = fmaxf(m2, lrelu(s4.z + ad4.z));
        m3 = fmaxf(m3, lrelu(s4.w + ad4.w));
    }
#pragma unroll
    for (int off = 1; off < 64; off <<= 1) {
        m0 = fmaxf(m0, __shfl_xor(m0, off));
        m1 = fmaxf(m1, __shfl_xor(m1, off));
        m2 = fmaxf(m2, __shfl_xor(m2, off));
        m3 = fmaxf(m3, __shfl_xor(m3, off));
    }
    // phase 2: denominator
    float t0 = 0.f, t1 = 0.f, t2 = 0.f, t3 = 0.f;
    for (int j = beg + lane; j < end; j += 64) {
        int u = csr_src[j];
        float4 s4 = *(const float4*)(als + (size_t)u * 4);
        t0 += __expf(lrelu(s4.x + ad4.x) - m0);
        t1 += __expf(lrelu(s4.y + ad4.y) - m1);
        t2 += __expf(lrelu(s4.z + ad4.z) - m2);
        t3 += __expf(lrelu(s4.w + ad4.w) - m3);
    }
#pragma unroll
    for (int off = 1; off < 64; off <<= 1) {
        t0 += __shfl_xor(t0, off);
        t1 += __shfl_xor(t1, off);
        t2 += __shfl_xor(t2, off);
        t3 += __shfl_xor(t3, off);
    }
    // phase 3: weighted accumulate; lane owns feats 2L,2L+1 -> head L/16
    int h = lane >> 4;
    float mh = (h & 2) ? ((h & 1) ? m3 : m2) : ((h & 1) ? m1 : m0);
    float sh = (h & 2) ? ((h & 1) ? t3 : t2) : ((h & 1) ? t1 : t0);
    float adh = (h & 2) ? ((h & 1) ? ad4.w : ad4.z) : ((h & 1) ? ad4.y : ad4.x);
    float inv = 1.f / (sh + 1e-16f);
    float ax = 0.f, ay = 0.f;
    for (int j = beg; j < end; ++j) {
        int u = csr_src[j];
        float e = lrelu(als[(size_t)u * 4 + h] + adh);
        float p = __expf(e - mh);
        float2 hv = *(const float2*)(Ht + (size_t)u * DHID + lane * 2);
        ax = fmaf(p, hv.x, ax);
        ay = fmaf(p, hv.y, ay);
    }
    out[(size_t)v * DHID + lane * 2] = ax * inv + bias[lane * 2];
    out[(size_t)v * DHID + lane * 2 + 1] = ay * inv + bias[lane * 2 + 1];
}

__global__ __launch_bounds__(256) void agg40_kernel(
    const int* __restrict__ row_ptr, const int* __restrict__ csr_src,
    const float* __restrict__ Ht, const float* __restrict__ als, const float* __restrict__ ald,
    const float* __restrict__ bias, float* __restrict__ out) {
    int v = (blockIdx.x * blockDim.x + threadIdx.x) >> 6;
    v = __builtin_amdgcn_readfirstlane(v);
    int lane = threadIdx.x & 63;
    if (v >= N_NODES) return;
    int beg = row_ptr[v], end = row_ptr[v + 1];
    float adv = ald[v];
    float m = -1e30f;
    for (int j = beg + lane; j < end; j += 64) {
        m = fmaxf(m, lrelu(als[csr_src[j]] + adv));
    }
#pragma unroll
    for (int off = 1; off < 64; off <<= 1) m = fmaxf(m, __shfl_xor(m, off));
    float s = 0.f;
    for (int j = beg + lane; j < end; j += 64) {
        s += __expf(lrelu(als[csr_src[j]] + adv) - m);
    }
#pragma unroll
    for (int off = 1; off < 64; off <<= 1) s += __shfl_xor(s, off);
    float inv = 1.f / (s + 1e-16f);
    bool act = lane < DOUT;
    float acc = 0.f;
    for (int j = beg; j < end; ++j) {
        int u = csr_src[j];
        float p = __expf(lrelu(als[u] + adv) - m);
        float hv = act ? Ht[(size_t)u * DOUT + lane] : 0.f;
        acc = fmaf(p, hv, acc);
    }
    float z = act ? (acc * inv + bias[lane]) : -1e30f;
    // log_softmax over the 40 cols
    float zm = z;
#pragma unroll
    for (int off = 1; off < 64; off <<= 1) zm = fmaxf(zm, __shfl_xor(zm, off));
    float se = act ? __expf(z - zm) : 0.f;
#pragma unroll
    for (int off = 1; off < 64; off <<= 1) se += __shfl_xor(se, off);
    float res = z - zm - logf(se);
    if (act) out[(size_t)v * DOUT + lane] = res;
}

// ---------------- batch norm ----------------
__global__ __launch_bounds__(256) void bn_stats_kernel(const float* __restrict__ X,
                                                       float* __restrict__ sums, float* __restrict__ sqs) {
    // grid 250 blocks x 200 rows each
    int f = threadIdx.x & 127;
    int sub = threadIdx.x >> 7;
    int rbeg = blockIdx.x * 200;
    float s = 0.f, q = 0.f;
    for (int r = rbeg + sub; r < rbeg + 200; r += 2) {
        float x = X[(size_t)r * DHID + f];
        s += x;
        q += x * x;
    }
    __shared__ float ls[256], lq[256];
    ls[threadIdx.x] = s;
    lq[threadIdx.x] = q;
    __syncthreads();
    if (threadIdx.x < 128) {
        s = ls[threadIdx.x] + ls[threadIdx.x + 128];
        q = lq[threadIdx.x] + lq[threadIdx.x + 128];
        atomicAdd(&sums[f], s);
        atomicAdd(&sqs[f], q);
    }
}

__global__ void bn_finalize_kernel(const float* __restrict__ sums, const float* __restrict__ sqs,
                                   const float* __restrict__ gamma, const float* __restrict__ beta,
                                   float* __restrict__ scale, float* __restrict__ shift) {
    int f = threadIdx.x;
    if (f < DHID) {
        float mu = sums[f] * (1.f / N_NODES);
        float var = sqs[f] * (1.f / N_NODES) - mu * mu;
        float sc = gamma[f] * rsqrtf(var + 1e-5f);
        scale[f] = sc;
        shift[f] = beta[f] - mu * sc;
    }
}

__global__ __launch_bounds__(256) void bn_apply_kernel(float* __restrict__ X, const float* __restrict__ scale,
                                                       const float* __restrict__ shift, float bscale) {
    const int total = N_NODES * DHID / 4;
    for (int idx = blockIdx.x * blockDim.x + threadIdx.x; idx < total; idx += gridDim.x * blockDim.x) {
        float4 x = ((const float4*)X)[idx];
        int c = (idx & 31) * 4;
        float4 sc = *(const float4*)(scale + c);
        float4 sh = *(const float4*)(shift + c);
        float y0 = x.x * sc.x + sh.x;
        float y1 = x.y * sc.y + sh.y;
        float y2 = x.z * sc.z + sh.z;
        float y3 = x.w * sc.w + sh.w;
        y0 = (y0 > 0.f ? y0 : expm1f(y0)) * bscale;
        y1 = (y1 > 0.f ? y1 : expm1f(y1)) * bscale;
        y2 = (y2 > 0.f ? y2 : expm1f(y2)) * bscale;
        y3 = (y3 > 0.f ? y3 : expm1f(y3)) * bscale;
        float4 y = {y0, y1, y2, y3};
        ((float4*)X)[idx] = y;
    }
}

// ---------------- launch ----------------
extern "C" void kernel_launch(void* const* d_in, const int* in_sizes, int n_in,
                              void* d_out, int out_size, void* d_ws, size_t ws_size,
                              hipStream_t stream) {
    (void)in_sizes; (void)n_in; (void)out_size; (void)ws_size;
    const float* x = (const float*)d_in[0];
    const int* ei = (const int*)d_in[1];
    const float* W0 = (const float*)d_in[2];
    const float* as0 = (const float*)d_in[3];
    const float* ad0 = (const float*)d_in[4];
    const float* b0 = (const float*)d_in[5];
    const float* W1 = (const float*)d_in[6];
    const float* as1 = (const float*)d_in[7];
    const float* ad1 = (const float*)d_in[8];
    const float* b1 = (const float*)d_in[9];
    const float* W2 = (const float*)d_in[10];
    const float* as2 = (const float*)d_in[11];
    const float* ad2 = (const float*)d_in[12];
    const float* b2 = (const float*)d_in[13];
    const float* g_bn0 = (const float*)d_in[14];
    const float* be_bn0 = (const float*)d_in[15];
    const float* g_bn1 = (const float*)d_in[16];
    const float* be_bn1 = (const float*)d_in[17];
    float* out = (float*)d_out;

    const int* srcv = ei;
    const int* dstv = ei + N_EDGES;

    // workspace carve (all 256B-aligned)
    char* p = (char*)d_ws;
    auto carve = [&](size_t bytes) {
        char* q = p;
        p += (bytes + 255) & ~(size_t)255;
        return q;
    };
    float* h_tmp = (float*)carve((size_t)N_NODES * DHID * 4);   // 25.6 MB (also reused as [N,40])
    float* agg   = (float*)carve((size_t)N_NODES * DHID * 4);   // 25.6 MB
    float* als   = (float*)carve((size_t)N_NODES * NH * 4);
    float* ald   = (float*)carve((size_t)N_NODES * NH * 4);
    int* counts  = (int*)carve((size_t)N_NODES * 4);
    int* row_ptr = (int*)carve((size_t)(N_NODES + 1) * 4);
    int* cursor  = (int*)carve((size_t)N_NODES * 4);
    int* csr_src = (int*)carve((size_t)N_EDGES * 4);
    float* sums  = (float*)carve(DHID * 4);
    float* sqs   = (float*)carve(DHID * 4);
    float* scale = (float*)carve(DHID * 4);
    float* shift = (float*)carve(DHID * 4);

    const float bs0 = 1.0f + 1.0f / 25.001f;
    const float bs1 = 1.0f + 0.5f / 25.001f;

    const int EB = (N_EDGES + 255) / 256;      // 3125
    const int NB = (N_NODES + 255) / 256;      // 196
    const int TWAVES = (N_NODES / 8 + 3) / 4;  // transform blocks: 6250 waves / 4 = 1563
    const int TB = (N_NODES / 8 * 64 + 255) / 256;
    const int AB = (N_NODES * 64 + 255) / 256; // 12500

    // ---- CSR build (shared by all layers) ----
    hipMemsetAsync(counts, 0, (size_t)N_NODES * 4, stream);
    count_kernel<<<EB, 256, 0, stream>>>(dstv, counts);
    scan_kernel<<<1, 1024, 0, stream>>>(counts, row_ptr);
    copy_cursor_kernel<<<NB, 256, 0, stream>>>(row_ptr, cursor);
    scatter_kernel<<<EB, 256, 0, stream>>>(srcv, dstv, cursor, csr_src);

    // ---- layer 0 ----
    transform128_kernel<<<TB, 256, 0, stream>>>(x, W0, as0, ad0, h_tmp, als, ald);
    agg128_kernel<<<AB, 256, 0, stream>>>(row_ptr, csr_src, h_tmp, als, ald, b0, agg);
    hipMemsetAsync(sums, 0, DHID * 4, stream);
    hipMemsetAsync(sqs, 0, DHID * 4, stream);
    bn_stats_kernel<<<250, 256, 0, stream>>>(agg, sums, sqs);
    bn_finalize_kernel<<<1, 128, 0, stream>>>(sums, sqs, g_bn0, be_bn0, scale, shift);
    bn_apply_kernel<<<2048, 256, 0, stream>>>(agg, scale, shift, bs0);

    // ---- layer 1 ----
    transform128_kernel<<<TB, 256, 0, stream>>>(agg, W1, as1, ad1, h_tmp, als, ald);
    agg128_kernel<<<AB, 256, 0, stream>>>(row_ptr, csr_src, h_tmp, als, ald, b1, agg);
    hipMemsetAsync(sums, 0, DHID * 4, stream);
    hipMemsetAsync(sqs, 0, DHID * 4, stream);
    bn_stats_kernel<<<250, 256, 0, stream>>>(agg, sums, sqs);
    bn_finalize_kernel<<<1, 128, 0, stream>>>(sums, sqs, g_bn1, be_bn1, scale, shift);
    bn_apply_kernel<<<2048, 256, 0, stream>>>(agg, scale, shift, bs1);

    // ---- layer 2 + log_softmax ----
    transform40_kernel<<<TB, 256, 0, stream>>>(agg, W2, as2, ad2, h_tmp, als, ald);
    agg40_kernel<<<AB, 256, 0, stream>>>(row_ptr, csr_src, h_tmp, als, ald, b2, out);

    (void)TWAVES;
}

// Round 2
// 522.558 us; speedup vs baseline: 1.0928x; 1.0928x over previous
//
#include <hip/hip_runtime.h>
#include <math.h>

#define N_NODES 50000
#define N_EDGES 800000
#define DIN 128
#define DHID 128   /* H*HID */
#define NH 4
#define HID 32
#define DOUT 40

static __device__ __forceinline__ float lrelu(float x) { return x > 0.f ? x : 0.2f * x; }

static __device__ __forceinline__ float sel4(int h, float a, float b, float c, float d) {
    float ab = (h & 1) ? b : a;
    float cd = (h & 1) ? d : c;
    return (h & 2) ? cd : ab;
}

// ---------------- CSR build ----------------
__global__ void count_kernel(const int* __restrict__ dstv, int* __restrict__ counts) {
    int i = blockIdx.x * blockDim.x + threadIdx.x;
    if (i < N_EDGES) atomicAdd(&counts[dstv[i]], 1);
}

__global__ __launch_bounds__(1024) void scan_kernel(const int* __restrict__ counts, int* __restrict__ row_ptr) {
    __shared__ int wsums[16];
    __shared__ int woff[17];
    __shared__ int carry_s;
    int t = threadIdx.x;
    int lane = t & 63, wid = t >> 6;
    if (t == 0) carry_s = 0;
    __syncthreads();
    for (int base = 0; base < N_NODES; base += 8192) {
        int c = carry_s;
        int i0 = base + t * 8;
        int vals[8];
        int local = 0;
#pragma unroll
        for (int k = 0; k < 8; k++) {
            int i = i0 + k;
            int v = (i < N_NODES) ? counts[i] : 0;
            vals[k] = local;
            local += v;
        }
        int ws = local;
#pragma unroll
        for (int off = 1; off < 64; off <<= 1) {
            int v = __shfl_up(ws, off);
            if (lane >= off) ws += v;
        }
        if (lane == 63) wsums[wid] = ws;
        __syncthreads();
        if (t < 16) {
            int v = wsums[t];
            int s = v;
#pragma unroll
            for (int off = 1; off < 16; off <<= 1) {
                int u = __shfl_up(s, off);
                if (t >= off) s += u;
            }
            woff[t] = s - v;
            if (t == 15) woff[16] = s;
        }
        __syncthreads();
        int texcl = c + woff[wid] + (ws - local);
#pragma unroll
        for (int k = 0; k < 8; k++) {
            int i = i0 + k;
            if (i < N_NODES) row_ptr[i] = texcl + vals[k];
        }
        __syncthreads();
        if (t == 0) carry_s = c + woff[16];
        __syncthreads();
    }
    if (t == 0) row_ptr[N_NODES] = carry_s;
}

__global__ void copy_cursor_kernel(const int* __restrict__ rp, int* __restrict__ cursor) {
    int i = blockIdx.x * blockDim.x + threadIdx.x;
    if (i < N_NODES) cursor[i] = rp[i];
}

__global__ void scatter_kernel(const int* __restrict__ srcv, const int* __restrict__ dstv,
                               int* __restrict__ cursor, int* __restrict__ csr_src) {
    int i = blockIdx.x * blockDim.x + threadIdx.x;
    if (i < N_EDGES) {
        int v = dstv[i];
        int pos = atomicAdd(&cursor[v], 1);
        csr_src[pos] = srcv[i];
    }
}

// ---------------- transforms (x @ W) + attention logit epilogue ----------------
// one wave per 8 rows; lane L computes cols L and L+64
__global__ __launch_bounds__(256) void transform128_kernel(
    const float* __restrict__ X, const float* __restrict__ W,
    const float* __restrict__ a_src, const float* __restrict__ a_dst,
    float* __restrict__ Hout, float* __restrict__ als, float* __restrict__ ald) {
    int wid = (blockIdx.x * blockDim.x + threadIdx.x) >> 6;
    wid = __builtin_amdgcn_readfirstlane(wid);
    int lane = threadIdx.x & 63;
    int i0 = wid * 8;
    if (i0 >= N_NODES) return;
    float acc0[8], acc1[8];
#pragma unroll
    for (int r = 0; r < 8; r++) { acc0[r] = 0.f; acc1[r] = 0.f; }
    const float* xrow = X + (size_t)i0 * DIN;
    for (int k = 0; k < DIN; k++) {
        float w0 = W[k * DHID + lane];
        float w1 = W[k * DHID + 64 + lane];
#pragma unroll
        for (int r = 0; r < 8; r++) {
            float xk = xrow[r * DIN + k];
            acc0[r] = fmaf(xk, w0, acc0[r]);
            acc1[r] = fmaf(xk, w1, acc1[r]);
        }
    }
    int h0 = lane >> 5;  // head of col `lane` (0/1); col lane+64 -> head 2+h0
    int d0 = lane & 31;
    float as0v = a_src[h0 * HID + d0];
    float as1v = a_src[(2 + h0) * HID + d0];
    float ad0v = a_dst[h0 * HID + d0];
    float ad1v = a_dst[(2 + h0) * HID + d0];
#pragma unroll
    for (int r = 0; r < 8; r++) {
        int i = i0 + r;
        Hout[(size_t)i * DHID + lane] = acc0[r];
        Hout[(size_t)i * DHID + 64 + lane] = acc1[r];
        float ps0 = acc0[r] * as0v;
        float ps1 = acc1[r] * as1v;
        float pd0 = acc0[r] * ad0v;
        float pd1 = acc1[r] * ad1v;
#pragma unroll
        for (int off = 1; off < 32; off <<= 1) {
            ps0 += __shfl_xor(ps0, off);
            ps1 += __shfl_xor(ps1, off);
            pd0 += __shfl_xor(pd0, off);
            pd1 += __shfl_xor(pd1, off);
        }
        if (d0 == 0) {  // lanes 0 and 32
            als[i * NH + h0] = ps0;
            als[i * NH + 2 + h0] = ps1;
            ald[i * NH + h0] = pd0;
            ald[i * NH + 2 + h0] = pd1;
        }
    }
}

__global__ __launch_bounds__(256) void transform40_kernel(
    const float* __restrict__ X, const float* __restrict__ W,
    const float* __restrict__ a_src, const float* __restrict__ a_dst,
    float* __restrict__ Hout, float* __restrict__ als, float* __restrict__ ald) {
    int wid = (blockIdx.x * blockDim.x + threadIdx.x) >> 6;
    wid = __builtin_amdgcn_readfirstlane(wid);
    int lane = threadIdx.x & 63;
    int i0 = wid * 8;
    if (i0 >= N_NODES) return;
    bool act = lane < DOUT;
    float acc[8];
#pragma unroll
    for (int r = 0; r < 8; r++) acc[r] = 0.f;
    const float* xrow = X + (size_t)i0 * DHID;
    for (int k = 0; k < DHID; k++) {
        float w = act ? W[k * DOUT + lane] : 0.f;
#pragma unroll
        for (int r = 0; r < 8; r++) {
            acc[r] = fmaf(xrow[r * DHID + k], w, acc[r]);
        }
    }
    float asv = act ? a_src[lane] : 0.f;
    float adv = act ? a_dst[lane] : 0.f;
#pragma unroll
    for (int r = 0; r < 8; r++) {
        int i = i0 + r;
        if (act) Hout[(size_t)i * DOUT + lane] = acc[r];
        float ps = acc[r] * asv;
        float pd = acc[r] * adv;
#pragma unroll
        for (int off = 1; off < 64; off <<= 1) {
            ps += __shfl_xor(ps, off);
            pd += __shfl_xor(pd, off);
        }
        if (lane == 0) {
            als[i] = ps;
            ald[i] = pd;
        }
    }
}

// ---------------- aggregation: one wave per destination node, single pass ----------------
__global__ __launch_bounds__(256) void agg128_kernel(
    const int* __restrict__ row_ptr, const int* __restrict__ csr_src,
    const float* __restrict__ Ht, const float* __restrict__ als, const float* __restrict__ ald,
    const float* __restrict__ bias, float* __restrict__ out) {
    __shared__ float s_p[4][256];
    __shared__ int s_u[4][64];
    int v = (blockIdx.x * blockDim.x + threadIdx.x) >> 6;
    v = __builtin_amdgcn_readfirstlane(v);
    int lane = threadIdx.x & 63;
    int wslot = threadIdx.x >> 6;
    if (v >= N_NODES) return;
    int beg = row_ptr[v], end = row_ptr[v + 1];
    float4 ad4 = *(const float4*)(ald + (size_t)v * 4);
    int h = lane >> 4;
    float m0 = -1e30f, m1 = -1e30f, m2 = -1e30f, m3 = -1e30f;
    float t0 = 0.f, t1 = 0.f, t2 = 0.f, t3 = 0.f;
    float ax = 0.f, ay = 0.f;
    for (int cbeg = beg; cbeg < end; cbeg += 64) {
        int cnt = min(64, end - cbeg);
        bool act = lane < cnt;
        int u = act ? csr_src[cbeg + lane] : 0;
        float e0, e1, e2, e3;
        if (act) {
            float4 s4 = *(const float4*)(als + (size_t)u * 4);
            e0 = lrelu(s4.x + ad4.x);
            e1 = lrelu(s4.y + ad4.y);
            e2 = lrelu(s4.z + ad4.z);
            e3 = lrelu(s4.w + ad4.w);
        } else {
            e0 = e1 = e2 = e3 = -1e30f;
        }
        float c0 = e0, c1 = e1, c2 = e2, c3 = e3;
#pragma unroll
        for (int off = 1; off < 64; off <<= 1) {
            c0 = fmaxf(c0, __shfl_xor(c0, off));
            c1 = fmaxf(c1, __shfl_xor(c1, off));
            c2 = fmaxf(c2, __shfl_xor(c2, off));
            c3 = fmaxf(c3, __shfl_xor(c3, off));
        }
        float n0 = fmaxf(m0, c0), n1 = fmaxf(m1, c1), n2 = fmaxf(m2, c2), n3 = fmaxf(m3, c3);
        float r0 = __expf(m0 - n0), r1 = __expf(m1 - n1), r2 = __expf(m2 - n2), r3 = __expf(m3 - n3);
        float p0 = act ? __expf(e0 - n0) : 0.f;
        float p1 = act ? __expf(e1 - n1) : 0.f;
        float p2 = act ? __expf(e2 - n2) : 0.f;
        float p3 = act ? __expf(e3 - n3) : 0.f;
        float q0 = p0, q1 = p1, q2 = p2, q3 = p3;
#pragma unroll
        for (int off = 1; off < 64; off <<= 1) {
            q0 += __shfl_xor(q0, off);
            q1 += __shfl_xor(q1, off);
            q2 += __shfl_xor(q2, off);
            q3 += __shfl_xor(q3, off);
        }
        t0 = t0 * r0 + q0;
        t1 = t1 * r1 + q1;
        t2 = t2 * r2 + q2;
        t3 = t3 * r3 + q3;
        float sc = sel4(h, r0, r1, r2, r3);
        ax *= sc;
        ay *= sc;
        m0 = n0; m1 = n1; m2 = n2; m3 = n3;
        s_u[wslot][lane] = u;
        float4 pv = {p0, p1, p2, p3};
        *(float4*)&s_p[wslot][lane * 4] = pv;
        for (int i = 0; i < cnt; ++i) {
            int uu = s_u[wslot][i];
            float p = s_p[wslot][i * 4 + h];
            float2 hv = *(const float2*)(Ht + (size_t)uu * DHID + lane * 2);
            ax = fmaf(p, hv.x, ax);
            ay = fmaf(p, hv.y, ay);
        }
    }
    float th = sel4(h, t0, t1, t2, t3);
    float inv = 1.f / (th + 1e-16f);
    out[(size_t)v * DHID + lane * 2] = ax * inv + bias[lane * 2];
    out[(size_t)v * DHID + lane * 2 + 1] = ay * inv + bias[lane * 2 + 1];
}

__global__ __launch_bounds__(256) void agg40_kernel(
    const int* __restrict__ row_ptr, const int* __restrict__ csr_src,
    const float* __restrict__ Ht, const float* __restrict__ als, const float* __restrict__ ald,
    const float* __restrict__ bias, float* __restrict__ out) {
    __shared__ float s_p[4][64];
    __shared__ int s_u[4][64];
    int v = (blockIdx.x * blockDim.x + threadIdx.x) >> 6;
    v = __builtin_amdgcn_readfirstlane(v);
    int lane = threadIdx.x & 63;
    int wslot = threadIdx.x >> 6;
    if (v >= N_NODES) return;
    int beg = row_ptr[v], end = row_ptr[v + 1];
    float adv = ald[v];
    bool actf = lane < DOUT;
    float m = -1e30f, t = 0.f, acc = 0.f;
    for (int cbeg = beg; cbeg < end; cbeg += 64) {
        int cnt = min(64, end - cbeg);
        bool act = lane < cnt;
        int u = act ? csr_src[cbeg + lane] : 0;
        float e = act ? lrelu(als[u] + adv) : -1e30f;
        float c = e;
#pragma unroll
        for (int off = 1; off < 64; off <<= 1) c = fmaxf(c, __shfl_xor(c, off));
        float n = fmaxf(m, c);
        float r = __expf(m - n);
        float p = act ? __expf(e - n) : 0.f;
        float q = p;
#pragma unroll
        for (int off = 1; off < 64; off <<= 1) q += __shfl_xor(q, off);
        t = t * r + q;
        acc *= r;
        m = n;
        s_u[wslot][lane] = u;
        s_p[wslot][lane] = p;
        for (int i = 0; i < cnt; ++i) {
            int uu = s_u[wslot][i];
            float pp = s_p[wslot][i];
            float hv = actf ? Ht[(size_t)uu * DOUT + lane] : 0.f;
            acc = fmaf(pp, hv, acc);
        }
    }
    float z = actf ? (acc / (t + 1e-16f) + bias[lane]) : -1e30f;
    // log_softmax over the 40 cols
    float zm = z;
#pragma unroll
    for (int off = 1; off < 64; off <<= 1) zm = fmaxf(zm, __shfl_xor(zm, off));
    float se = actf ? __expf(z - zm) : 0.f;
#pragma unroll
    for (int off = 1; off < 64; off <<= 1) se += __shfl_xor(se, off);
    float res = z - zm - logf(se);
    if (actf) out[(size_t)v * DOUT + lane] = res;
}

// ---------------- batch norm ----------------
__global__ __launch_bounds__(256) void bn_stats_kernel(const float* __restrict__ X,
                                                       float* __restrict__ sums, float* __restrict__ sqs) {
    // grid 500 blocks x 100 rows each
    int f = threadIdx.x & 127;
    int sub = threadIdx.x >> 7;
    int rbeg = blockIdx.x * 100;
    float s = 0.f, q = 0.f;
    for (int r = rbeg + sub; r < rbeg + 100; r += 2) {
        float x = X[(size_t)r * DHID + f];
        s += x;
        q += x * x;
    }
    __shared__ float ls[256], lq[256];
    ls[threadIdx.x] = s;
    lq[threadIdx.x] = q;
    __syncthreads();
    if (threadIdx.x < 128) {
        s = ls[threadIdx.x] + ls[threadIdx.x + 128];
        q = lq[threadIdx.x] + lq[threadIdx.x + 128];
        atomicAdd(&sums[f], s);
        atomicAdd(&sqs[f], q);
    }
}

__global__ void bn_finalize_kernel(const float* __restrict__ sums, const float* __restrict__ sqs,
                                   const float* __restrict__ gamma, const float* __restrict__ beta,
                                   float* __restrict__ scale, float* __restrict__ shift) {
    int f = threadIdx.x;
    if (f < DHID) {
        float mu = sums[f] * (1.f / N_NODES);
        float var = sqs[f] * (1.f / N_NODES) - mu * mu;
        float sc = gamma[f] * rsqrtf(var + 1e-5f);
        scale[f] = sc;
        shift[f] = beta[f] - mu * sc;
    }
}

__global__ __launch_bounds__(256) void bn_apply_kernel(float* __restrict__ X, const float* __restrict__ scale,
                                                       const float* __restrict__ shift, float bscale) {
    const int total = N_NODES * DHID / 4;
    for (int idx = blockIdx.x * blockDim.x + threadIdx.x; idx < total; idx += gridDim.x * blockDim.x) {
        float4 x = ((const float4*)X)[idx];
        int c = (idx & 31) * 4;
        float4 sc = *(const float4*)(scale + c);
        float4 sh = *(const float4*)(shift + c);
        float y0 = x.x * sc.x + sh.x;
        float y1 = x.y * sc.y + sh.y;
        float y2 = x.z * sc.z + sh.z;
        float y3 = x.w * sc.w + sh.w;
        y0 = (y0 > 0.f ? y0 : expm1f(y0)) * bscale;
        y1 = (y1 > 0.f ? y1 : expm1f(y1)) * bscale;
        y2 = (y2 > 0.f ? y2 : expm1f(y2)) * bscale;
        y3 = (y3 > 0.f ? y3 : expm1f(y3)) * bscale;
        float4 y = {y0, y1, y2, y3};
        ((float4*)X)[idx] = y;
    }
}

// ---------------- launch ----------------
extern "C" void kernel_launch(void* const* d_in, const int* in_sizes, int n_in,
                              void* d_out, int out_size, void* d_ws, size_t ws_size,
                              hipStream_t stream) {
    (void)in_sizes; (void)n_in; (void)out_size; (void)ws_size;
    const float* x = (const float*)d_in[0];
    const int* ei = (const int*)d_in[1];
    const float* W0 = (const float*)d_in[2];
    const float* as0 = (const float*)d_in[3];
    const float* ad0 = (const float*)d_in[4];
    const float* b0 = (const float*)d_in[5];
    const float* W1 = (const float*)d_in[6];
    const float* as1 = (const float*)d_in[7];
    const float* ad1 = (const float*)d_in[8];
    const float* b1 = (const float*)d_in[9];
    const float* W2 = (const float*)d_in[10];
    const float* as2 = (const float*)d_in[11];
    const float* ad2 = (const float*)d_in[12];
    const float* b2 = (const float*)d_in[13];
    const float* g_bn0 = (const float*)d_in[14];
    const float* be_bn0 = (const float*)d_in[15];
    const float* g_bn1 = (const float*)d_in[16];
    const float* be_bn1 = (const float*)d_in[17];
    float* out = (float*)d_out;

    const int* srcv = ei;
    const int* dstv = ei + N_EDGES;

    // workspace carve (all 256B-aligned)
    char* p = (char*)d_ws;
    auto carve = [&](size_t bytes) {
        char* q = p;
        p += (bytes + 255) & ~(size_t)255;
        return q;
    };
    float* h_tmp = (float*)carve((size_t)N_NODES * DHID * 4);   // 25.6 MB (also reused as [N,40])
    float* agg   = (float*)carve((size_t)N_NODES * DHID * 4);   // 25.6 MB
    float* als   = (float*)carve((size_t)N_NODES * NH * 4);
    float* ald   = (float*)carve((size_t)N_NODES * NH * 4);
    int* counts  = (int*)carve((size_t)N_NODES * 4);
    int* row_ptr = (int*)carve((size_t)(N_NODES + 1) * 4);
    int* cursor  = (int*)carve((size_t)N_NODES * 4);
    int* csr_src = (int*)carve((size_t)N_EDGES * 4);
    float* sums  = (float*)carve(DHID * 4);
    float* sqs   = (float*)carve(DHID * 4);
    float* scale = (float*)carve(DHID * 4);
    float* shift = (float*)carve(DHID * 4);

    const float bs0 = 1.0f + 1.0f / 25.001f;
    const float bs1 = 1.0f + 0.5f / 25.001f;

    const int EB = (N_EDGES + 255) / 256;      // 3125
    const int NB = (N_NODES + 255) / 256;      // 196
    const int TB = (N_NODES / 8 * 64 + 255) / 256;
    const int AB = (N_NODES * 64 + 255) / 256; // 12500

    // ---- CSR build (shared by all layers) ----
    hipMemsetAsync(counts, 0, (size_t)N_NODES * 4, stream);
    count_kernel<<<EB, 256, 0, stream>>>(dstv, counts);
    scan_kernel<<<1, 1024, 0, stream>>>(counts, row_ptr);
    copy_cursor_kernel<<<NB, 256, 0, stream>>>(row_ptr, cursor);
    scatter_kernel<<<EB, 256, 0, stream>>>(srcv, dstv, cursor, csr_src);

    // ---- layer 0 ----
    transform128_kernel<<<TB, 256, 0, stream>>>(x, W0, as0, ad0, h_tmp, als, ald);
    agg128_kernel<<<AB, 256, 0, stream>>>(row_ptr, csr_src, h_tmp, als, ald, b0, agg);
    hipMemsetAsync(sums, 0, DHID * 4, stream);
    hipMemsetAsync(sqs, 0, DHID * 4, stream);
    bn_stats_kernel<<<500, 256, 0, stream>>>(agg, sums, sqs);
    bn_finalize_kernel<<<1, 128, 0, stream>>>(sums, sqs, g_bn0, be_bn0, scale, shift);
    bn_apply_kernel<<<2048, 256, 0, stream>>>(agg, scale, shift, bs0);

    // ---- layer 1 ----
    transform128_kernel<<<TB, 256, 0, stream>>>(agg, W1, as1, ad1, h_tmp, als, ald);
    agg128_kernel<<<AB, 256, 0, stream>>>(row_ptr, csr_src, h_tmp, als, ald, b1, agg);
    hipMemsetAsync(sums, 0, DHID * 4, stream);
    hipMemsetAsync(sqs, 0, DHID * 4, stream);
    bn_stats_kernel<<<500, 256, 0, stream>>>(agg, sums, sqs);
    bn_finalize_kernel<<<1, 128, 0, stream>>>(sums, sqs, g_bn1, be_bn1, scale, shift);
    bn_apply_kernel<<<2048, 256, 0, stream>>>(agg, scale, shift, bs1);

    // ---- layer 2 + log_softmax ----
    transform40_kernel<<<TB, 256, 0, stream>>>(agg, W2, as2, ad2, h_tmp, als, ald);
    agg40_kernel<<<AB, 256, 0, stream>>>(row_ptr, csr_src, h_tmp, als, ald, b2, out);
}

// Round 3
// 495.500 us; speedup vs baseline: 1.1525x; 1.0546x over previous
//
#include <hip/hip_runtime.h>
#include <math.h>

#define N_NODES 50000
#define N_EDGES 800000
#define DIN 128
#define DHID 128   /* H*HID */
#define NH 4
#define HID 32
#define DOUT 40

static __device__ __forceinline__ float lrelu(float x) { return x > 0.f ? x : 0.2f * x; }

static __device__ __forceinline__ float sel4(int h, float a, float b, float c, float d) {
    float ab = (h & 1) ? b : a;
    float cd = (h & 1) ? d : c;
    return (h & 2) ? cd : ab;
}

static __device__ __forceinline__ unsigned short f2bf(float f) {
    unsigned int u = __float_as_uint(f);
    u = (u + 0x7FFFu + ((u >> 16) & 1u)) >> 16;
    return (unsigned short)u;
}
static __device__ __forceinline__ float bf2f(unsigned short u) {
    return __uint_as_float(((unsigned int)u) << 16);
}

// ---------------- CSR build ----------------
__global__ void count_kernel(const int* __restrict__ dstv, int* __restrict__ counts) {
    int i = blockIdx.x * blockDim.x + threadIdx.x;
    if (i < N_EDGES) atomicAdd(&counts[dstv[i]], 1);
}

__global__ __launch_bounds__(1024) void scan_kernel(const int* __restrict__ counts, int* __restrict__ row_ptr) {
    __shared__ int wsums[16];
    __shared__ int woff[17];
    __shared__ int carry_s;
    int t = threadIdx.x;
    int lane = t & 63, wid = t >> 6;
    if (t == 0) carry_s = 0;
    __syncthreads();
    for (int base = 0; base < N_NODES; base += 8192) {
        int c = carry_s;
        int i0 = base + t * 8;
        int vals[8];
        int local = 0;
#pragma unroll
        for (int k = 0; k < 8; k++) {
            int i = i0 + k;
            int v = (i < N_NODES) ? counts[i] : 0;
            vals[k] = local;
            local += v;
        }
        int ws = local;
#pragma unroll
        for (int off = 1; off < 64; off <<= 1) {
            int v = __shfl_up(ws, off);
            if (lane >= off) ws += v;
        }
        if (lane == 63) wsums[wid] = ws;
        __syncthreads();
        if (t < 16) {
            int v = wsums[t];
            int s = v;
#pragma unroll
            for (int off = 1; off < 16; off <<= 1) {
                int u = __shfl_up(s, off);
                if (t >= off) s += u;
            }
            woff[t] = s - v;
            if (t == 15) woff[16] = s;
        }
        __syncthreads();
        int texcl = c + woff[wid] + (ws - local);
#pragma unroll
        for (int k = 0; k < 8; k++) {
            int i = i0 + k;
            if (i < N_NODES) row_ptr[i] = texcl + vals[k];
        }
        __syncthreads();
        if (t == 0) carry_s = c + woff[16];
        __syncthreads();
    }
    if (t == 0) row_ptr[N_NODES] = carry_s;
}

__global__ void copy_cursor_kernel(const int* __restrict__ rp, int* __restrict__ cursor) {
    int i = blockIdx.x * blockDim.x + threadIdx.x;
    if (i < N_NODES) cursor[i] = rp[i];
}

__global__ void scatter_kernel(const int* __restrict__ srcv, const int* __restrict__ dstv,
                               int* __restrict__ cursor, int* __restrict__ csr_src) {
    int i = blockIdx.x * blockDim.x + threadIdx.x;
    if (i < N_EDGES) {
        int v = dstv[i];
        int pos = atomicAdd(&cursor[v], 1);
        csr_src[pos] = srcv[i];
    }
}

// ---------------- gemm128: [N,128]@[128,128] + als/ald epilogue, bf16 h out ----------------
// block 256 thr, tile 128 rows x 128 cols, thread 8x8 (rows ty*8.., cols 2tx+32h+{0,1})
__global__ __launch_bounds__(256) void gemm128_kernel(
    const float* __restrict__ X, const float* __restrict__ W,
    const float* __restrict__ a_src, const float* __restrict__ a_dst,
    unsigned int* __restrict__ Hout, float* __restrict__ als, float* __restrict__ ald) {
    __shared__ float Xs[32][132];   // [k][row], pad 132 -> conflict-free b128 reads
    __shared__ float Ws[32][128];   // [k][col]
    const int t = threadIdx.x;
    const int tx = t & 15, ty = t >> 4;
    const int r0 = blockIdx.x * 128;
    const int sr = t >> 3, sa = t & 7;        // X staging: row, k-quad
    const int wk = t >> 5, wc = (t & 31) * 4; // W staging

    float4 xpre[4], wpre[4];
#pragma unroll
    for (int it = 0; it < 4; ++it) {
        int gr = r0 + sr + 32 * it; gr = gr < N_NODES ? gr : N_NODES - 1;
        xpre[it] = *(const float4*)(X + (size_t)gr * 128 + 4 * sa);
        wpre[it] = *(const float4*)(W + (size_t)(wk + 8 * it) * 128 + wc);
    }
    float acc[8][8];
#pragma unroll
    for (int i = 0; i < 8; ++i)
#pragma unroll
        for (int c = 0; c < 8; ++c) acc[i][c] = 0.f;

    for (int step = 0; step < 4; ++step) {
        __syncthreads();
#pragma unroll
        for (int it = 0; it < 4; ++it) {
            int r = sr + 32 * it;
            Xs[4 * sa + 0][r] = xpre[it].x;
            Xs[4 * sa + 1][r] = xpre[it].y;
            Xs[4 * sa + 2][r] = xpre[it].z;
            Xs[4 * sa + 3][r] = xpre[it].w;
            *(float4*)&Ws[wk + 8 * it][wc] = wpre[it];
        }
        if (step < 3) {
            int k0 = (step + 1) * 32;
#pragma unroll
            for (int it = 0; it < 4; ++it) {
                int gr = r0 + sr + 32 * it; gr = gr < N_NODES ? gr : N_NODES - 1;
                xpre[it] = *(const float4*)(X + (size_t)gr * 128 + k0 + 4 * sa);
                wpre[it] = *(const float4*)(W + (size_t)(k0 + wk + 8 * it) * 128 + wc);
            }
        }
        __syncthreads();
#pragma unroll
        for (int kk = 0; kk < 32; ++kk) {
            float4 xa = *(const float4*)&Xs[kk][ty * 8];
            float4 xb = *(const float4*)&Xs[kk][ty * 8 + 4];
            float2 w0 = *(const float2*)&Ws[kk][2 * tx];
            float2 w1 = *(const float2*)&Ws[kk][2 * tx + 32];
            float2 w2 = *(const float2*)&Ws[kk][2 * tx + 64];
            float2 w3 = *(const float2*)&Ws[kk][2 * tx + 96];
            float xr[8] = {xa.x, xa.y, xa.z, xa.w, xb.x, xb.y, xb.z, xb.w};
            float wr[8] = {w0.x, w0.y, w1.x, w1.y, w2.x, w2.y, w3.x, w3.y};
#pragma unroll
            for (int i = 0; i < 8; ++i)
#pragma unroll
                for (int c = 0; c < 8; ++c)
                    acc[i][c] = fmaf(xr[i], wr[c], acc[i][c]);
        }
    }
    // epilogue: bf16 h store + per-head als/ald
    float asv[8], adv[8];
#pragma unroll
    for (int c = 0; c < 8; ++c) {
        int col = 2 * tx + 32 * (c >> 1) + (c & 1);
        asv[c] = a_src[col];
        adv[c] = a_dst[col];
    }
#pragma unroll
    for (int i = 0; i < 8; ++i) {
        int r = r0 + ty * 8 + i;
        bool valid = r < N_NODES;
        if (valid) {
#pragma unroll
            for (int h = 0; h < 4; ++h) {
                unsigned int pk = (unsigned int)f2bf(acc[i][2 * h]) |
                                  ((unsigned int)f2bf(acc[i][2 * h + 1]) << 16);
                Hout[(size_t)r * 64 + tx + 16 * h] = pk;
            }
        }
        float sa4[4], sd4[4];
#pragma unroll
        for (int h = 0; h < 4; ++h) {
            sa4[h] = acc[i][2 * h] * asv[2 * h] + acc[i][2 * h + 1] * asv[2 * h + 1];
            sd4[h] = acc[i][2 * h] * adv[2 * h] + acc[i][2 * h + 1] * adv[2 * h + 1];
#pragma unroll
            for (int off = 1; off < 16; off <<= 1) {
                sa4[h] += __shfl_xor(sa4[h], off);
                sd4[h] += __shfl_xor(sd4[h], off);
            }
        }
        if (valid && tx == 0) {
#pragma unroll
            for (int h = 0; h < 4; ++h) {
                als[r * 4 + h] = sa4[h];
                ald[r * 4 + h] = sd4[h];
            }
        }
    }
}

// ---------------- gemm40: [N,128]@[128,40] + als/ald epilogue, bf16 h out ----------------
// block 256 thr, tile 256 rows x 40 cols, thread 8x5 (rows ty*8.., cols tx+8j)
__global__ __launch_bounds__(256) void gemm40_kernel(
    const float* __restrict__ X, const float* __restrict__ W,
    const float* __restrict__ a_src, const float* __restrict__ a_dst,
    unsigned short* __restrict__ Hout, float* __restrict__ als, float* __restrict__ ald) {
    __shared__ float Xs[256][33];   // [row][k], pad 33
    __shared__ float Wsf[1280];     // [k][col] flat, 32x40
    const int t = threadIdx.x;
    const int tx = t & 7, ty = t >> 3;
    const int r0 = blockIdx.x * 256;
    const int sr = t >> 3, sa = t & 7;

    float4 xpre[8];
    float wpre[5];
#pragma unroll
    for (int it = 0; it < 8; ++it) {
        int gr = r0 + sr + 32 * it; gr = gr < N_NODES ? gr : N_NODES - 1;
        xpre[it] = *(const float4*)(X + (size_t)gr * 128 + 4 * sa);
    }
#pragma unroll
    for (int i = 0; i < 5; ++i) wpre[i] = W[t + 256 * i];

    float acc[8][5];
#pragma unroll
    for (int i = 0; i < 8; ++i)
#pragma unroll
        for (int j = 0; j < 5; ++j) acc[i][j] = 0.f;

    for (int step = 0; step < 4; ++step) {
        __syncthreads();
#pragma unroll
        for (int it = 0; it < 8; ++it) {
            int r = sr + 32 * it;
            Xs[r][4 * sa + 0] = xpre[it].x;
            Xs[r][4 * sa + 1] = xpre[it].y;
            Xs[r][4 * sa + 2] = xpre[it].z;
            Xs[r][4 * sa + 3] = xpre[it].w;
        }
#pragma unroll
        for (int i = 0; i < 5; ++i) Wsf[t + 256 * i] = wpre[i];
        if (step < 3) {
            int k0 = (step + 1) * 32;
#pragma unroll
            for (int it = 0; it < 8; ++it) {
                int gr = r0 + sr + 32 * it; gr = gr < N_NODES ? gr : N_NODES - 1;
                xpre[it] = *(const float4*)(X + (size_t)gr * 128 + k0 + 4 * sa);
            }
#pragma unroll
            for (int i = 0; i < 5; ++i) wpre[i] = W[k0 * 40 + t + 256 * i];
        }
        __syncthreads();
#pragma unroll
        for (int kk = 0; kk < 32; ++kk) {
            float xr[8];
#pragma unroll
            for (int i = 0; i < 8; ++i) xr[i] = Xs[ty * 8 + i][kk];
            float wr[5];
#pragma unroll
            for (int j = 0; j < 5; ++j) wr[j] = Wsf[kk * 40 + tx + 8 * j];
#pragma unroll
            for (int i = 0; i < 8; ++i)
#pragma unroll
                for (int j = 0; j < 5; ++j)
                    acc[i][j] = fmaf(xr[i], wr[j], acc[i][j]);
        }
    }
    float asv[5], adv[5];
#pragma unroll
    for (int j = 0; j < 5; ++j) {
        asv[j] = a_src[tx + 8 * j];
        adv[j] = a_dst[tx + 8 * j];
    }
#pragma unroll
    for (int i = 0; i < 8; ++i) {
        int r = r0 + ty * 8 + i;
        bool valid = r < N_NODES;
        if (valid) {
#pragma unroll
            for (int j = 0; j < 5; ++j)
                Hout[(size_t)r * 40 + tx + 8 * j] = f2bf(acc[i][j]);
        }
        float ps = 0.f, pd = 0.f;
#pragma unroll
        for (int j = 0; j < 5; ++j) {
            ps = fmaf(acc[i][j], asv[j], ps);
            pd = fmaf(acc[i][j], adv[j], pd);
        }
#pragma unroll
        for (int off = 1; off < 8; off <<= 1) {
            ps += __shfl_xor(ps, off);
            pd += __shfl_xor(pd, off);
        }
        if (valid && tx == 0) {
            als[r] = ps;
            ald[r] = pd;
        }
    }
}

// ---------------- aggregation: one wave per destination node, single pass ----------------
__global__ __launch_bounds__(256) void agg128_kernel(
    const int* __restrict__ row_ptr, const int* __restrict__ csr_src,
    const unsigned int* __restrict__ Ht, const float* __restrict__ als, const float* __restrict__ ald,
    const float* __restrict__ bias, float* __restrict__ out) {
    __shared__ float s_p[4][256];
    __shared__ int s_u[4][64];
    int v = (blockIdx.x * blockDim.x + threadIdx.x) >> 6;
    v = __builtin_amdgcn_readfirstlane(v);
    int lane = threadIdx.x & 63;
    int wslot = threadIdx.x >> 6;
    if (v >= N_NODES) return;
    int beg = row_ptr[v], end = row_ptr[v + 1];
    float4 ad4 = *(const float4*)(ald + (size_t)v * 4);
    int h = lane >> 4;
    float m0 = -1e30f, m1 = -1e30f, m2 = -1e30f, m3 = -1e30f;
    float t0 = 0.f, t1 = 0.f, t2 = 0.f, t3 = 0.f;
    float ax = 0.f, ay = 0.f;
    for (int cbeg = beg; cbeg < end; cbeg += 64) {
        int cnt = min(64, end - cbeg);
        bool act = lane < cnt;
        int u = act ? csr_src[cbeg + lane] : 0;
        float e0, e1, e2, e3;
        if (act) {
            float4 s4 = *(const float4*)(als + (size_t)u * 4);
            e0 = lrelu(s4.x + ad4.x);
            e1 = lrelu(s4.y + ad4.y);
            e2 = lrelu(s4.z + ad4.z);
            e3 = lrelu(s4.w + ad4.w);
        } else {
            e0 = e1 = e2 = e3 = -1e30f;
        }
        float c0 = e0, c1 = e1, c2 = e2, c3 = e3;
#pragma unroll
        for (int off = 1; off < 64; off <<= 1) {
            c0 = fmaxf(c0, __shfl_xor(c0, off));
            c1 = fmaxf(c1, __shfl_xor(c1, off));
            c2 = fmaxf(c2, __shfl_xor(c2, off));
            c3 = fmaxf(c3, __shfl_xor(c3, off));
        }
        float n0 = fmaxf(m0, c0), n1 = fmaxf(m1, c1), n2 = fmaxf(m2, c2), n3 = fmaxf(m3, c3);
        float r0 = __expf(m0 - n0), r1 = __expf(m1 - n1), r2 = __expf(m2 - n2), r3 = __expf(m3 - n3);
        float p0 = act ? __expf(e0 - n0) : 0.f;
        float p1 = act ? __expf(e1 - n1) : 0.f;
        float p2 = act ? __expf(e2 - n2) : 0.f;
        float p3 = act ? __expf(e3 - n3) : 0.f;
        float q0 = p0, q1 = p1, q2 = p2, q3 = p3;
#pragma unroll
        for (int off = 1; off < 64; off <<= 1) {
            q0 += __shfl_xor(q0, off);
            q1 += __shfl_xor(q1, off);
            q2 += __shfl_xor(q2, off);
            q3 += __shfl_xor(q3, off);
        }
        t0 = t0 * r0 + q0;
        t1 = t1 * r1 + q1;
        t2 = t2 * r2 + q2;
        t3 = t3 * r3 + q3;
        float sc = sel4(h, r0, r1, r2, r3);
        ax *= sc;
        ay *= sc;
        m0 = n0; m1 = n1; m2 = n2; m3 = n3;
        s_u[wslot][lane] = u;
        float4 pv = {p0, p1, p2, p3};
        *(float4*)&s_p[wslot][lane * 4] = pv;
        for (int i = 0; i < cnt; ++i) {
            int uu = s_u[wslot][i];
            float p = s_p[wslot][i * 4 + h];
            unsigned int w = Ht[(size_t)uu * 64 + lane];
            float hx = __uint_as_float(w << 16);
            float hy = __uint_as_float(w & 0xFFFF0000u);
            ax = fmaf(p, hx, ax);
            ay = fmaf(p, hy, ay);
        }
    }
    float th = sel4(h, t0, t1, t2, t3);
    float inv = 1.f / (th + 1e-16f);
    out[(size_t)v * DHID + lane * 2] = ax * inv + bias[lane * 2];
    out[(size_t)v * DHID + lane * 2 + 1] = ay * inv + bias[lane * 2 + 1];
}

__global__ __launch_bounds__(256) void agg40_kernel(
    const int* __restrict__ row_ptr, const int* __restrict__ csr_src,
    const unsigned short* __restrict__ Ht, const float* __restrict__ als, const float* __restrict__ ald,
    const float* __restrict__ bias, float* __restrict__ out) {
    __shared__ float s_p[4][64];
    __shared__ int s_u[4][64];
    int v = (blockIdx.x * blockDim.x + threadIdx.x) >> 6;
    v = __builtin_amdgcn_readfirstlane(v);
    int lane = threadIdx.x & 63;
    int wslot = threadIdx.x >> 6;
    if (v >= N_NODES) return;
    int beg = row_ptr[v], end = row_ptr[v + 1];
    float adv = ald[v];
    bool actf = lane < DOUT;
    float m = -1e30f, t = 0.f, acc = 0.f;
    for (int cbeg = beg; cbeg < end; cbeg += 64) {
        int cnt = min(64, end - cbeg);
        bool act = lane < cnt;
        int u = act ? csr_src[cbeg + lane] : 0;
        float e = act ? lrelu(als[u] + adv) : -1e30f;
        float c = e;
#pragma unroll
        for (int off = 1; off < 64; off <<= 1) c = fmaxf(c, __shfl_xor(c, off));
        float n = fmaxf(m, c);
        float r = __expf(m - n);
        float p = act ? __expf(e - n) : 0.f;
        float q = p;
#pragma unroll
        for (int off = 1; off < 64; off <<= 1) q += __shfl_xor(q, off);
        t = t * r + q;
        acc *= r;
        m = n;
        s_u[wslot][lane] = u;
        s_p[wslot][lane] = p;
        for (int i = 0; i < cnt; ++i) {
            int uu = s_u[wslot][i];
            float pp = s_p[wslot][i];
            float hv = actf ? bf2f(Ht[(size_t)uu * 40 + lane]) : 0.f;
            acc = fmaf(pp, hv, acc);
        }
    }
    float z = actf ? (acc / (t + 1e-16f) + bias[lane]) : -1e30f;
    // log_softmax over the 40 cols
    float zm = z;
#pragma unroll
    for (int off = 1; off < 64; off <<= 1) zm = fmaxf(zm, __shfl_xor(zm, off));
    float se = actf ? __expf(z - zm) : 0.f;
#pragma unroll
    for (int off = 1; off < 64; off <<= 1) se += __shfl_xor(se, off);
    float res = z - zm - logf(se);
    if (actf) out[(size_t)v * DOUT + lane] = res;
}

// ---------------- batch norm ----------------
__global__ __launch_bounds__(256) void bn_stats_kernel(const float* __restrict__ X,
                                                       float* __restrict__ sums, float* __restrict__ sqs) {
    int f = threadIdx.x & 127;
    int sub = threadIdx.x >> 7;
    int rbeg = blockIdx.x * 100;
    float s = 0.f, q = 0.f;
    for (int r = rbeg + sub; r < rbeg + 100; r += 2) {
        float x = X[(size_t)r * DHID + f];
        s += x;
        q += x * x;
    }
    __shared__ float ls[256], lq[256];
    ls[threadIdx.x] = s;
    lq[threadIdx.x] = q;
    __syncthreads();
    if (threadIdx.x < 128) {
        s = ls[threadIdx.x] + ls[threadIdx.x + 128];
        q = lq[threadIdx.x] + lq[threadIdx.x + 128];
        atomicAdd(&sums[f], s);
        atomicAdd(&sqs[f], q);
    }
}

__global__ void bn_finalize_kernel(const float* __restrict__ sums, const float* __restrict__ sqs,
                                   const float* __restrict__ gamma, const float* __restrict__ beta,
                                   float* __restrict__ scale, float* __restrict__ shift) {
    int f = threadIdx.x;
    if (f < DHID) {
        float mu = sums[f] * (1.f / N_NODES);
        float var = sqs[f] * (1.f / N_NODES) - mu * mu;
        float sc = gamma[f] * rsqrtf(var + 1e-5f);
        scale[f] = sc;
        shift[f] = beta[f] - mu * sc;
    }
}

__global__ __launch_bounds__(256) void bn_apply_kernel(float* __restrict__ X, const float* __restrict__ scale,
                                                       const float* __restrict__ shift, float bscale) {
    const int total = N_NODES * DHID / 4;
    for (int idx = blockIdx.x * blockDim.x + threadIdx.x; idx < total; idx += gridDim.x * blockDim.x) {
        float4 x = ((const float4*)X)[idx];
        int c = (idx & 31) * 4;
        float4 sc = *(const float4*)(scale + c);
        float4 sh = *(const float4*)(shift + c);
        float y0 = x.x * sc.x + sh.x;
        float y1 = x.y * sc.y + sh.y;
        float y2 = x.z * sc.z + sh.z;
        float y3 = x.w * sc.w + sh.w;
        y0 = (y0 > 0.f ? y0 : expm1f(y0)) * bscale;
        y1 = (y1 > 0.f ? y1 : expm1f(y1)) * bscale;
        y2 = (y2 > 0.f ? y2 : expm1f(y2)) * bscale;
        y3 = (y3 > 0.f ? y3 : expm1f(y3)) * bscale;
        float4 y = {y0, y1, y2, y3};
        ((float4*)X)[idx] = y;
    }
}

// ---------------- launch ----------------
extern "C" void kernel_launch(void* const* d_in, const int* in_sizes, int n_in,
                              void* d_out, int out_size, void* d_ws, size_t ws_size,
                              hipStream_t stream) {
    (void)in_sizes; (void)n_in; (void)out_size; (void)ws_size;
    const float* x = (const float*)d_in[0];
    const int* ei = (const int*)d_in[1];
    const float* W0 = (const float*)d_in[2];
    const float* as0 = (const float*)d_in[3];
    const float* ad0 = (const float*)d_in[4];
    const float* b0 = (const float*)d_in[5];
    const float* W1 = (const float*)d_in[6];
    const float* as1 = (const float*)d_in[7];
    const float* ad1 = (const float*)d_in[8];
    const float* b1 = (const float*)d_in[9];
    const float* W2 = (const float*)d_in[10];
    const float* as2 = (const float*)d_in[11];
    const float* ad2 = (const float*)d_in[12];
    const float* b2 = (const float*)d_in[13];
    const float* g_bn0 = (const float*)d_in[14];
    const float* be_bn0 = (const float*)d_in[15];
    const float* g_bn1 = (const float*)d_in[16];
    const float* be_bn1 = (const float*)d_in[17];
    float* out = (float*)d_out;

    const int* srcv = ei;
    const int* dstv = ei + N_EDGES;

    char* p = (char*)d_ws;
    auto carve = [&](size_t bytes) {
        char* q = p;
        p += (bytes + 255) & ~(size_t)255;
        return q;
    };
    unsigned int* h_bf = (unsigned int*)carve((size_t)N_NODES * 64 * 4);  // bf16 h, 12.8 MB (also as [N,40] ushort)
    float* agg   = (float*)carve((size_t)N_NODES * DHID * 4);             // 25.6 MB
    float* als   = (float*)carve((size_t)N_NODES * NH * 4);
    float* ald   = (float*)carve((size_t)N_NODES * NH * 4);
    int* counts  = (int*)carve((size_t)N_NODES * 4);
    int* row_ptr = (int*)carve((size_t)(N_NODES + 1) * 4);
    int* cursor  = (int*)carve((size_t)N_NODES * 4);
    int* csr_src = (int*)carve((size_t)N_EDGES * 4);
    float* sums  = (float*)carve(DHID * 4);
    float* sqs   = (float*)carve(DHID * 4);
    float* scale = (float*)carve(DHID * 4);
    float* shift = (float*)carve(DHID * 4);

    const float bs0 = 1.0f + 1.0f / 25.001f;
    const float bs1 = 1.0f + 0.5f / 25.001f;

    const int EB = (N_EDGES + 255) / 256;
    const int NB = (N_NODES + 255) / 256;
    const int G128B = (N_NODES + 127) / 128;   // 391
    const int G40B = (N_NODES + 255) / 256;    // 196
    const int AB = (N_NODES * 64 + 255) / 256; // 12500

    // ---- CSR build (shared by all layers) ----
    hipMemsetAsync(counts, 0, (size_t)N_NODES * 4, stream);
    count_kernel<<<EB, 256, 0, stream>>>(dstv, counts);
    scan_kernel<<<1, 1024, 0, stream>>>(counts, row_ptr);
    copy_cursor_kernel<<<NB, 256, 0, stream>>>(row_ptr, cursor);
    scatter_kernel<<<EB, 256, 0, stream>>>(srcv, dstv, cursor, csr_src);

    // ---- layer 0 ----
    gemm128_kernel<<<G128B, 256, 0, stream>>>(x, W0, as0, ad0, h_bf, als, ald);
    agg128_kernel<<<AB, 256, 0, stream>>>(row_ptr, csr_src, h_bf, als, ald, b0, agg);
    hipMemsetAsync(sums, 0, DHID * 4, stream);
    hipMemsetAsync(sqs, 0, DHID * 4, stream);
    bn_stats_kernel<<<500, 256, 0, stream>>>(agg, sums, sqs);
    bn_finalize_kernel<<<1, 128, 0, stream>>>(sums, sqs, g_bn0, be_bn0, scale, shift);
    bn_apply_kernel<<<2048, 256, 0, stream>>>(agg, scale, shift, bs0);

    // ---- layer 1 ----
    gemm128_kernel<<<G128B, 256, 0, stream>>>(agg, W1, as1, ad1, h_bf, als, ald);
    agg128_kernel<<<AB, 256, 0, stream>>>(row_ptr, csr_src, h_bf, als, ald, b1, agg);
    hipMemsetAsync(sums, 0, DHID * 4, stream);
    hipMemsetAsync(sqs, 0, DHID * 4, stream);
    bn_stats_kernel<<<500, 256, 0, stream>>>(agg, sums, sqs);
    bn_finalize_kernel<<<1, 128, 0, stream>>>(sums, sqs, g_bn1, be_bn1, scale, shift);
    bn_apply_kernel<<<2048, 256, 0, stream>>>(agg, scale, shift, bs1);

    // ---- layer 2 + log_softmax ----
    gemm40_kernel<<<G40B, 256, 0, stream>>>(agg, W2, as2, ad2, (unsigned short*)h_bf, als, ald);
    agg40_kernel<<<AB, 256, 0, stream>>>(row_ptr, csr_src, (const unsigned short*)h_bf, als, ald, b2, out);
}

// Round 4
// 444.332 us; speedup vs baseline: 1.2852x; 1.1152x over previous
//
#include <hip/hip_runtime.h>
#include <math.h>

#define N_NODES 50000
#define N_EDGES 800000
#define DIN 128
#define DHID 128   /* H*HID */
#define NH 4
#define HID 32
#define DOUT 40

static __device__ __forceinline__ float lrelu(float x) { return x > 0.f ? x : 0.2f * x; }

static __device__ __forceinline__ float sel4(int h, float a, float b, float c, float d) {
    float ab = (h & 1) ? b : a;
    float cd = (h & 1) ? d : c;
    return (h & 2) ? cd : ab;
}

static __device__ __forceinline__ unsigned short f2bf(float f) {
    unsigned int u = __float_as_uint(f);
    u = (u + 0x7FFFu + ((u >> 16) & 1u)) >> 16;
    return (unsigned short)u;
}
static __device__ __forceinline__ float bf2f(unsigned short u) {
    return __uint_as_float(((unsigned int)u) << 16);
}

// ---------------- CSR build ----------------
__global__ void count_kernel(const int* __restrict__ dstv, int* __restrict__ counts) {
    int i = blockIdx.x * blockDim.x + threadIdx.x;
    if (i < N_EDGES) atomicAdd(&counts[dstv[i]], 1);
}

__global__ __launch_bounds__(1024) void scan_kernel(const int* __restrict__ counts, int* __restrict__ row_ptr) {
    __shared__ int wsums[16];
    __shared__ int woff[17];
    __shared__ int carry_s;
    int t = threadIdx.x;
    int lane = t & 63, wid = t >> 6;
    if (t == 0) carry_s = 0;
    __syncthreads();
    for (int base = 0; base < N_NODES; base += 8192) {
        int c = carry_s;
        int i0 = base + t * 8;
        int vals[8];
        int local = 0;
#pragma unroll
        for (int k = 0; k < 8; k++) {
            int i = i0 + k;
            int v = (i < N_NODES) ? counts[i] : 0;
            vals[k] = local;
            local += v;
        }
        int ws = local;
#pragma unroll
        for (int off = 1; off < 64; off <<= 1) {
            int v = __shfl_up(ws, off);
            if (lane >= off) ws += v;
        }
        if (lane == 63) wsums[wid] = ws;
        __syncthreads();
        if (t < 16) {
            int v = wsums[t];
            int s = v;
#pragma unroll
            for (int off = 1; off < 16; off <<= 1) {
                int u = __shfl_up(s, off);
                if (t >= off) s += u;
            }
            woff[t] = s - v;
            if (t == 15) woff[16] = s;
        }
        __syncthreads();
        int texcl = c + woff[wid] + (ws - local);
#pragma unroll
        for (int k = 0; k < 8; k++) {
            int i = i0 + k;
            if (i < N_NODES) row_ptr[i] = texcl + vals[k];
        }
        __syncthreads();
        if (t == 0) carry_s = c + woff[16];
        __syncthreads();
    }
    if (t == 0) row_ptr[N_NODES] = carry_s;
}

__global__ void copy_cursor_kernel(const int* __restrict__ rp, int* __restrict__ cursor) {
    int i = blockIdx.x * blockDim.x + threadIdx.x;
    if (i < N_NODES) cursor[i] = rp[i];
}

__global__ void scatter_kernel(const int* __restrict__ srcv, const int* __restrict__ dstv,
                               int* __restrict__ cursor, int* __restrict__ csr_src) {
    int i = blockIdx.x * blockDim.x + threadIdx.x;
    if (i < N_EDGES) {
        int v = dstv[i];
        int pos = atomicAdd(&cursor[v], 1);
        csr_src[pos] = srcv[i];
    }
}

// ---------------- gemm128: [N,128]@[128,128] + als/ald epilogue, bf16 h out ----------------
// 64x64 tile per block (grid 2*782), 256 thr, 4x4 micro-tile. high occupancy.
__global__ __launch_bounds__(256) void gemm128_kernel(
    const float* __restrict__ X, const float* __restrict__ W,
    const float* __restrict__ a_src, const float* __restrict__ a_dst,
    unsigned int* __restrict__ Hout, float* __restrict__ als, float* __restrict__ ald) {
    __shared__ float Xs[32][68];   // [k][row], stride 68 -> 16B-aligned b128 reads
    __shared__ float Ws[32][64];   // [k][col]
    const int t = threadIdx.x;
    const int tx = t & 15, ty = t >> 4;       // cols 4tx.., rows 4ty..
    const int r0 = (blockIdx.x >> 1) * 64;
    const int c0 = (blockIdx.x & 1) * 64;
    const int sr = t >> 2, sa = t & 3;        // X staging: row, k-octet
    const int wk = t >> 4, wc = (t & 15) * 4; // W staging

    int gr = r0 + sr; gr = gr < N_NODES ? gr : N_NODES - 1;
    const float* Xrow = X + (size_t)gr * 128;
    float4 xpreA = *(const float4*)(Xrow + 8 * sa);
    float4 xpreB = *(const float4*)(Xrow + 8 * sa + 4);
    float4 wpreA = *(const float4*)(W + (size_t)wk * 128 + c0 + wc);
    float4 wpreB = *(const float4*)(W + (size_t)(wk + 16) * 128 + c0 + wc);

    float acc[4][4];
#pragma unroll
    for (int i = 0; i < 4; ++i)
#pragma unroll
        for (int c = 0; c < 4; ++c) acc[i][c] = 0.f;

    for (int step = 0; step < 4; ++step) {
        __syncthreads();
        Xs[8 * sa + 0][sr] = xpreA.x;
        Xs[8 * sa + 1][sr] = xpreA.y;
        Xs[8 * sa + 2][sr] = xpreA.z;
        Xs[8 * sa + 3][sr] = xpreA.w;
        Xs[8 * sa + 4][sr] = xpreB.x;
        Xs[8 * sa + 5][sr] = xpreB.y;
        Xs[8 * sa + 6][sr] = xpreB.z;
        Xs[8 * sa + 7][sr] = xpreB.w;
        *(float4*)&Ws[wk][wc] = wpreA;
        *(float4*)&Ws[wk + 16][wc] = wpreB;
        if (step < 3) {
            int k0 = (step + 1) * 32;
            xpreA = *(const float4*)(Xrow + k0 + 8 * sa);
            xpreB = *(const float4*)(Xrow + k0 + 8 * sa + 4);
            wpreA = *(const float4*)(W + (size_t)(k0 + wk) * 128 + c0 + wc);
            wpreB = *(const float4*)(W + (size_t)(k0 + wk + 16) * 128 + c0 + wc);
        }
        __syncthreads();
#pragma unroll
        for (int kk = 0; kk < 32; ++kk) {
            float4 xv = *(const float4*)&Xs[kk][4 * ty];
            float4 wv = *(const float4*)&Ws[kk][4 * tx];
            float xr[4] = {xv.x, xv.y, xv.z, xv.w};
            float wr[4] = {wv.x, wv.y, wv.z, wv.w};
#pragma unroll
            for (int i = 0; i < 4; ++i)
#pragma unroll
                for (int c = 0; c < 4; ++c)
                    acc[i][c] = fmaf(xr[i], wr[c], acc[i][c]);
        }
    }
    // epilogue: bf16 h store + per-head als/ald (this block covers 2 heads)
    const int head = (c0 >> 5) + (tx >> 3);   // cols 4tx..4tx+3 all in one head
    float asv[4], adv[4];
#pragma unroll
    for (int c = 0; c < 4; ++c) {
        asv[c] = a_src[(head & 1) * 32 + (4 * tx + c) % 32 + (head >> 1) * 64];
        adv[c] = a_dst[(head & 1) * 32 + (4 * tx + c) % 32 + (head >> 1) * 64];
    }
#pragma unroll
    for (int i = 0; i < 4; ++i) {
        int r = r0 + 4 * ty + i;
        bool valid = r < N_NODES;
        if (valid) {
            unsigned int lo = (unsigned int)f2bf(acc[i][0]) | ((unsigned int)f2bf(acc[i][1]) << 16);
            unsigned int hi = (unsigned int)f2bf(acc[i][2]) | ((unsigned int)f2bf(acc[i][3]) << 16);
            uint2 pk = {lo, hi};
            *(uint2*)(Hout + (size_t)r * 64 + (c0 >> 1) + 2 * tx) = pk;
        }
        float ps = 0.f, pd = 0.f;
#pragma unroll
        for (int c = 0; c < 4; ++c) {
            ps = fmaf(acc[i][c], asv[c], ps);
            pd = fmaf(acc[i][c], adv[c], pd);
        }
#pragma unroll
        for (int off = 1; off < 8; off <<= 1) {
            ps += __shfl_xor(ps, off);
            pd += __shfl_xor(pd, off);
        }
        if (valid && (tx & 7) == 0) {
            als[r * 4 + head] = ps;
            ald[r * 4 + head] = pd;
        }
    }
}

// ---------------- gemm40: [N,128]@[128,40] + als/ald epilogue, bf16 h out ----------------
// 64x40 tile per block (grid 782), 256 thr, 2x5 micro-tile
__global__ __launch_bounds__(256) void gemm40_kernel(
    const float* __restrict__ X, const float* __restrict__ W,
    const float* __restrict__ a_src, const float* __restrict__ a_dst,
    unsigned short* __restrict__ Hout, float* __restrict__ als, float* __restrict__ ald) {
    __shared__ float Xs[64][36];   // [row][k], stride 36 -> aligned b128
    __shared__ float Ws[40][36];   // [col][k] transposed
    const int t = threadIdx.x;
    const int tx = t & 7, ty = t >> 3;   // cols tx+8j, rows 2ty..
    const int r0 = blockIdx.x * 64;
    const int sr = t >> 2, sa = t & 3;

    int gr = r0 + sr; gr = gr < N_NODES ? gr : N_NODES - 1;
    const float* Xrow = X + (size_t)gr * 128;
    float4 xpreA = *(const float4*)(Xrow + 8 * sa);
    float4 xpreB = *(const float4*)(Xrow + 8 * sa + 4);
    float wpre[5];
#pragma unroll
    for (int i = 0; i < 5; ++i) wpre[i] = W[t + 256 * i];

    float acc[2][5];
#pragma unroll
    for (int i = 0; i < 2; ++i)
#pragma unroll
        for (int j = 0; j < 5; ++j) acc[i][j] = 0.f;

    for (int step = 0; step < 4; ++step) {
        __syncthreads();
        *(float4*)&Xs[sr][8 * sa] = xpreA;
        *(float4*)&Xs[sr][8 * sa + 4] = xpreB;
#pragma unroll
        for (int i = 0; i < 5; ++i) {
            int idx = t + 256 * i;
            Ws[idx % 40][idx / 40] = wpre[i];
        }
        if (step < 3) {
            int k0 = (step + 1) * 32;
            xpreA = *(const float4*)(Xrow + k0 + 8 * sa);
            xpreB = *(const float4*)(Xrow + k0 + 8 * sa + 4);
#pragma unroll
            for (int i = 0; i < 5; ++i) wpre[i] = W[k0 * 40 + t + 256 * i];
        }
        __syncthreads();
#pragma unroll
        for (int kk4 = 0; kk4 < 8; ++kk4) {
            float4 xa = *(const float4*)&Xs[2 * ty][4 * kk4];
            float4 xb = *(const float4*)&Xs[2 * ty + 1][4 * kk4];
#pragma unroll
            for (int j = 0; j < 5; ++j) {
                float4 wv = *(const float4*)&Ws[tx + 8 * j][4 * kk4];
                acc[0][j] = fmaf(xa.x, wv.x, acc[0][j]);
                acc[0][j] = fmaf(xa.y, wv.y, acc[0][j]);
                acc[0][j] = fmaf(xa.z, wv.z, acc[0][j]);
                acc[0][j] = fmaf(xa.w, wv.w, acc[0][j]);
                acc[1][j] = fmaf(xb.x, wv.x, acc[1][j]);
                acc[1][j] = fmaf(xb.y, wv.y, acc[1][j]);
                acc[1][j] = fmaf(xb.z, wv.z, acc[1][j]);
                acc[1][j] = fmaf(xb.w, wv.w, acc[1][j]);
            }
        }
    }
    float asv[5], adv[5];
#pragma unroll
    for (int j = 0; j < 5; ++j) {
        asv[j] = a_src[tx + 8 * j];
        adv[j] = a_dst[tx + 8 * j];
    }
#pragma unroll
    for (int i = 0; i < 2; ++i) {
        int r = r0 + 2 * ty + i;
        bool valid = r < N_NODES;
        if (valid) {
#pragma unroll
            for (int j = 0; j < 5; ++j)
                Hout[(size_t)r * 40 + tx + 8 * j] = f2bf(acc[i][j]);
        }
        float ps = 0.f, pd = 0.f;
#pragma unroll
        for (int j = 0; j < 5; ++j) {
            ps = fmaf(acc[i][j], asv[j], ps);
            pd = fmaf(acc[i][j], adv[j], pd);
        }
#pragma unroll
        for (int off = 1; off < 8; off <<= 1) {
            ps += __shfl_xor(ps, off);
            pd += __shfl_xor(pd, off);
        }
        if (valid && tx == 0) {
            als[r] = ps;
            ald[r] = pd;
        }
    }
}

// ---------------- aggregation: one wave per destination node, single pass ----------------
__global__ __launch_bounds__(256) void agg128_kernel(
    const int* __restrict__ row_ptr, const int* __restrict__ csr_src,
    const unsigned int* __restrict__ Ht, const float* __restrict__ als, const float* __restrict__ ald,
    const float* __restrict__ bias, float* __restrict__ out) {
    __shared__ float s_p[4][256];
    __shared__ int s_u[4][64];
    int v = (blockIdx.x * blockDim.x + threadIdx.x) >> 6;
    v = __builtin_amdgcn_readfirstlane(v);
    int lane = threadIdx.x & 63;
    int wslot = threadIdx.x >> 6;
    if (v >= N_NODES) return;
    int beg = row_ptr[v], end = row_ptr[v + 1];
    float4 ad4 = *(const float4*)(ald + (size_t)v * 4);
    int h = lane >> 4;
    float m0 = -1e30f, m1 = -1e30f, m2 = -1e30f, m3 = -1e30f;
    float t0 = 0.f, t1 = 0.f, t2 = 0.f, t3 = 0.f;
    float ax = 0.f, ay = 0.f;
    for (int cbeg = beg; cbeg < end; cbeg += 64) {
        int cnt = min(64, end - cbeg);
        bool act = lane < cnt;
        int u = act ? csr_src[cbeg + lane] : 0;
        float e0, e1, e2, e3;
        if (act) {
            float4 s4 = *(const float4*)(als + (size_t)u * 4);
            e0 = lrelu(s4.x + ad4.x);
            e1 = lrelu(s4.y + ad4.y);
            e2 = lrelu(s4.z + ad4.z);
            e3 = lrelu(s4.w + ad4.w);
        } else {
            e0 = e1 = e2 = e3 = -1e30f;
        }
        float c0 = e0, c1 = e1, c2 = e2, c3 = e3;
#pragma unroll
        for (int off = 1; off < 64; off <<= 1) {
            c0 = fmaxf(c0, __shfl_xor(c0, off));
            c1 = fmaxf(c1, __shfl_xor(c1, off));
            c2 = fmaxf(c2, __shfl_xor(c2, off));
            c3 = fmaxf(c3, __shfl_xor(c3, off));
        }
        float n0 = fmaxf(m0, c0), n1 = fmaxf(m1, c1), n2 = fmaxf(m2, c2), n3 = fmaxf(m3, c3);
        float r0 = __expf(m0 - n0), r1 = __expf(m1 - n1), r2 = __expf(m2 - n2), r3 = __expf(m3 - n3);
        float p0 = act ? __expf(e0 - n0) : 0.f;
        float p1 = act ? __expf(e1 - n1) : 0.f;
        float p2 = act ? __expf(e2 - n2) : 0.f;
        float p3 = act ? __expf(e3 - n3) : 0.f;
        float q0 = p0, q1 = p1, q2 = p2, q3 = p3;
#pragma unroll
        for (int off = 1; off < 64; off <<= 1) {
            q0 += __shfl_xor(q0, off);
            q1 += __shfl_xor(q1, off);
            q2 += __shfl_xor(q2, off);
            q3 += __shfl_xor(q3, off);
        }
        t0 = t0 * r0 + q0;
        t1 = t1 * r1 + q1;
        t2 = t2 * r2 + q2;
        t3 = t3 * r3 + q3;
        float sc = sel4(h, r0, r1, r2, r3);
        ax *= sc;
        ay *= sc;
        m0 = n0; m1 = n1; m2 = n2; m3 = n3;
        s_u[wslot][lane] = u;
        float4 pv = {p0, p1, p2, p3};
        *(float4*)&s_p[wslot][lane * 4] = pv;
        for (int i = 0; i < cnt; ++i) {
            int uu = s_u[wslot][i];
            float p = s_p[wslot][i * 4 + h];
            unsigned int w = Ht[(size_t)uu * 64 + lane];
            float hx = __uint_as_float(w << 16);
            float hy = __uint_as_float(w & 0xFFFF0000u);
            ax = fmaf(p, hx, ax);
            ay = fmaf(p, hy, ay);
        }
    }
    float th = sel4(h, t0, t1, t2, t3);
    float inv = 1.f / (th + 1e-16f);
    out[(size_t)v * DHID + lane * 2] = ax * inv + bias[lane * 2];
    out[(size_t)v * DHID + lane * 2 + 1] = ay * inv + bias[lane * 2 + 1];
}

__global__ __launch_bounds__(256) void agg40_kernel(
    const int* __restrict__ row_ptr, const int* __restrict__ csr_src,
    const unsigned short* __restrict__ Ht, const float* __restrict__ als, const float* __restrict__ ald,
    const float* __restrict__ bias, float* __restrict__ out) {
    __shared__ float s_p[4][64];
    __shared__ int s_u[4][64];
    int v = (blockIdx.x * blockDim.x + threadIdx.x) >> 6;
    v = __builtin_amdgcn_readfirstlane(v);
    int lane = threadIdx.x & 63;
    int wslot = threadIdx.x >> 6;
    if (v >= N_NODES) return;
    int beg = row_ptr[v], end = row_ptr[v + 1];
    float adv = ald[v];
    bool actf = lane < DOUT;
    float m = -1e30f, t = 0.f, acc = 0.f;
    for (int cbeg = beg; cbeg < end; cbeg += 64) {
        int cnt = min(64, end - cbeg);
        bool act = lane < cnt;
        int u = act ? csr_src[cbeg + lane] : 0;
        float e = act ? lrelu(als[u] + adv) : -1e30f;
        float c = e;
#pragma unroll
        for (int off = 1; off < 64; off <<= 1) c = fmaxf(c, __shfl_xor(c, off));
        float n = fmaxf(m, c);
        float r = __expf(m - n);
        float p = act ? __expf(e - n) : 0.f;
        float q = p;
#pragma unroll
        for (int off = 1; off < 64; off <<= 1) q += __shfl_xor(q, off);
        t = t * r + q;
        acc *= r;
        m = n;
        s_u[wslot][lane] = u;
        s_p[wslot][lane] = p;
        for (int i = 0; i < cnt; ++i) {
            int uu = s_u[wslot][i];
            float pp = s_p[wslot][i];
            float hv = actf ? bf2f(Ht[(size_t)uu * 40 + lane]) : 0.f;
            acc = fmaf(pp, hv, acc);
        }
    }
    float z = actf ? (acc / (t + 1e-16f) + bias[lane]) : -1e30f;
    // log_softmax over the 40 cols
    float zm = z;
#pragma unroll
    for (int off = 1; off < 64; off <<= 1) zm = fmaxf(zm, __shfl_xor(zm, off));
    float se = actf ? __expf(z - zm) : 0.f;
#pragma unroll
    for (int off = 1; off < 64; off <<= 1) se += __shfl_xor(se, off);
    float res = z - zm - logf(se);
    if (actf) out[(size_t)v * DOUT + lane] = res;
}

// ---------------- batch norm ----------------
__global__ __launch_bounds__(256) void bn_stats_kernel(const float* __restrict__ X,
                                                       float* __restrict__ sums, float* __restrict__ sqs) {
    int f = threadIdx.x & 127;
    int sub = threadIdx.x >> 7;
    int rbeg = blockIdx.x * 100;
    float s = 0.f, q = 0.f;
    for (int r = rbeg + sub; r < rbeg + 100; r += 2) {
        float x = X[(size_t)r * DHID + f];
        s += x;
        q += x * x;
    }
    __shared__ float ls[256], lq[256];
    ls[threadIdx.x] = s;
    lq[threadIdx.x] = q;
    __syncthreads();
    if (threadIdx.x < 128) {
        s = ls[threadIdx.x] + ls[threadIdx.x + 128];
        q = lq[threadIdx.x] + lq[threadIdx.x + 128];
        atomicAdd(&sums[f], s);
        atomicAdd(&sqs[f], q);
    }
}

__global__ void bn_finalize_kernel(const float* __restrict__ sums, const float* __restrict__ sqs,
                                   const float* __restrict__ gamma, const float* __restrict__ beta,
                                   float* __restrict__ scale, float* __restrict__ shift) {
    int f = threadIdx.x;
    if (f < DHID) {
        float mu = sums[f] * (1.f / N_NODES);
        float var = sqs[f] * (1.f / N_NODES) - mu * mu;
        float sc = gamma[f] * rsqrtf(var + 1e-5f);
        scale[f] = sc;
        shift[f] = beta[f] - mu * sc;
    }
}

__global__ __launch_bounds__(256) void bn_apply_kernel(float* __restrict__ X, const float* __restrict__ scale,
                                                       const float* __restrict__ shift, float bscale) {
    const int total = N_NODES * DHID / 4;
    for (int idx = blockIdx.x * blockDim.x + threadIdx.x; idx < total; idx += gridDim.x * blockDim.x) {
        float4 x = ((const float4*)X)[idx];
        int c = (idx & 31) * 4;
        float4 sc = *(const float4*)(scale + c);
        float4 sh = *(const float4*)(shift + c);
        float y0 = x.x * sc.x + sh.x;
        float y1 = x.y * sc.y + sh.y;
        float y2 = x.z * sc.z + sh.z;
        float y3 = x.w * sc.w + sh.w;
        y0 = (y0 > 0.f ? y0 : expm1f(y0)) * bscale;
        y1 = (y1 > 0.f ? y1 : expm1f(y1)) * bscale;
        y2 = (y2 > 0.f ? y2 : expm1f(y2)) * bscale;
        y3 = (y3 > 0.f ? y3 : expm1f(y3)) * bscale;
        float4 y = {y0, y1, y2, y3};
        ((float4*)X)[idx] = y;
    }
}

// ---------------- launch ----------------
extern "C" void kernel_launch(void* const* d_in, const int* in_sizes, int n_in,
                              void* d_out, int out_size, void* d_ws, size_t ws_size,
                              hipStream_t stream) {
    (void)in_sizes; (void)n_in; (void)out_size; (void)ws_size;
    const float* x = (const float*)d_in[0];
    const int* ei = (const int*)d_in[1];
    const float* W0 = (const float*)d_in[2];
    const float* as0 = (const float*)d_in[3];
    const float* ad0 = (const float*)d_in[4];
    const float* b0 = (const float*)d_in[5];
    const float* W1 = (const float*)d_in[6];
    const float* as1 = (const float*)d_in[7];
    const float* ad1 = (const float*)d_in[8];
    const float* b1 = (const float*)d_in[9];
    const float* W2 = (const float*)d_in[10];
    const float* as2 = (const float*)d_in[11];
    const float* ad2 = (const float*)d_in[12];
    const float* b2 = (const float*)d_in[13];
    const float* g_bn0 = (const float*)d_in[14];
    const float* be_bn0 = (const float*)d_in[15];
    const float* g_bn1 = (const float*)d_in[16];
    const float* be_bn1 = (const float*)d_in[17];
    float* out = (float*)d_out;

    const int* srcv = ei;
    const int* dstv = ei + N_EDGES;

    char* p = (char*)d_ws;
    auto carve = [&](size_t bytes) {
        char* q = p;
        p += (bytes + 255) & ~(size_t)255;
        return q;
    };
    unsigned int* h_bf = (unsigned int*)carve((size_t)N_NODES * 64 * 4);  // bf16 h, 12.8 MB (also as [N,40] ushort)
    float* agg   = (float*)carve((size_t)N_NODES * DHID * 4);             // 25.6 MB
    float* als   = (float*)carve((size_t)N_NODES * NH * 4);
    float* ald   = (float*)carve((size_t)N_NODES * NH * 4);
    int* counts  = (int*)carve((size_t)N_NODES * 4);
    int* row_ptr = (int*)carve((size_t)(N_NODES + 1) * 4);
    int* cursor  = (int*)carve((size_t)N_NODES * 4);
    int* csr_src = (int*)carve((size_t)N_EDGES * 4);
    float* sums  = (float*)carve(DHID * 4);
    float* sqs   = (float*)carve(DHID * 4);
    float* scale = (float*)carve(DHID * 4);
    float* shift = (float*)carve(DHID * 4);

    const float bs0 = 1.0f + 1.0f / 25.001f;
    const float bs1 = 1.0f + 0.5f / 25.001f;

    const int EB = (N_EDGES + 255) / 256;
    const int NB = (N_NODES + 255) / 256;
    const int RT64 = (N_NODES + 63) / 64;      // 782
    const int G128B = RT64 * 2;                // 1564 (row tiles x 2 col tiles)
    const int G40B = RT64;                     // 782
    const int AB = (N_NODES * 64 + 255) / 256; // 12500

    // ---- CSR build (shared by all layers) ----
    hipMemsetAsync(counts, 0, (size_t)N_NODES * 4, stream);
    count_kernel<<<EB, 256, 0, stream>>>(dstv, counts);
    scan_kernel<<<1, 1024, 0, stream>>>(counts, row_ptr);
    copy_cursor_kernel<<<NB, 256, 0, stream>>>(row_ptr, cursor);
    scatter_kernel<<<EB, 256, 0, stream>>>(srcv, dstv, cursor, csr_src);

    // ---- layer 0 ----
    gemm128_kernel<<<G128B, 256, 0, stream>>>(x, W0, as0, ad0, h_bf, als, ald);
    agg128_kernel<<<AB, 256, 0, stream>>>(row_ptr, csr_src, h_bf, als, ald, b0, agg);
    hipMemsetAsync(sums, 0, DHID * 4, stream);
    hipMemsetAsync(sqs, 0, DHID * 4, stream);
    bn_stats_kernel<<<500, 256, 0, stream>>>(agg, sums, sqs);
    bn_finalize_kernel<<<1, 128, 0, stream>>>(sums, sqs, g_bn0, be_bn0, scale, shift);
    bn_apply_kernel<<<2048, 256, 0, stream>>>(agg, scale, shift, bs0);

    // ---- layer 1 ----
    gemm128_kernel<<<G128B, 256, 0, stream>>>(agg, W1, as1, ad1, h_bf, als, ald);
    agg128_kernel<<<AB, 256, 0, stream>>>(row_ptr, csr_src, h_bf, als, ald, b1, agg);
    hipMemsetAsync(sums, 0, DHID * 4, stream);
    hipMemsetAsync(sqs, 0, DHID * 4, stream);
    bn_stats_kernel<<<500, 256, 0, stream>>>(agg, sums, sqs);
    bn_finalize_kernel<<<1, 128, 0, stream>>>(sums, sqs, g_bn1, be_bn1, scale, shift);
    bn_apply_kernel<<<2048, 256, 0, stream>>>(agg, scale, shift, bs1);

    // ---- layer 2 + log_softmax ----
    gemm40_kernel<<<G40B, 256, 0, stream>>>(agg, W2, as2, ad2, (unsigned short*)h_bf, als, ald);
    agg40_kernel<<<AB, 256, 0, stream>>>(row_ptr, csr_src, (const unsigned short*)h_bf, als, ald, b2, out);
}

// Round 5
// 375.401 us; speedup vs baseline: 1.5212x; 1.1836x over previous
//
#include <hip/hip_runtime.h>
#include <math.h>

#define N_NODES 50000
#define N_EDGES 800000
#define DIN 128
#define DHID 128   /* H*HID */
#define NH 4
#define HID 32
#define DOUT 40

static __device__ __forceinline__ float lrelu(float x) { return x > 0.f ? x : 0.2f * x; }

static __device__ __forceinline__ float sel4(int h, float a, float b, float c, float d) {
    float ab = (h & 1) ? b : a;
    float cd = (h & 1) ? d : c;
    return (h & 2) ? cd : ab;
}

static __device__ __forceinline__ unsigned short f2bf(float f) {
    unsigned int u = __float_as_uint(f);
    u = (u + 0x7FFFu + ((u >> 16) & 1u)) >> 16;
    return (unsigned short)u;
}

static __device__ __forceinline__ float4 bnelu4(float4 x, float4 sc, float4 sh, float bs) {
    float y0 = fmaf(x.x, sc.x, sh.x);
    float y1 = fmaf(x.y, sc.y, sh.y);
    float y2 = fmaf(x.z, sc.z, sh.z);
    float y3 = fmaf(x.w, sc.w, sh.w);
    y0 = (y0 > 0.f ? y0 : __expf(y0) - 1.f) * bs;
    y1 = (y1 > 0.f ? y1 : __expf(y1) - 1.f) * bs;
    y2 = (y2 > 0.f ? y2 : __expf(y2) - 1.f) * bs;
    y3 = (y3 > 0.f ? y3 : __expf(y3) - 1.f) * bs;
    return {y0, y1, y2, y3};
}

// ---------------- CSR build ----------------
__global__ void count_kernel(const int* __restrict__ dstv, int* __restrict__ counts) {
    int i = blockIdx.x * blockDim.x + threadIdx.x;
    if (i < N_EDGES) atomicAdd(&counts[dstv[i]], 1);
}

__global__ __launch_bounds__(1024) void scan_kernel(const int* __restrict__ counts, int* __restrict__ row_ptr) {
    __shared__ int wsums[16];
    __shared__ int woff[17];
    __shared__ int carry_s;
    int t = threadIdx.x;
    int lane = t & 63, wid = t >> 6;
    if (t == 0) carry_s = 0;
    __syncthreads();
    for (int base = 0; base < N_NODES; base += 8192) {
        int c = carry_s;
        int i0 = base + t * 8;
        int vals[8];
        int local = 0;
#pragma unroll
        for (int k = 0; k < 8; k++) {
            int i = i0 + k;
            int v = (i < N_NODES) ? counts[i] : 0;
            vals[k] = local;
            local += v;
        }
        int ws = local;
#pragma unroll
        for (int off = 1; off < 64; off <<= 1) {
            int v = __shfl_up(ws, off);
            if (lane >= off) ws += v;
        }
        if (lane == 63) wsums[wid] = ws;
        __syncthreads();
        if (t < 16) {
            int v = wsums[t];
            int s = v;
#pragma unroll
            for (int off = 1; off < 16; off <<= 1) {
                int u = __shfl_up(s, off);
                if (t >= off) s += u;
            }
            woff[t] = s - v;
            if (t == 15) woff[16] = s;
        }
        __syncthreads();
        int texcl = c + woff[wid] + (ws - local);
#pragma unroll
        for (int k = 0; k < 8; k++) {
            int i = i0 + k;
            if (i < N_NODES) row_ptr[i] = texcl + vals[k];
        }
        __syncthreads();
        if (t == 0) carry_s = c + woff[16];
        __syncthreads();
    }
    if (t == 0) row_ptr[N_NODES] = carry_s;
}

__global__ void copy_cursor_kernel(const int* __restrict__ rp, int* __restrict__ cursor) {
    int i = blockIdx.x * blockDim.x + threadIdx.x;
    if (i < N_NODES) cursor[i] = rp[i];
}

__global__ void scatter_kernel(const int* __restrict__ srcv, const int* __restrict__ dstv,
                               int* __restrict__ cursor, int* __restrict__ csr_src) {
    int i = blockIdx.x * blockDim.x + threadIdx.x;
    if (i < N_EDGES) {
        int v = dstv[i];
        int pos = atomicAdd(&cursor[v], 1);
        csr_src[pos] = srcv[i];
    }
}

// ---------------- gemm128: [N,128]@[128,128] (+ fused BN/ELU on X) + als/ald epilogue ----------------
// 64x64 tile per block, 256 thr, 4x4 micro-tile
__global__ __launch_bounds__(256) void gemm128_kernel(
    const float* __restrict__ X, const float* __restrict__ W,
    const float* __restrict__ a_src, const float* __restrict__ a_dst,
    const float* __restrict__ scale, const float* __restrict__ shift, float bscale, int apply_bn,
    unsigned int* __restrict__ Hout, float* __restrict__ als, float* __restrict__ ald) {
    __shared__ float Xs[32][68];   // [k][row]
    __shared__ float Ws[32][64];   // [k][col]
    const int t = threadIdx.x;
    const int tx = t & 15, ty = t >> 4;
    const int r0 = (blockIdx.x >> 1) * 64;
    const int c0 = (blockIdx.x & 1) * 64;
    const int sr = t >> 2, sa = t & 3;
    const int wk = t >> 4, wc = (t & 15) * 4;

    int gr = r0 + sr; gr = gr < N_NODES ? gr : N_NODES - 1;
    const float* Xrow = X + (size_t)gr * 128;
    float4 xpreA = *(const float4*)(Xrow + 8 * sa);
    float4 xpreB = *(const float4*)(Xrow + 8 * sa + 4);
    if (apply_bn) {
        xpreA = bnelu4(xpreA, *(const float4*)(scale + 8 * sa), *(const float4*)(shift + 8 * sa), bscale);
        xpreB = bnelu4(xpreB, *(const float4*)(scale + 8 * sa + 4), *(const float4*)(shift + 8 * sa + 4), bscale);
    }
    float4 wpreA = *(const float4*)(W + (size_t)wk * 128 + c0 + wc);
    float4 wpreB = *(const float4*)(W + (size_t)(wk + 16) * 128 + c0 + wc);

    float acc[4][4];
#pragma unroll
    for (int i = 0; i < 4; ++i)
#pragma unroll
        for (int c = 0; c < 4; ++c) acc[i][c] = 0.f;

    for (int step = 0; step < 4; ++step) {
        __syncthreads();
        Xs[8 * sa + 0][sr] = xpreA.x;
        Xs[8 * sa + 1][sr] = xpreA.y;
        Xs[8 * sa + 2][sr] = xpreA.z;
        Xs[8 * sa + 3][sr] = xpreA.w;
        Xs[8 * sa + 4][sr] = xpreB.x;
        Xs[8 * sa + 5][sr] = xpreB.y;
        Xs[8 * sa + 6][sr] = xpreB.z;
        Xs[8 * sa + 7][sr] = xpreB.w;
        *(float4*)&Ws[wk][wc] = wpreA;
        *(float4*)&Ws[wk + 16][wc] = wpreB;
        if (step < 3) {
            int k0 = (step + 1) * 32;
            xpreA = *(const float4*)(Xrow + k0 + 8 * sa);
            xpreB = *(const float4*)(Xrow + k0 + 8 * sa + 4);
            if (apply_bn) {
                xpreA = bnelu4(xpreA, *(const float4*)(scale + k0 + 8 * sa), *(const float4*)(shift + k0 + 8 * sa), bscale);
                xpreB = bnelu4(xpreB, *(const float4*)(scale + k0 + 8 * sa + 4), *(const float4*)(shift + k0 + 8 * sa + 4), bscale);
            }
            wpreA = *(const float4*)(W + (size_t)(k0 + wk) * 128 + c0 + wc);
            wpreB = *(const float4*)(W + (size_t)(k0 + wk + 16) * 128 + c0 + wc);
        }
        __syncthreads();
#pragma unroll
        for (int kk = 0; kk < 32; ++kk) {
            float4 xv = *(const float4*)&Xs[kk][4 * ty];
            float4 wv = *(const float4*)&Ws[kk][4 * tx];
            float xr[4] = {xv.x, xv.y, xv.z, xv.w};
            float wr[4] = {wv.x, wv.y, wv.z, wv.w};
#pragma unroll
            for (int i = 0; i < 4; ++i)
#pragma unroll
                for (int c = 0; c < 4; ++c)
                    acc[i][c] = fmaf(xr[i], wr[c], acc[i][c]);
        }
    }
    const int head = (c0 >> 5) + (tx >> 3);
    float asv[4], adv[4];
#pragma unroll
    for (int c = 0; c < 4; ++c) {
        asv[c] = a_src[(head & 1) * 32 + (4 * tx + c) % 32 + (head >> 1) * 64];
        adv[c] = a_dst[(head & 1) * 32 + (4 * tx + c) % 32 + (head >> 1) * 64];
    }
#pragma unroll
    for (int i = 0; i < 4; ++i) {
        int r = r0 + 4 * ty + i;
        bool valid = r < N_NODES;
        if (valid) {
            unsigned int lo = (unsigned int)f2bf(acc[i][0]) | ((unsigned int)f2bf(acc[i][1]) << 16);
            unsigned int hi = (unsigned int)f2bf(acc[i][2]) | ((unsigned int)f2bf(acc[i][3]) << 16);
            uint2 pk = {lo, hi};
            *(uint2*)(Hout + (size_t)r * 64 + (c0 >> 1) + 2 * tx) = pk;
        }
        float ps = 0.f, pd = 0.f;
#pragma unroll
        for (int c = 0; c < 4; ++c) {
            ps = fmaf(acc[i][c], asv[c], ps);
            pd = fmaf(acc[i][c], adv[c], pd);
        }
#pragma unroll
        for (int off = 1; off < 8; off <<= 1) {
            ps += __shfl_xor(ps, off);
            pd += __shfl_xor(pd, off);
        }
        if (valid && (tx & 7) == 0) {
            als[r * 4 + head] = ps;
            ald[r * 4 + head] = pd;
        }
    }
}

// ---------------- gemm40: [N,128]@[128,40] (+ fused BN/ELU on X) + als/ald, bf16 h out ----------------
__global__ __launch_bounds__(256) void gemm40_kernel(
    const float* __restrict__ X, const float* __restrict__ W,
    const float* __restrict__ a_src, const float* __restrict__ a_dst,
    const float* __restrict__ scale, const float* __restrict__ shift, float bscale,
    unsigned short* __restrict__ Hout, float* __restrict__ als, float* __restrict__ ald) {
    __shared__ float Xs[64][36];
    __shared__ float Ws[40][36];
    const int t = threadIdx.x;
    const int tx = t & 7, ty = t >> 3;
    const int r0 = blockIdx.x * 64;
    const int sr = t >> 2, sa = t & 3;

    int gr = r0 + sr; gr = gr < N_NODES ? gr : N_NODES - 1;
    const float* Xrow = X + (size_t)gr * 128;
    float4 xpreA = bnelu4(*(const float4*)(Xrow + 8 * sa),
                          *(const float4*)(scale + 8 * sa), *(const float4*)(shift + 8 * sa), bscale);
    float4 xpreB = bnelu4(*(const float4*)(Xrow + 8 * sa + 4),
                          *(const float4*)(scale + 8 * sa + 4), *(const float4*)(shift + 8 * sa + 4), bscale);
    float wpre[5];
#pragma unroll
    for (int i = 0; i < 5; ++i) wpre[i] = W[t + 256 * i];

    float acc[2][5];
#pragma unroll
    for (int i = 0; i < 2; ++i)
#pragma unroll
        for (int j = 0; j < 5; ++j) acc[i][j] = 0.f;

    for (int step = 0; step < 4; ++step) {
        __syncthreads();
        *(float4*)&Xs[sr][8 * sa] = xpreA;
        *(float4*)&Xs[sr][8 * sa + 4] = xpreB;
#pragma unroll
        for (int i = 0; i < 5; ++i) {
            int idx = t + 256 * i;
            Ws[idx % 40][idx / 40] = wpre[i];
        }
        if (step < 3) {
            int k0 = (step + 1) * 32;
            xpreA = bnelu4(*(const float4*)(Xrow + k0 + 8 * sa),
                           *(const float4*)(scale + k0 + 8 * sa), *(const float4*)(shift + k0 + 8 * sa), bscale);
            xpreB = bnelu4(*(const float4*)(Xrow + k0 + 8 * sa + 4),
                           *(const float4*)(scale + k0 + 8 * sa + 4), *(const float4*)(shift + k0 + 8 * sa + 4), bscale);
#pragma unroll
            for (int i = 0; i < 5; ++i) wpre[i] = W[k0 * 40 + t + 256 * i];
        }
        __syncthreads();
#pragma unroll
        for (int kk4 = 0; kk4 < 8; ++kk4) {
            float4 xa = *(const float4*)&Xs[2 * ty][4 * kk4];
            float4 xb = *(const float4*)&Xs[2 * ty + 1][4 * kk4];
#pragma unroll
            for (int j = 0; j < 5; ++j) {
                float4 wv = *(const float4*)&Ws[tx + 8 * j][4 * kk4];
                acc[0][j] = fmaf(xa.x, wv.x, acc[0][j]);
                acc[0][j] = fmaf(xa.y, wv.y, acc[0][j]);
                acc[0][j] = fmaf(xa.z, wv.z, acc[0][j]);
                acc[0][j] = fmaf(xa.w, wv.w, acc[0][j]);
                acc[1][j] = fmaf(xb.x, wv.x, acc[1][j]);
                acc[1][j] = fmaf(xb.y, wv.y, acc[1][j]);
                acc[1][j] = fmaf(xb.z, wv.z, acc[1][j]);
                acc[1][j] = fmaf(xb.w, wv.w, acc[1][j]);
            }
        }
    }
    float asv[5], adv[5];
#pragma unroll
    for (int j = 0; j < 5; ++j) {
        asv[j] = a_src[tx + 8 * j];
        adv[j] = a_dst[tx + 8 * j];
    }
#pragma unroll
    for (int i = 0; i < 2; ++i) {
        int r = r0 + 2 * ty + i;
        bool valid = r < N_NODES;
        if (valid) {
#pragma unroll
            for (int j = 0; j < 5; ++j)
                Hout[(size_t)r * 40 + tx + 8 * j] = f2bf(acc[i][j]);
        }
        float ps = 0.f, pd = 0.f;
#pragma unroll
        for (int j = 0; j < 5; ++j) {
            ps = fmaf(acc[i][j], asv[j], ps);
            pd = fmaf(acc[i][j], adv[j], pd);
        }
#pragma unroll
        for (int off = 1; off < 8; off <<= 1) {
            ps += __shfl_xor(ps, off);
            pd += __shfl_xor(pd, off);
        }
        if (valid && tx == 0) {
            als[r] = ps;
            ald[r] = pd;
        }
    }
}

// ---------------- agg128: one wave per node; 4-edge-parallel uint4 gather ----------------
__global__ __launch_bounds__(256) void agg128_kernel(
    const int* __restrict__ row_ptr, const int* __restrict__ csr_src,
    const unsigned int* __restrict__ Ht, const float* __restrict__ als, const float* __restrict__ ald,
    const float* __restrict__ bias, float* __restrict__ out) {
    __shared__ float s_p[4][256];
    __shared__ int s_u[4][64];
    int v = (blockIdx.x * blockDim.x + threadIdx.x) >> 6;
    v = __builtin_amdgcn_readfirstlane(v);
    int lane = threadIdx.x & 63;
    int wslot = threadIdx.x >> 6;
    if (v >= N_NODES) return;
    int beg = row_ptr[v], end = row_ptr[v + 1];
    float4 ad4 = *(const float4*)(ald + (size_t)v * 4);
    const int g = lane >> 4;     // gather group: edge i+g
    const int li = lane & 15;    // owns feats 8li..8li+7 (uints 4li..4li+3), head li>>2
    const int hh = li >> 2;
    float m0 = -1e30f, m1 = -1e30f, m2 = -1e30f, m3 = -1e30f;
    float t0 = 0.f, t1 = 0.f, t2 = 0.f, t3 = 0.f;
    float acc[8];
#pragma unroll
    for (int j = 0; j < 8; ++j) acc[j] = 0.f;

    for (int cbeg = beg; cbeg < end; cbeg += 64) {
        int cnt = min(64, end - cbeg);
        bool act = lane < cnt;
        int u = act ? csr_src[cbeg + lane] : 0;
        float e0, e1, e2, e3;
        if (act) {
            float4 s4 = *(const float4*)(als + (size_t)u * 4);
            e0 = lrelu(s4.x + ad4.x);
            e1 = lrelu(s4.y + ad4.y);
            e2 = lrelu(s4.z + ad4.z);
            e3 = lrelu(s4.w + ad4.w);
        } else {
            e0 = e1 = e2 = e3 = -1e30f;
        }
        float c0 = e0, c1 = e1, c2 = e2, c3 = e3;
#pragma unroll
        for (int off = 1; off < 64; off <<= 1) {
            c0 = fmaxf(c0, __shfl_xor(c0, off));
            c1 = fmaxf(c1, __shfl_xor(c1, off));
            c2 = fmaxf(c2, __shfl_xor(c2, off));
            c3 = fmaxf(c3, __shfl_xor(c3, off));
        }
        float n0 = fmaxf(m0, c0), n1 = fmaxf(m1, c1), n2 = fmaxf(m2, c2), n3 = fmaxf(m3, c3);
        float r0 = __expf(m0 - n0), r1 = __expf(m1 - n1), r2 = __expf(m2 - n2), r3 = __expf(m3 - n3);
        float p0 = act ? __expf(e0 - n0) : 0.f;
        float p1 = act ? __expf(e1 - n1) : 0.f;
        float p2 = act ? __expf(e2 - n2) : 0.f;
        float p3 = act ? __expf(e3 - n3) : 0.f;
        float q0 = p0, q1 = p1, q2 = p2, q3 = p3;
#pragma unroll
        for (int off = 1; off < 64; off <<= 1) {
            q0 += __shfl_xor(q0, off);
            q1 += __shfl_xor(q1, off);
            q2 += __shfl_xor(q2, off);
            q3 += __shfl_xor(q3, off);
        }
        t0 = t0 * r0 + q0;
        t1 = t1 * r1 + q1;
        t2 = t2 * r2 + q2;
        t3 = t3 * r3 + q3;
        float sc = sel4(hh, r0, r1, r2, r3);
#pragma unroll
        for (int j = 0; j < 8; ++j) acc[j] *= sc;
        m0 = n0; m1 = n1; m2 = n2; m3 = n3;
        s_u[wslot][lane] = u;
        float4 pv = {p0, p1, p2, p3};
        *(float4*)&s_p[wslot][lane * 4] = pv;
        for (int i = 0; i < cnt; i += 4) {
            int e = i + g;                    // < 64 always (p=0 beyond cnt)
            int uu = s_u[wslot][e];
            float p = s_p[wslot][e * 4 + hh];
            uint4 w4 = *(const uint4*)(Ht + (size_t)uu * 64 + li * 4);
            acc[0] = fmaf(p, __uint_as_float(w4.x << 16), acc[0]);
            acc[1] = fmaf(p, __uint_as_float(w4.x & 0xFFFF0000u), acc[1]);
            acc[2] = fmaf(p, __uint_as_float(w4.y << 16), acc[2]);
            acc[3] = fmaf(p, __uint_as_float(w4.y & 0xFFFF0000u), acc[3]);
            acc[4] = fmaf(p, __uint_as_float(w4.z << 16), acc[4]);
            acc[5] = fmaf(p, __uint_as_float(w4.z & 0xFFFF0000u), acc[5]);
            acc[6] = fmaf(p, __uint_as_float(w4.w << 16), acc[6]);
            acc[7] = fmaf(p, __uint_as_float(w4.w & 0xFFFF0000u), acc[7]);
        }
    }
    // combine the 4 gather groups (same features in lanes li, li+16, li+32, li+48)
#pragma unroll
    for (int j = 0; j < 8; ++j) {
        acc[j] += __shfl_xor(acc[j], 16);
        acc[j] += __shfl_xor(acc[j], 32);
    }
    float th = sel4(hh, t0, t1, t2, t3);
    float inv = 1.f / (th + 1e-16f);
    if (g == 0) {
        float4 b0 = *(const float4*)(bias + 8 * li);
        float4 b1 = *(const float4*)(bias + 8 * li + 4);
        float4 o0 = {acc[0] * inv + b0.x, acc[1] * inv + b0.y, acc[2] * inv + b0.z, acc[3] * inv + b0.w};
        float4 o1 = {acc[4] * inv + b1.x, acc[5] * inv + b1.y, acc[6] * inv + b1.z, acc[7] * inv + b1.w};
        *(float4*)(out + (size_t)v * DHID + 8 * li) = o0;
        *(float4*)(out + (size_t)v * DHID + 8 * li + 4) = o1;
    }
}

// ---------------- agg40: one wave per node; 2-edge-parallel uint gather + log_softmax ----------------
__global__ __launch_bounds__(256) void agg40_kernel(
    const int* __restrict__ row_ptr, const int* __restrict__ csr_src,
    const unsigned int* __restrict__ HtU, const float* __restrict__ als, const float* __restrict__ ald,
    const float* __restrict__ bias, float* __restrict__ out) {
    __shared__ float s_p[4][64];
    __shared__ int s_u[4][64];
    int v = (blockIdx.x * blockDim.x + threadIdx.x) >> 6;
    v = __builtin_amdgcn_readfirstlane(v);
    int lane = threadIdx.x & 63;
    int wslot = threadIdx.x >> 6;
    if (v >= N_NODES) return;
    int beg = row_ptr[v], end = row_ptr[v + 1];
    float adv = ald[v];
    const int g = lane >> 5;     // gather half: edge i+g
    const int li = lane & 31;    // owns uint li -> feats 2li, 2li+1 (li<20)
    const bool own = li < 20;
    float m = -1e30f, t = 0.f;
    float a0 = 0.f, a1 = 0.f;
    for (int cbeg = beg; cbeg < end; cbeg += 64) {
        int cnt = min(64, end - cbeg);
        bool act = lane < cnt;
        int u = act ? csr_src[cbeg + lane] : 0;
        float e = act ? lrelu(als[u] + adv) : -1e30f;
        float c = e;
#pragma unroll
        for (int off = 1; off < 64; off <<= 1) c = fmaxf(c, __shfl_xor(c, off));
        float n = fmaxf(m, c);
        float r = __expf(m - n);
        float p = act ? __expf(e - n) : 0.f;
        float q = p;
#pragma unroll
        for (int off = 1; off < 64; off <<= 1) q += __shfl_xor(q, off);
        t = t * r + q;
        a0 *= r;
        a1 *= r;
        m = n;
        s_u[wslot][lane] = u;
        s_p[wslot][lane] = p;
        for (int i = 0; i < cnt; i += 2) {
            int e2 = i + g;
            int uu = s_u[wslot][e2];
            float pp = s_p[wslot][e2];
            unsigned int w = own ? HtU[(size_t)uu * 20 + li] : 0u;
            a0 = fmaf(pp, __uint_as_float(w << 16), a0);
            a1 = fmaf(pp, __uint_as_float(w & 0xFFFF0000u), a1);
        }
    }
    a0 += __shfl_xor(a0, 32);
    a1 += __shfl_xor(a1, 32);
    float inv = 1.f / (t + 1e-16f);
    float z0 = own ? (a0 * inv + bias[2 * li]) : -1e30f;
    float z1 = own ? (a1 * inv + bias[2 * li + 1]) : -1e30f;
    float zm = fmaxf(z0, z1);
#pragma unroll
    for (int off = 1; off < 32; off <<= 1) zm = fmaxf(zm, __shfl_xor(zm, off));
    float se = own ? (__expf(z0 - zm) + __expf(z1 - zm)) : 0.f;
#pragma unroll
    for (int off = 1; off < 32; off <<= 1) se += __shfl_xor(se, off);
    float ls = zm + logf(se);
    if (own && g == 0) {
        float2 o = {z0 - ls, z1 - ls};
        *(float2*)(out + (size_t)v * DOUT + 2 * li) = o;
    }
}

// ---------------- batch norm stats ----------------
__global__ __launch_bounds__(256) void bn_stats_kernel(const float* __restrict__ X,
                                                       float* __restrict__ sums, float* __restrict__ sqs) {
    int f = threadIdx.x & 127;
    int sub = threadIdx.x >> 7;
    int rbeg = blockIdx.x * 100;
    float s = 0.f, q = 0.f;
    for (int r = rbeg + sub; r < rbeg + 100; r += 2) {
        float x = X[(size_t)r * DHID + f];
        s += x;
        q += x * x;
    }
    __shared__ float ls[256], lq[256];
    ls[threadIdx.x] = s;
    lq[threadIdx.x] = q;
    __syncthreads();
    if (threadIdx.x < 128) {
        s = ls[threadIdx.x] + ls[threadIdx.x + 128];
        q = lq[threadIdx.x] + lq[threadIdx.x + 128];
        atomicAdd(&sums[f], s);
        atomicAdd(&sqs[f], q);
    }
}

__global__ void bn_finalize_kernel(const float* __restrict__ sums, const float* __restrict__ sqs,
                                   const float* __restrict__ gamma, const float* __restrict__ beta,
                                   float* __restrict__ scale, float* __restrict__ shift) {
    int f = threadIdx.x;
    if (f < DHID) {
        float mu = sums[f] * (1.f / N_NODES);
        float var = sqs[f] * (1.f / N_NODES) - mu * mu;
        float sc = gamma[f] * rsqrtf(var + 1e-5f);
        scale[f] = sc;
        shift[f] = beta[f] - mu * sc;
    }
}

// ---------------- launch ----------------
extern "C" void kernel_launch(void* const* d_in, const int* in_sizes, int n_in,
                              void* d_out, int out_size, void* d_ws, size_t ws_size,
                              hipStream_t stream) {
    (void)in_sizes; (void)n_in; (void)out_size; (void)ws_size;
    const float* x = (const float*)d_in[0];
    const int* ei = (const int*)d_in[1];
    const float* W0 = (const float*)d_in[2];
    const float* as0 = (const float*)d_in[3];
    const float* ad0 = (const float*)d_in[4];
    const float* b0 = (const float*)d_in[5];
    const float* W1 = (const float*)d_in[6];
    const float* as1 = (const float*)d_in[7];
    const float* ad1 = (const float*)d_in[8];
    const float* b1 = (const float*)d_in[9];
    const float* W2 = (const float*)d_in[10];
    const float* as2 = (const float*)d_in[11];
    const float* ad2 = (const float*)d_in[12];
    const float* b2 = (const float*)d_in[13];
    const float* g_bn0 = (const float*)d_in[14];
    const float* be_bn0 = (const float*)d_in[15];
    const float* g_bn1 = (const float*)d_in[16];
    const float* be_bn1 = (const float*)d_in[17];
    float* out = (float*)d_out;

    const int* srcv = ei;
    const int* dstv = ei + N_EDGES;

    char* p = (char*)d_ws;
    auto carve = [&](size_t bytes) {
        char* q = p;
        p += (bytes + 255) & ~(size_t)255;
        return q;
    };
    unsigned int* h_bf = (unsigned int*)carve((size_t)N_NODES * 64 * 4);  // bf16 h (also as [N,40] ushort rows)
    float* agg   = (float*)carve((size_t)N_NODES * DHID * 4);
    float* als   = (float*)carve((size_t)N_NODES * NH * 4);
    float* ald   = (float*)carve((size_t)N_NODES * NH * 4);
    int* counts  = (int*)carve((size_t)N_NODES * 4);
    int* row_ptr = (int*)carve((size_t)(N_NODES + 1) * 4);
    int* cursor  = (int*)carve((size_t)N_NODES * 4);
    int* csr_src = (int*)carve((size_t)N_EDGES * 4);
    float* sums  = (float*)carve(256 * 4);   // sums[0:128], sqs[128:256]
    float* sqs   = sums + 128;
    float* scale = (float*)carve(DHID * 4);
    float* shift = (float*)carve(DHID * 4);

    const float bs0 = 1.0f + 1.0f / 25.001f;
    const float bs1 = 1.0f + 0.5f / 25.001f;

    const int EB = (N_EDGES + 255) / 256;
    const int NB = (N_NODES + 255) / 256;
    const int RT64 = (N_NODES + 63) / 64;      // 782
    const int G128B = RT64 * 2;                // 1564
    const int G40B = RT64;                     // 782
    const int AB = (N_NODES * 64 + 255) / 256; // 12500

    // ---- CSR build ----
    hipMemsetAsync(counts, 0, (size_t)N_NODES * 4, stream);
    count_kernel<<<EB, 256, 0, stream>>>(dstv, counts);
    scan_kernel<<<1, 1024, 0, stream>>>(counts, row_ptr);
    copy_cursor_kernel<<<NB, 256, 0, stream>>>(row_ptr, cursor);
    scatter_kernel<<<EB, 256, 0, stream>>>(srcv, dstv, cursor, csr_src);

    // ---- layer 0 ----
    gemm128_kernel<<<G128B, 256, 0, stream>>>(x, W0, as0, ad0, nullptr, nullptr, 1.f, 0, h_bf, als, ald);
    agg128_kernel<<<AB, 256, 0, stream>>>(row_ptr, csr_src, h_bf, als, ald, b0, agg);
    hipMemsetAsync(sums, 0, 256 * 4, stream);
    bn_stats_kernel<<<500, 256, 0, stream>>>(agg, sums, sqs);
    bn_finalize_kernel<<<1, 128, 0, stream>>>(sums, sqs, g_bn0, be_bn0, scale, shift);

    // ---- layer 1 (BN0+ELU fused into gemm staging) ----
    gemm128_kernel<<<G128B, 256, 0, stream>>>(agg, W1, as1, ad1, scale, shift, bs0, 1, h_bf, als, ald);
    agg128_kernel<<<AB, 256, 0, stream>>>(row_ptr, csr_src, h_bf, als, ald, b1, agg);
    hipMemsetAsync(sums, 0, 256 * 4, stream);
    bn_stats_kernel<<<500, 256, 0, stream>>>(agg, sums, sqs);
    bn_finalize_kernel<<<1, 128, 0, stream>>>(sums, sqs, g_bn1, be_bn1, scale, shift);

    // ---- layer 2 (BN1+ELU fused) + log_softmax ----
    gemm40_kernel<<<G40B, 256, 0, stream>>>(agg, W2, as2, ad2, scale, shift, bs1, (unsigned short*)h_bf, als, ald);
    agg40_kernel<<<AB, 256, 0, stream>>>(row_ptr, csr_src, h_bf, als, ald, b2, out);
}

// Round 6
// 319.450 us; speedup vs baseline: 1.7876x; 1.1751x over previous
//
#include <hip/hip_runtime.h>
#include <math.h>

#define N_NODES 50000
#define N_EDGES 800000
#define DIN 128
#define DHID 128   /* H*HID */
#define NH 4
#define HID 32
#define DOUT 40

#define PB 128      /* dst buckets */
#define NPB 391     /* nodes per bucket: 391*128 = 50048 >= 50000 */

static __device__ __forceinline__ float lrelu(float x) { return x > 0.f ? x : 0.2f * x; }

static __device__ __forceinline__ float sel4(int h, float a, float b, float c, float d) {
    float ab = (h & 1) ? b : a;
    float cd = (h & 1) ? d : c;
    return (h & 2) ? cd : ab;
}

static __device__ __forceinline__ unsigned short f2bf(float f) {
    unsigned int u = __float_as_uint(f);
    u = (u + 0x7FFFu + ((u >> 16) & 1u)) >> 16;
    return (unsigned short)u;
}

static __device__ __forceinline__ float4 bnelu4(float4 x, float4 sc, float4 sh, float bs) {
    float y0 = fmaf(x.x, sc.x, sh.x);
    float y1 = fmaf(x.y, sc.y, sh.y);
    float y2 = fmaf(x.z, sc.z, sh.z);
    float y3 = fmaf(x.w, sc.w, sh.w);
    y0 = (y0 > 0.f ? y0 : __expf(y0) - 1.f) * bs;
    y1 = (y1 > 0.f ? y1 : __expf(y1) - 1.f) * bs;
    y2 = (y2 > 0.f ? y2 : __expf(y2) - 1.f) * bs;
    y3 = (y3 > 0.f ? y3 : __expf(y3) - 1.f) * bs;
    return {y0, y1, y2, y3};
}

// ================= bucketed CSR build (XCD-local writes) =================
__global__ __launch_bounds__(256) void bucket_hist_kernel(const int* __restrict__ dstv, int* __restrict__ bhist) {
    __shared__ int h[PB];
    if (threadIdx.x < PB) h[threadIdx.x] = 0;
    __syncthreads();
    for (int i = blockIdx.x * blockDim.x + threadIdx.x; i < N_EDGES; i += gridDim.x * blockDim.x)
        atomicAdd(&h[(unsigned)dstv[i] / NPB], 1);
    __syncthreads();
    if (threadIdx.x < PB) atomicAdd(&bhist[threadIdx.x], h[threadIdx.x]);
}

__global__ __launch_bounds__(128) void bucket_scan_kernel(const int* __restrict__ bhist,
                                                          int* __restrict__ bucket_base, int* __restrict__ cursor) {
    __shared__ int sA[PB], sB[PB];
    int t = threadIdx.x;
    sA[t] = bhist[t];
    __syncthreads();
    int* s = sA; int* d2 = sB;
    for (int off = 1; off < PB; off <<= 1) {
        d2[t] = s[t] + (t >= off ? s[t - off] : 0);
        __syncthreads();
        int* tmp = s; s = d2; d2 = tmp;
    }
    int excl = s[t] - bhist[t];
    bucket_base[t] = excl;
    cursor[t] = excl;
    if (t == PB - 1) bucket_base[PB] = s[t];
}

// bin edges into bucket regions; LDS reorder -> coalesced run writes
__global__ __launch_bounds__(256) void partition_kernel(const int* __restrict__ srcv, const int* __restrict__ dstv,
                                                        int* __restrict__ cursor, uint2* __restrict__ part) {
    __shared__ uint2 rec[2048];
    __shared__ int cnt[PB], lofs[PB], gbase[PB];
    __shared__ int sA[PB], sB[PB];
    __shared__ int tot_s;
    const int t = threadIdx.x;
    const int base0 = blockIdx.x * 4096;
    for (int round = 0; round < 2; ++round) {
        int rbase = base0 + round * 2048;
        if (t < PB) cnt[t] = 0;
        __syncthreads();
        int myb[8]; int myr[8]; uint2 myrec[8];
#pragma unroll
        for (int i = 0; i < 8; ++i) {
            int e = rbase + i * 256 + t;
            bool valid = e < N_EDGES;
            int sv = valid ? srcv[e] : 0;
            int dv = valid ? dstv[e] : 0;
            myrec[i].x = (unsigned)sv;
            myrec[i].y = (unsigned)dv;
            int b = (unsigned)dv / NPB;
            myb[i] = valid ? b : -1;
            myr[i] = valid ? atomicAdd(&cnt[b], 1) : 0;
        }
        __syncthreads();
        // scan cnt[128]
        if (t < PB) sA[t] = cnt[t];
        __syncthreads();
        int* s = sA; int* d2 = sB;
        for (int off = 1; off < PB; off <<= 1) {
            if (t < PB) d2[t] = s[t] + (t >= off ? s[t - off] : 0);
            __syncthreads();
            int* tmp = s; s = d2; d2 = tmp;
        }
        if (t < PB) {
            int c = cnt[t];
            lofs[t] = s[t] - c;
            gbase[t] = c > 0 ? atomicAdd(&cursor[t], c) : 0;
            if (t == PB - 1) tot_s = s[t];
        }
        __syncthreads();
#pragma unroll
        for (int i = 0; i < 8; ++i)
            if (myb[i] >= 0) rec[lofs[myb[i]] + myr[i]] = myrec[i];
        __syncthreads();
        int tot = tot_s;
#pragma unroll
        for (int i = 0; i < 8; ++i) {
            int lp = i * 256 + t;
            if (lp < tot) {
                uint2 r = rec[lp];
                int b = r.y / NPB;
                part[gbase[b] + (lp - lofs[b])] = r;
            }
        }
        __syncthreads();
    }
}

// one block per bucket: LDS hist + scan -> row_ptr; LDS-cursor scatter -> csr_src (single-XCD writes)
__global__ __launch_bounds__(256) void bucket_csr_kernel(const uint2* __restrict__ part, const int* __restrict__ bucket_base,
                                                         int* __restrict__ row_ptr, int* __restrict__ csr_src) {
    __shared__ int hist[512], sA[512], sB[512], cur[NPB];
    const int b = blockIdx.x, t = threadIdx.x;
    const int base = bucket_base[b];
    const int n = bucket_base[b + 1] - base;
    hist[t] = 0; hist[t + 256] = 0;
    __syncthreads();
    for (int i = t; i < n; i += 256)
        atomicAdd(&hist[part[base + i].y - b * NPB], 1);
    __syncthreads();
    sA[t] = hist[t]; sA[t + 256] = hist[t + 256];
    __syncthreads();
    int* s = sA; int* d2 = sB;
    for (int off = 1; off < 512; off <<= 1) {
        d2[t] = s[t] + (t >= off ? s[t - off] : 0);
        int u = t + 256;
        d2[u] = s[u] + (u >= off ? s[u - off] : 0);
        __syncthreads();
        int* tmp = s; s = d2; d2 = tmp;
    }
    for (int j = t; j < NPB; j += 256) {
        int node = b * NPB + j;
        int excl = s[j] - hist[j];
        if (node < N_NODES) row_ptr[node] = base + excl;
        cur[j] = excl;
    }
    if (b == PB - 1 && t == 0) row_ptr[N_NODES] = N_EDGES;
    __syncthreads();
    for (int i = t; i < n; i += 256) {
        uint2 r = part[base + i];
        int loc = r.y - b * NPB;
        int p = atomicAdd(&cur[loc], 1);
        csr_src[base + p] = (int)r.x;
    }
}

// ---------------- gemm128: [N,128]@[128,128] (+ fused BN/ELU on X) + als/ald epilogue ----------------
__global__ __launch_bounds__(256) void gemm128_kernel(
    const float* __restrict__ X, const float* __restrict__ W,
    const float* __restrict__ a_src, const float* __restrict__ a_dst,
    const float* __restrict__ scale, const float* __restrict__ shift, float bscale, int apply_bn,
    unsigned int* __restrict__ Hout, float* __restrict__ als, float* __restrict__ ald) {
    __shared__ float Xs[32][68];
    __shared__ float Ws[32][64];
    const int t = threadIdx.x;
    const int tx = t & 15, ty = t >> 4;
    const int r0 = (blockIdx.x >> 1) * 64;
    const int c0 = (blockIdx.x & 1) * 64;
    const int sr = t >> 2, sa = t & 3;
    const int wk = t >> 4, wc = (t & 15) * 4;

    int gr = r0 + sr; gr = gr < N_NODES ? gr : N_NODES - 1;
    const float* Xrow = X + (size_t)gr * 128;
    float4 xpreA = *(const float4*)(Xrow + 8 * sa);
    float4 xpreB = *(const float4*)(Xrow + 8 * sa + 4);
    if (apply_bn) {
        xpreA = bnelu4(xpreA, *(const float4*)(scale + 8 * sa), *(const float4*)(shift + 8 * sa), bscale);
        xpreB = bnelu4(xpreB, *(const float4*)(scale + 8 * sa + 4), *(const float4*)(shift + 8 * sa + 4), bscale);
    }
    float4 wpreA = *(const float4*)(W + (size_t)wk * 128 + c0 + wc);
    float4 wpreB = *(const float4*)(W + (size_t)(wk + 16) * 128 + c0 + wc);

    float acc[4][4];
#pragma unroll
    for (int i = 0; i < 4; ++i)
#pragma unroll
        for (int c = 0; c < 4; ++c) acc[i][c] = 0.f;

    for (int step = 0; step < 4; ++step) {
        __syncthreads();
        Xs[8 * sa + 0][sr] = xpreA.x;
        Xs[8 * sa + 1][sr] = xpreA.y;
        Xs[8 * sa + 2][sr] = xpreA.z;
        Xs[8 * sa + 3][sr] = xpreA.w;
        Xs[8 * sa + 4][sr] = xpreB.x;
        Xs[8 * sa + 5][sr] = xpreB.y;
        Xs[8 * sa + 6][sr] = xpreB.z;
        Xs[8 * sa + 7][sr] = xpreB.w;
        *(float4*)&Ws[wk][wc] = wpreA;
        *(float4*)&Ws[wk + 16][wc] = wpreB;
        if (step < 3) {
            int k0 = (step + 1) * 32;
            xpreA = *(const float4*)(Xrow + k0 + 8 * sa);
            xpreB = *(const float4*)(Xrow + k0 + 8 * sa + 4);
            if (apply_bn) {
                xpreA = bnelu4(xpreA, *(const float4*)(scale + k0 + 8 * sa), *(const float4*)(shift + k0 + 8 * sa), bscale);
                xpreB = bnelu4(xpreB, *(const float4*)(scale + k0 + 8 * sa + 4), *(const float4*)(shift + k0 + 8 * sa + 4), bscale);
            }
            wpreA = *(const float4*)(W + (size_t)(k0 + wk) * 128 + c0 + wc);
            wpreB = *(const float4*)(W + (size_t)(k0 + wk + 16) * 128 + c0 + wc);
        }
        __syncthreads();
#pragma unroll
        for (int kk = 0; kk < 32; ++kk) {
            float4 xv = *(const float4*)&Xs[kk][4 * ty];
            float4 wv = *(const float4*)&Ws[kk][4 * tx];
            float xr[4] = {xv.x, xv.y, xv.z, xv.w};
            float wr[4] = {wv.x, wv.y, wv.z, wv.w};
#pragma unroll
            for (int i = 0; i < 4; ++i)
#pragma unroll
                for (int c = 0; c < 4; ++c)
                    acc[i][c] = fmaf(xr[i], wr[c], acc[i][c]);
        }
    }
    const int head = (c0 >> 5) + (tx >> 3);
    float asv[4], adv[4];
#pragma unroll
    for (int c = 0; c < 4; ++c) {
        asv[c] = a_src[(head & 1) * 32 + (4 * tx + c) % 32 + (head >> 1) * 64];
        adv[c] = a_dst[(head & 1) * 32 + (4 * tx + c) % 32 + (head >> 1) * 64];
    }
#pragma unroll
    for (int i = 0; i < 4; ++i) {
        int r = r0 + 4 * ty + i;
        bool valid = r < N_NODES;
        if (valid) {
            unsigned int lo = (unsigned int)f2bf(acc[i][0]) | ((unsigned int)f2bf(acc[i][1]) << 16);
            unsigned int hi = (unsigned int)f2bf(acc[i][2]) | ((unsigned int)f2bf(acc[i][3]) << 16);
            uint2 pk = {lo, hi};
            *(uint2*)(Hout + (size_t)r * 64 + (c0 >> 1) + 2 * tx) = pk;
        }
        float ps = 0.f, pd = 0.f;
#pragma unroll
        for (int c = 0; c < 4; ++c) {
            ps = fmaf(acc[i][c], asv[c], ps);
            pd = fmaf(acc[i][c], adv[c], pd);
        }
#pragma unroll
        for (int off = 1; off < 8; off <<= 1) {
            ps += __shfl_xor(ps, off);
            pd += __shfl_xor(pd, off);
        }
        if (valid && (tx & 7) == 0) {
            als[r * 4 + head] = ps;
            ald[r * 4 + head] = pd;
        }
    }
}

// ---------------- gemm40: [N,128]@[128,40] (+ fused BN/ELU on X) + als/ald, bf16 h out ----------------
__global__ __launch_bounds__(256) void gemm40_kernel(
    const float* __restrict__ X, const float* __restrict__ W,
    const float* __restrict__ a_src, const float* __restrict__ a_dst,
    const float* __restrict__ scale, const float* __restrict__ shift, float bscale,
    unsigned short* __restrict__ Hout, float* __restrict__ als, float* __restrict__ ald) {
    __shared__ float Xs[64][36];
    __shared__ float Ws[40][36];
    const int t = threadIdx.x;
    const int tx = t & 7, ty = t >> 3;
    const int r0 = blockIdx.x * 64;
    const int sr = t >> 2, sa = t & 3;

    int gr = r0 + sr; gr = gr < N_NODES ? gr : N_NODES - 1;
    const float* Xrow = X + (size_t)gr * 128;
    float4 xpreA = bnelu4(*(const float4*)(Xrow + 8 * sa),
                          *(const float4*)(scale + 8 * sa), *(const float4*)(shift + 8 * sa), bscale);
    float4 xpreB = bnelu4(*(const float4*)(Xrow + 8 * sa + 4),
                          *(const float4*)(scale + 8 * sa + 4), *(const float4*)(shift + 8 * sa + 4), bscale);
    float wpre[5];
#pragma unroll
    for (int i = 0; i < 5; ++i) wpre[i] = W[t + 256 * i];

    float acc[2][5];
#pragma unroll
    for (int i = 0; i < 2; ++i)
#pragma unroll
        for (int j = 0; j < 5; ++j) acc[i][j] = 0.f;

    for (int step = 0; step < 4; ++step) {
        __syncthreads();
        *(float4*)&Xs[sr][8 * sa] = xpreA;
        *(float4*)&Xs[sr][8 * sa + 4] = xpreB;
#pragma unroll
        for (int i = 0; i < 5; ++i) {
            int idx = t + 256 * i;
            Ws[idx % 40][idx / 40] = wpre[i];
        }
        if (step < 3) {
            int k0 = (step + 1) * 32;
            xpreA = bnelu4(*(const float4*)(Xrow + k0 + 8 * sa),
                           *(const float4*)(scale + k0 + 8 * sa), *(const float4*)(shift + k0 + 8 * sa), bscale);
            xpreB = bnelu4(*(const float4*)(Xrow + k0 + 8 * sa + 4),
                           *(const float4*)(scale + k0 + 8 * sa + 4), *(const float4*)(shift + k0 + 8 * sa + 4), bscale);
#pragma unroll
            for (int i = 0; i < 5; ++i) wpre[i] = W[k0 * 40 + t + 256 * i];
        }
        __syncthreads();
#pragma unroll
        for (int kk4 = 0; kk4 < 8; ++kk4) {
            float4 xa = *(const float4*)&Xs[2 * ty][4 * kk4];
            float4 xb = *(const float4*)&Xs[2 * ty + 1][4 * kk4];
#pragma unroll
            for (int j = 0; j < 5; ++j) {
                float4 wv = *(const float4*)&Ws[tx + 8 * j][4 * kk4];
                acc[0][j] = fmaf(xa.x, wv.x, acc[0][j]);
                acc[0][j] = fmaf(xa.y, wv.y, acc[0][j]);
                acc[0][j] = fmaf(xa.z, wv.z, acc[0][j]);
                acc[0][j] = fmaf(xa.w, wv.w, acc[0][j]);
                acc[1][j] = fmaf(xb.x, wv.x, acc[1][j]);
                acc[1][j] = fmaf(xb.y, wv.y, acc[1][j]);
                acc[1][j] = fmaf(xb.z, wv.z, acc[1][j]);
                acc[1][j] = fmaf(xb.w, wv.w, acc[1][j]);
            }
        }
    }
    float asv[5], adv[5];
#pragma unroll
    for (int j = 0; j < 5; ++j) {
        asv[j] = a_src[tx + 8 * j];
        adv[j] = a_dst[tx + 8 * j];
    }
#pragma unroll
    for (int i = 0; i < 2; ++i) {
        int r = r0 + 2 * ty + i;
        bool valid = r < N_NODES;
        if (valid) {
#pragma unroll
            for (int j = 0; j < 5; ++j)
                Hout[(size_t)r * 40 + tx + 8 * j] = f2bf(acc[i][j]);
        }
        float ps = 0.f, pd = 0.f;
#pragma unroll
        for (int j = 0; j < 5; ++j) {
            ps = fmaf(acc[i][j], asv[j], ps);
            pd = fmaf(acc[i][j], adv[j], pd);
        }
#pragma unroll
        for (int off = 1; off < 8; off <<= 1) {
            ps += __shfl_xor(ps, off);
            pd += __shfl_xor(pd, off);
        }
        if (valid && tx == 0) {
            als[r] = ps;
            ald[r] = pd;
        }
    }
}

// ---------------- agg128: one wave per node; 4-edge-parallel uint4 gather ----------------
__global__ __launch_bounds__(256) void agg128_kernel(
    const int* __restrict__ row_ptr, const int* __restrict__ csr_src,
    const unsigned int* __restrict__ Ht, const float* __restrict__ als, const float* __restrict__ ald,
    const float* __restrict__ bias, float* __restrict__ out) {
    __shared__ float s_p[4][256];
    __shared__ int s_u[4][64];
    int v = (blockIdx.x * blockDim.x + threadIdx.x) >> 6;
    v = __builtin_amdgcn_readfirstlane(v);
    int lane = threadIdx.x & 63;
    int wslot = threadIdx.x >> 6;
    if (v >= N_NODES) return;
    int beg = row_ptr[v], end = row_ptr[v + 1];
    float4 ad4 = *(const float4*)(ald + (size_t)v * 4);
    const int g = lane >> 4;
    const int li = lane & 15;
    const int hh = li >> 2;
    float m0 = -1e30f, m1 = -1e30f, m2 = -1e30f, m3 = -1e30f;
    float t0 = 0.f, t1 = 0.f, t2 = 0.f, t3 = 0.f;
    float acc[8];
#pragma unroll
    for (int j = 0; j < 8; ++j) acc[j] = 0.f;

    for (int cbeg = beg; cbeg < end; cbeg += 64) {
        int cnt = min(64, end - cbeg);
        bool act = lane < cnt;
        int u = act ? csr_src[cbeg + lane] : 0;
        float e0, e1, e2, e3;
        if (act) {
            float4 s4 = *(const float4*)(als + (size_t)u * 4);
            e0 = lrelu(s4.x + ad4.x);
            e1 = lrelu(s4.y + ad4.y);
            e2 = lrelu(s4.z + ad4.z);
            e3 = lrelu(s4.w + ad4.w);
        } else {
            e0 = e1 = e2 = e3 = -1e30f;
        }
        float c0 = e0, c1 = e1, c2 = e2, c3 = e3;
#pragma unroll
        for (int off = 1; off < 64; off <<= 1) {
            c0 = fmaxf(c0, __shfl_xor(c0, off));
            c1 = fmaxf(c1, __shfl_xor(c1, off));
            c2 = fmaxf(c2, __shfl_xor(c2, off));
            c3 = fmaxf(c3, __shfl_xor(c3, off));
        }
        float n0 = fmaxf(m0, c0), n1 = fmaxf(m1, c1), n2 = fmaxf(m2, c2), n3 = fmaxf(m3, c3);
        float r0 = __expf(m0 - n0), r1 = __expf(m1 - n1), r2 = __expf(m2 - n2), r3 = __expf(m3 - n3);
        float p0 = act ? __expf(e0 - n0) : 0.f;
        float p1 = act ? __expf(e1 - n1) : 0.f;
        float p2 = act ? __expf(e2 - n2) : 0.f;
        float p3 = act ? __expf(e3 - n3) : 0.f;
        float q0 = p0, q1 = p1, q2 = p2, q3 = p3;
#pragma unroll
        for (int off = 1; off < 64; off <<= 1) {
            q0 += __shfl_xor(q0, off);
            q1 += __shfl_xor(q1, off);
            q2 += __shfl_xor(q2, off);
            q3 += __shfl_xor(q3, off);
        }
        t0 = t0 * r0 + q0;
        t1 = t1 * r1 + q1;
        t2 = t2 * r2 + q2;
        t3 = t3 * r3 + q3;
        float sc = sel4(hh, r0, r1, r2, r3);
#pragma unroll
        for (int j = 0; j < 8; ++j) acc[j] *= sc;
        m0 = n0; m1 = n1; m2 = n2; m3 = n3;
        s_u[wslot][lane] = u;
        float4 pv = {p0, p1, p2, p3};
        *(float4*)&s_p[wslot][lane * 4] = pv;
        for (int i = 0; i < cnt; i += 4) {
            int e = i + g;
            int uu = s_u[wslot][e];
            float p = s_p[wslot][e * 4 + hh];
            uint4 w4 = *(const uint4*)(Ht + (size_t)uu * 64 + li * 4);
            acc[0] = fmaf(p, __uint_as_float(w4.x << 16), acc[0]);
            acc[1] = fmaf(p, __uint_as_float(w4.x & 0xFFFF0000u), acc[1]);
            acc[2] = fmaf(p, __uint_as_float(w4.y << 16), acc[2]);
            acc[3] = fmaf(p, __uint_as_float(w4.y & 0xFFFF0000u), acc[3]);
            acc[4] = fmaf(p, __uint_as_float(w4.z << 16), acc[4]);
            acc[5] = fmaf(p, __uint_as_float(w4.z & 0xFFFF0000u), acc[5]);
            acc[6] = fmaf(p, __uint_as_float(w4.w << 16), acc[6]);
            acc[7] = fmaf(p, __uint_as_float(w4.w & 0xFFFF0000u), acc[7]);
        }
    }
#pragma unroll
    for (int j = 0; j < 8; ++j) {
        acc[j] += __shfl_xor(acc[j], 16);
        acc[j] += __shfl_xor(acc[j], 32);
    }
    float th = sel4(hh, t0, t1, t2, t3);
    float inv = 1.f / (th + 1e-16f);
    if (g == 0) {
        float4 b0 = *(const float4*)(bias + 8 * li);
        float4 b1 = *(const float4*)(bias + 8 * li + 4);
        float4 o0 = {acc[0] * inv + b0.x, acc[1] * inv + b0.y, acc[2] * inv + b0.z, acc[3] * inv + b0.w};
        float4 o1 = {acc[4] * inv + b1.x, acc[5] * inv + b1.y, acc[6] * inv + b1.z, acc[7] * inv + b1.w};
        *(float4*)(out + (size_t)v * DHID + 8 * li) = o0;
        *(float4*)(out + (size_t)v * DHID + 8 * li + 4) = o1;
    }
}

// ---------------- agg40: one wave per node; 2-edge-parallel uint gather + log_softmax ----------------
__global__ __launch_bounds__(256) void agg40_kernel(
    const int* __restrict__ row_ptr, const int* __restrict__ csr_src,
    const unsigned int* __restrict__ HtU, const float* __restrict__ als, const float* __restrict__ ald,
    const float* __restrict__ bias, float* __restrict__ out) {
    __shared__ float s_p[4][64];
    __shared__ int s_u[4][64];
    int v = (blockIdx.x * blockDim.x + threadIdx.x) >> 6;
    v = __builtin_amdgcn_readfirstlane(v);
    int lane = threadIdx.x & 63;
    int wslot = threadIdx.x >> 6;
    if (v >= N_NODES) return;
    int beg = row_ptr[v], end = row_ptr[v + 1];
    float adv = ald[v];
    const int g = lane >> 5;
    const int li = lane & 31;
    const bool own = li < 20;
    float m = -1e30f, t = 0.f;
    float a0 = 0.f, a1 = 0.f;
    for (int cbeg = beg; cbeg < end; cbeg += 64) {
        int cnt = min(64, end - cbeg);
        bool act = lane < cnt;
        int u = act ? csr_src[cbeg + lane] : 0;
        float e = act ? lrelu(als[u] + adv) : -1e30f;
        float c = e;
#pragma unroll
        for (int off = 1; off < 64; off <<= 1) c = fmaxf(c, __shfl_xor(c, off));
        float n = fmaxf(m, c);
        float r = __expf(m - n);
        float p = act ? __expf(e - n) : 0.f;
        float q = p;
#pragma unroll
        for (int off = 1; off < 64; off <<= 1) q += __shfl_xor(q, off);
        t = t * r + q;
        a0 *= r;
        a1 *= r;
        m = n;
        s_u[wslot][lane] = u;
        s_p[wslot][lane] = p;
        for (int i = 0; i < cnt; i += 2) {
            int e2 = i + g;
            int uu = s_u[wslot][e2];
            float pp = s_p[wslot][e2];
            unsigned int w = own ? HtU[(size_t)uu * 20 + li] : 0u;
            a0 = fmaf(pp, __uint_as_float(w << 16), a0);
            a1 = fmaf(pp, __uint_as_float(w & 0xFFFF0000u), a1);
        }
    }
    a0 += __shfl_xor(a0, 32);
    a1 += __shfl_xor(a1, 32);
    float inv = 1.f / (t + 1e-16f);
    float z0 = own ? (a0 * inv + bias[2 * li]) : -1e30f;
    float z1 = own ? (a1 * inv + bias[2 * li + 1]) : -1e30f;
    float zm = fmaxf(z0, z1);
#pragma unroll
    for (int off = 1; off < 32; off <<= 1) zm = fmaxf(zm, __shfl_xor(zm, off));
    float se = own ? (__expf(z0 - zm) + __expf(z1 - zm)) : 0.f;
#pragma unroll
    for (int off = 1; off < 32; off <<= 1) se += __shfl_xor(se, off);
    float ls = zm + logf(se);
    if (own && g == 0) {
        float2 o = {z0 - ls, z1 - ls};
        *(float2*)(out + (size_t)v * DOUT + 2 * li) = o;
    }
}

// ---------------- batch norm stats ----------------
__global__ __launch_bounds__(256) void bn_stats_kernel(const float* __restrict__ X,
                                                       float* __restrict__ sums, float* __restrict__ sqs) {
    int f = threadIdx.x & 127;
    int sub = threadIdx.x >> 7;
    int rbeg = blockIdx.x * 100;
    float s = 0.f, q = 0.f;
    for (int r = rbeg + sub; r < rbeg + 100; r += 2) {
        float x = X[(size_t)r * DHID + f];
        s += x;
        q += x * x;
    }
    __shared__ float ls[256], lq[256];
    ls[threadIdx.x] = s;
    lq[threadIdx.x] = q;
    __syncthreads();
    if (threadIdx.x < 128) {
        s = ls[threadIdx.x] + ls[threadIdx.x + 128];
        q = lq[threadIdx.x] + lq[threadIdx.x + 128];
        atomicAdd(&sums[f], s);
        atomicAdd(&sqs[f], q);
    }
}

__global__ void bn_finalize_kernel(const float* __restrict__ sums, const float* __restrict__ sqs,
                                   const float* __restrict__ gamma, const float* __restrict__ beta,
                                   float* __restrict__ scale, float* __restrict__ shift) {
    int f = threadIdx.x;
    if (f < DHID) {
        float mu = sums[f] * (1.f / N_NODES);
        float var = sqs[f] * (1.f / N_NODES) - mu * mu;
        float sc = gamma[f] * rsqrtf(var + 1e-5f);
        scale[f] = sc;
        shift[f] = beta[f] - mu * sc;
    }
}

// ---------------- launch ----------------
extern "C" void kernel_launch(void* const* d_in, const int* in_sizes, int n_in,
                              void* d_out, int out_size, void* d_ws, size_t ws_size,
                              hipStream_t stream) {
    (void)in_sizes; (void)n_in; (void)out_size; (void)ws_size;
    const float* x = (const float*)d_in[0];
    const int* ei = (const int*)d_in[1];
    const float* W0 = (const float*)d_in[2];
    const float* as0 = (const float*)d_in[3];
    const float* ad0 = (const float*)d_in[4];
    const float* b0 = (const float*)d_in[5];
    const float* W1 = (const float*)d_in[6];
    const float* as1 = (const float*)d_in[7];
    const float* ad1 = (const float*)d_in[8];
    const float* b1 = (const float*)d_in[9];
    const float* W2 = (const float*)d_in[10];
    const float* as2 = (const float*)d_in[11];
    const float* ad2 = (const float*)d_in[12];
    const float* b2 = (const float*)d_in[13];
    const float* g_bn0 = (const float*)d_in[14];
    const float* be_bn0 = (const float*)d_in[15];
    const float* g_bn1 = (const float*)d_in[16];
    const float* be_bn1 = (const float*)d_in[17];
    float* out = (float*)d_out;

    const int* srcv = ei;
    const int* dstv = ei + N_EDGES;

    char* p = (char*)d_ws;
    auto carve = [&](size_t bytes) {
        char* q = p;
        p += (bytes + 255) & ~(size_t)255;
        return q;
    };
    unsigned int* h_bf = (unsigned int*)carve((size_t)N_NODES * 64 * 4);  // bf16 h
    float* agg   = (float*)carve((size_t)N_NODES * DHID * 4);
    float* als   = (float*)carve((size_t)N_NODES * NH * 4);
    float* ald   = (float*)carve((size_t)N_NODES * NH * 4);
    int* row_ptr = (int*)carve((size_t)(N_NODES + 1) * 4);
    int* csr_src = (int*)carve((size_t)N_EDGES * 4);
    uint2* part  = (uint2*)carve((size_t)N_EDGES * 8);
    int* bhist   = (int*)carve(PB * 4);
    int* bucket_base = (int*)carve((PB + 1) * 4);
    int* cursor  = (int*)carve(PB * 4);
    float* sums  = (float*)carve(256 * 4);
    float* sqs   = sums + 128;
    float* scale = (float*)carve(DHID * 4);
    float* shift = (float*)carve(DHID * 4);

    const float bs0 = 1.0f + 1.0f / 25.001f;
    const float bs1 = 1.0f + 0.5f / 25.001f;

    const int RT64 = (N_NODES + 63) / 64;      // 782
    const int G128B = RT64 * 2;                // 1564
    const int G40B = RT64;                     // 782
    const int AB = (N_NODES * 64 + 255) / 256; // 12500
    const int PARTB = (N_EDGES + 4095) / 4096; // 196

    // ---- bucketed CSR build ----
    hipMemsetAsync(bhist, 0, PB * 4, stream);
    bucket_hist_kernel<<<400, 256, 0, stream>>>(dstv, bhist);
    bucket_scan_kernel<<<1, PB, 0, stream>>>(bhist, bucket_base, cursor);
    partition_kernel<<<PARTB, 256, 0, stream>>>(srcv, dstv, cursor, part);
    bucket_csr_kernel<<<PB, 256, 0, stream>>>(part, bucket_base, row_ptr, csr_src);

    // ---- layer 0 ----
    gemm128_kernel<<<G128B, 256, 0, stream>>>(x, W0, as0, ad0, nullptr, nullptr, 1.f, 0, h_bf, als, ald);
    agg128_kernel<<<AB, 256, 0, stream>>>(row_ptr, csr_src, h_bf, als, ald, b0, agg);
    hipMemsetAsync(sums, 0, 256 * 4, stream);
    bn_stats_kernel<<<500, 256, 0, stream>>>(agg, sums, sqs);
    bn_finalize_kernel<<<1, 128, 0, stream>>>(sums, sqs, g_bn0, be_bn0, scale, shift);

    // ---- layer 1 (BN0+ELU fused into gemm staging) ----
    gemm128_kernel<<<G128B, 256, 0, stream>>>(agg, W1, as1, ad1, scale, shift, bs0, 1, h_bf, als, ald);
    agg128_kernel<<<AB, 256, 0, stream>>>(row_ptr, csr_src, h_bf, als, ald, b1, agg);
    hipMemsetAsync(sums, 0, 256 * 4, stream);
    bn_stats_kernel<<<500, 256, 0, stream>>>(agg, sums, sqs);
    bn_finalize_kernel<<<1, 128, 0, stream>>>(sums, sqs, g_bn1, be_bn1, scale, shift);

    // ---- layer 2 (BN1+ELU fused) + log_softmax ----
    gemm40_kernel<<<G40B, 256, 0, stream>>>(agg, W2, as2, ad2, scale, shift, bs1, (unsigned short*)h_bf, als, ald);
    agg40_kernel<<<AB, 256, 0, stream>>>(row_ptr, csr_src, h_bf, als, ald, b2, out);
}

// Round 8
// 314.369 us; speedup vs baseline: 1.8165x; 1.0162x over previous
//
#include <hip/hip_runtime.h>
#include <math.h>

#define N_NODES 50000
#define N_EDGES 800000
#define DIN 128
#define DHID 128   /* H*HID */
#define NH 4
#define HID 32
#define DOUT 40

#define PB 128      /* dst buckets */
#define NPB 391     /* nodes per bucket: 391*128 = 50048 >= 50000 */

typedef __fp16 fp16x2 __attribute__((ext_vector_type(2)));

static __device__ __forceinline__ float lrelu(float x) { return x > 0.f ? x : 0.2f * x; }

static __device__ __forceinline__ float sel4(int h, float a, float b, float c, float d) {
    float ab = (h & 1) ? b : a;
    float cd = (h & 1) ? d : c;
    return (h & 2) ? cd : ab;
}

// pack two floats to f16x2 (v_cvt_pkrtz_f16_f32, single instruction)
static __device__ __forceinline__ unsigned int pkh(float a, float b) {
    union { fp16x2 h2; unsigned int u; } cv;
    cv.h2 = __builtin_amdgcn_cvt_pkrtz(a, b);
    return cv.u;
}
static __device__ __forceinline__ unsigned short f2h(float a) {
    union { _Float16 h; unsigned short s; } cv;
    cv.h = (_Float16)a;
    return cv.s;
}

// acc[0..7] += p * f16x8(w)  — unpack via f16->f32 (fuses to v_fma_mix)
static __device__ __forceinline__ void fma8(float* acc, uint4 w, float p) {
    union { unsigned int u; _Float16 h[2]; } c0, c1, c2, c3;
    c0.u = w.x; c1.u = w.y; c2.u = w.z; c3.u = w.w;
    acc[0] = fmaf((float)c0.h[0], p, acc[0]);
    acc[1] = fmaf((float)c0.h[1], p, acc[1]);
    acc[2] = fmaf((float)c1.h[0], p, acc[2]);
    acc[3] = fmaf((float)c1.h[1], p, acc[3]);
    acc[4] = fmaf((float)c2.h[0], p, acc[4]);
    acc[5] = fmaf((float)c2.h[1], p, acc[5]);
    acc[6] = fmaf((float)c3.h[0], p, acc[6]);
    acc[7] = fmaf((float)c3.h[1], p, acc[7]);
}

static __device__ __forceinline__ float4 bnelu4(float4 x, float4 sc, float4 sh, float bs) {
    float y0 = fmaf(x.x, sc.x, sh.x);
    float y1 = fmaf(x.y, sc.y, sh.y);
    float y2 = fmaf(x.z, sc.z, sh.z);
    float y3 = fmaf(x.w, sc.w, sh.w);
    y0 = (y0 > 0.f ? y0 : __expf(y0) - 1.f) * bs;
    y1 = (y1 > 0.f ? y1 : __expf(y1) - 1.f) * bs;
    y2 = (y2 > 0.f ? y2 : __expf(y2) - 1.f) * bs;
    y3 = (y3 > 0.f ? y3 : __expf(y3) - 1.f) * bs;
    return {y0, y1, y2, y3};
}

// ================= bucketed CSR build (XCD-local writes) =================
__global__ __launch_bounds__(256) void bucket_hist_kernel(const int* __restrict__ dstv, int* __restrict__ bhist) {
    __shared__ int h[PB];
    if (threadIdx.x < PB) h[threadIdx.x] = 0;
    __syncthreads();
    for (int i = blockIdx.x * blockDim.x + threadIdx.x; i < N_EDGES; i += gridDim.x * blockDim.x)
        atomicAdd(&h[(unsigned)dstv[i] / NPB], 1);
    __syncthreads();
    if (threadIdx.x < PB) atomicAdd(&bhist[threadIdx.x], h[threadIdx.x]);
}

__global__ __launch_bounds__(128) void bucket_scan_kernel(const int* __restrict__ bhist,
                                                          int* __restrict__ bucket_base, int* __restrict__ cursor) {
    __shared__ int sA[PB], sB[PB];
    int t = threadIdx.x;
    sA[t] = bhist[t];
    __syncthreads();
    int* s = sA; int* d2 = sB;
    for (int off = 1; off < PB; off <<= 1) {
        d2[t] = s[t] + (t >= off ? s[t - off] : 0);
        __syncthreads();
        int* tmp = s; s = d2; d2 = tmp;
    }
    int excl = s[t] - bhist[t];
    bucket_base[t] = excl;
    cursor[t] = excl;
    if (t == PB - 1) bucket_base[PB] = s[t];
}

__global__ __launch_bounds__(256) void partition_kernel(const int* __restrict__ srcv, const int* __restrict__ dstv,
                                                        int* __restrict__ cursor, uint2* __restrict__ part) {
    __shared__ uint2 rec[2048];
    __shared__ int cnt[PB], lofs[PB], gbase[PB];
    __shared__ int sA[PB], sB[PB];
    __shared__ int tot_s;
    const int t = threadIdx.x;
    const int base0 = blockIdx.x * 4096;
    for (int round = 0; round < 2; ++round) {
        int rbase = base0 + round * 2048;
        if (t < PB) cnt[t] = 0;
        __syncthreads();
        int myb[8]; int myr[8]; uint2 myrec[8];
#pragma unroll
        for (int i = 0; i < 8; ++i) {
            int e = rbase + i * 256 + t;
            bool valid = e < N_EDGES;
            int sv = valid ? srcv[e] : 0;
            int dv = valid ? dstv[e] : 0;
            myrec[i].x = (unsigned)sv;
            myrec[i].y = (unsigned)dv;
            int b = (unsigned)dv / NPB;
            myb[i] = valid ? b : -1;
            myr[i] = valid ? atomicAdd(&cnt[b], 1) : 0;
        }
        __syncthreads();
        if (t < PB) sA[t] = cnt[t];
        __syncthreads();
        int* s = sA; int* d2 = sB;
        for (int off = 1; off < PB; off <<= 1) {
            if (t < PB) d2[t] = s[t] + (t >= off ? s[t - off] : 0);
            __syncthreads();
            int* tmp = s; s = d2; d2 = tmp;
        }
        if (t < PB) {
            int c = cnt[t];
            lofs[t] = s[t] - c;
            gbase[t] = c > 0 ? atomicAdd(&cursor[t], c) : 0;
            if (t == PB - 1) tot_s = s[t];
        }
        __syncthreads();
#pragma unroll
        for (int i = 0; i < 8; ++i)
            if (myb[i] >= 0) rec[lofs[myb[i]] + myr[i]] = myrec[i];
        __syncthreads();
        int tot = tot_s;
#pragma unroll
        for (int i = 0; i < 8; ++i) {
            int lp = i * 256 + t;
            if (lp < tot) {
                uint2 r = rec[lp];
                int b = r.y / NPB;
                part[gbase[b] + (lp - lofs[b])] = r;
            }
        }
        __syncthreads();
    }
}

__global__ __launch_bounds__(256) void bucket_csr_kernel(const uint2* __restrict__ part, const int* __restrict__ bucket_base,
                                                         int* __restrict__ row_ptr, int* __restrict__ csr_src) {
    __shared__ int hist[512], sA[512], sB[512], cur[NPB];
    const int b = blockIdx.x, t = threadIdx.x;
    const int base = bucket_base[b];
    const int n = bucket_base[b + 1] - base;
    hist[t] = 0; hist[t + 256] = 0;
    __syncthreads();
    for (int i = t; i < n; i += 256)
        atomicAdd(&hist[part[base + i].y - b * NPB], 1);
    __syncthreads();
    sA[t] = hist[t]; sA[t + 256] = hist[t + 256];
    __syncthreads();
    int* s = sA; int* d2 = sB;
    for (int off = 1; off < 512; off <<= 1) {
        d2[t] = s[t] + (t >= off ? s[t - off] : 0);
        int u = t + 256;
        d2[u] = s[u] + (u >= off ? s[u - off] : 0);
        __syncthreads();
        int* tmp = s; s = d2; d2 = tmp;
    }
    for (int j = t; j < NPB; j += 256) {
        int node = b * NPB + j;
        int excl = s[j] - hist[j];
        if (node < N_NODES) row_ptr[node] = base + excl;
        cur[j] = excl;
    }
    if (b == PB - 1 && t == 0) row_ptr[N_NODES] = N_EDGES;
    __syncthreads();
    for (int i = t; i < n; i += 256) {
        uint2 r = part[base + i];
        int loc = r.y - b * NPB;
        int p = atomicAdd(&cur[loc], 1);
        csr_src[base + p] = (int)r.x;
    }
}

// ---------------- gemm128: [N,128]@[128,128] (+ fused BN/ELU on X) + als/ald epilogue ----------------
__global__ __launch_bounds__(256) void gemm128_kernel(
    const float* __restrict__ X, const float* __restrict__ W,
    const float* __restrict__ a_src, const float* __restrict__ a_dst,
    const float* __restrict__ scale, const float* __restrict__ shift, float bscale, int apply_bn,
    unsigned int* __restrict__ Hout, float* __restrict__ als, float* __restrict__ ald) {
    __shared__ float Xs[32][68];
    __shared__ float Ws[32][64];
    const int t = threadIdx.x;
    const int tx = t & 15, ty = t >> 4;
    const int r0 = (blockIdx.x >> 1) * 64;
    const int c0 = (blockIdx.x & 1) * 64;
    const int sr = t >> 2, sa = t & 3;
    const int wk = t >> 4, wc = (t & 15) * 4;

    int gr = r0 + sr; gr = gr < N_NODES ? gr : N_NODES - 1;
    const float* Xrow = X + (size_t)gr * 128;
    float4 xpreA = *(const float4*)(Xrow + 8 * sa);
    float4 xpreB = *(const float4*)(Xrow + 8 * sa + 4);
    if (apply_bn) {
        xpreA = bnelu4(xpreA, *(const float4*)(scale + 8 * sa), *(const float4*)(shift + 8 * sa), bscale);
        xpreB = bnelu4(xpreB, *(const float4*)(scale + 8 * sa + 4), *(const float4*)(shift + 8 * sa + 4), bscale);
    }
    float4 wpreA = *(const float4*)(W + (size_t)wk * 128 + c0 + wc);
    float4 wpreB = *(const float4*)(W + (size_t)(wk + 16) * 128 + c0 + wc);

    float acc[4][4];
#pragma unroll
    for (int i = 0; i < 4; ++i)
#pragma unroll
        for (int c = 0; c < 4; ++c) acc[i][c] = 0.f;

    for (int step = 0; step < 4; ++step) {
        __syncthreads();
        Xs[8 * sa + 0][sr] = xpreA.x;
        Xs[8 * sa + 1][sr] = xpreA.y;
        Xs[8 * sa + 2][sr] = xpreA.z;
        Xs[8 * sa + 3][sr] = xpreA.w;
        Xs[8 * sa + 4][sr] = xpreB.x;
        Xs[8 * sa + 5][sr] = xpreB.y;
        Xs[8 * sa + 6][sr] = xpreB.z;
        Xs[8 * sa + 7][sr] = xpreB.w;
        *(float4*)&Ws[wk][wc] = wpreA;
        *(float4*)&Ws[wk + 16][wc] = wpreB;
        if (step < 3) {
            int k0 = (step + 1) * 32;
            xpreA = *(const float4*)(Xrow + k0 + 8 * sa);
            xpreB = *(const float4*)(Xrow + k0 + 8 * sa + 4);
            if (apply_bn) {
                xpreA = bnelu4(xpreA, *(const float4*)(scale + k0 + 8 * sa), *(const float4*)(shift + k0 + 8 * sa), bscale);
                xpreB = bnelu4(xpreB, *(const float4*)(scale + k0 + 8 * sa + 4), *(const float4*)(shift + k0 + 8 * sa + 4), bscale);
            }
            wpreA = *(const float4*)(W + (size_t)(k0 + wk) * 128 + c0 + wc);
            wpreB = *(const float4*)(W + (size_t)(k0 + wk + 16) * 128 + c0 + wc);
        }
        __syncthreads();
#pragma unroll
        for (int kk = 0; kk < 32; ++kk) {
            float4 xv = *(const float4*)&Xs[kk][4 * ty];
            float4 wv = *(const float4*)&Ws[kk][4 * tx];
            float xr[4] = {xv.x, xv.y, xv.z, xv.w};
            float wr[4] = {wv.x, wv.y, wv.z, wv.w};
#pragma unroll
            for (int i = 0; i < 4; ++i)
#pragma unroll
                for (int c = 0; c < 4; ++c)
                    acc[i][c] = fmaf(xr[i], wr[c], acc[i][c]);
        }
    }
    const int head = (c0 >> 5) + (tx >> 3);
    float asv[4], adv[4];
#pragma unroll
    for (int c = 0; c < 4; ++c) {
        asv[c] = a_src[(head & 1) * 32 + (4 * tx + c) % 32 + (head >> 1) * 64];
        adv[c] = a_dst[(head & 1) * 32 + (4 * tx + c) % 32 + (head >> 1) * 64];
    }
#pragma unroll
    for (int i = 0; i < 4; ++i) {
        int r = r0 + 4 * ty + i;
        bool valid = r < N_NODES;
        if (valid) {
            uint2 pk = {pkh(acc[i][0], acc[i][1]), pkh(acc[i][2], acc[i][3])};
            *(uint2*)(Hout + (size_t)r * 64 + (c0 >> 1) + 2 * tx) = pk;
        }
        float ps = 0.f, pd = 0.f;
#pragma unroll
        for (int c = 0; c < 4; ++c) {
            ps = fmaf(acc[i][c], asv[c], ps);
            pd = fmaf(acc[i][c], adv[c], pd);
        }
#pragma unroll
        for (int off = 1; off < 8; off <<= 1) {
            ps += __shfl_xor(ps, off);
            pd += __shfl_xor(pd, off);
        }
        if (valid && (tx & 7) == 0) {
            als[r * 4 + head] = ps;
            ald[r * 4 + head] = pd;
        }
    }
}

// ---------------- gemm40: [N,128]@[128,40] (+ fused BN/ELU on X) + als/ald, f16 h out ----------------
__global__ __launch_bounds__(256) void gemm40_kernel(
    const float* __restrict__ X, const float* __restrict__ W,
    const float* __restrict__ a_src, const float* __restrict__ a_dst,
    const float* __restrict__ scale, const float* __restrict__ shift, float bscale,
    unsigned short* __restrict__ Hout, float* __restrict__ als, float* __restrict__ ald) {
    __shared__ float Xs[64][36];
    __shared__ float Ws[40][36];
    const int t = threadIdx.x;
    const int tx = t & 7, ty = t >> 3;
    const int r0 = blockIdx.x * 64;
    const int sr = t >> 2, sa = t & 3;

    int gr = r0 + sr; gr = gr < N_NODES ? gr : N_NODES - 1;
    const float* Xrow = X + (size_t)gr * 128;
    float4 xpreA = bnelu4(*(const float4*)(Xrow + 8 * sa),
                          *(const float4*)(scale + 8 * sa), *(const float4*)(shift + 8 * sa), bscale);
    float4 xpreB = bnelu4(*(const float4*)(Xrow + 8 * sa + 4),
                          *(const float4*)(scale + 8 * sa + 4), *(const float4*)(shift + 8 * sa + 4), bscale);
    float wpre[5];
#pragma unroll
    for (int i = 0; i < 5; ++i) wpre[i] = W[t + 256 * i];

    float acc[2][5];
#pragma unroll
    for (int i = 0; i < 2; ++i)
#pragma unroll
        for (int j = 0; j < 5; ++j) acc[i][j] = 0.f;

    for (int step = 0; step < 4; ++step) {
        __syncthreads();
        *(float4*)&Xs[sr][8 * sa] = xpreA;
        *(float4*)&Xs[sr][8 * sa + 4] = xpreB;
#pragma unroll
        for (int i = 0; i < 5; ++i) {
            int idx = t + 256 * i;
            Ws[idx % 40][idx / 40] = wpre[i];
        }
        if (step < 3) {
            int k0 = (step + 1) * 32;
            xpreA = bnelu4(*(const float4*)(Xrow + k0 + 8 * sa),
                           *(const float4*)(scale + k0 + 8 * sa), *(const float4*)(shift + k0 + 8 * sa), bscale);
            xpreB = bnelu4(*(const float4*)(Xrow + k0 + 8 * sa + 4),
                           *(const float4*)(scale + k0 + 8 * sa + 4), *(const float4*)(shift + k0 + 8 * sa + 4), bscale);
#pragma unroll
            for (int i = 0; i < 5; ++i) wpre[i] = W[k0 * 40 + t + 256 * i];
        }
        __syncthreads();
#pragma unroll
        for (int kk4 = 0; kk4 < 8; ++kk4) {
            float4 xa = *(const float4*)&Xs[2 * ty][4 * kk4];
            float4 xb = *(const float4*)&Xs[2 * ty + 1][4 * kk4];
#pragma unroll
            for (int j = 0; j < 5; ++j) {
                float4 wv = *(const float4*)&Ws[tx + 8 * j][4 * kk4];
                acc[0][j] = fmaf(xa.x, wv.x, acc[0][j]);
                acc[0][j] = fmaf(xa.y, wv.y, acc[0][j]);
                acc[0][j] = fmaf(xa.z, wv.z, acc[0][j]);
                acc[0][j] = fmaf(xa.w, wv.w, acc[0][j]);
                acc[1][j] = fmaf(xb.x, wv.x, acc[1][j]);
                acc[1][j] = fmaf(xb.y, wv.y, acc[1][j]);
                acc[1][j] = fmaf(xb.z, wv.z, acc[1][j]);
                acc[1][j] = fmaf(xb.w, wv.w, acc[1][j]);
            }
        }
    }
    float asv[5], adv[5];
#pragma unroll
    for (int j = 0; j < 5; ++j) {
        asv[j] = a_src[tx + 8 * j];
        adv[j] = a_dst[tx + 8 * j];
    }
#pragma unroll
    for (int i = 0; i < 2; ++i) {
        int r = r0 + 2 * ty + i;
        bool valid = r < N_NODES;
        if (valid) {
#pragma unroll
            for (int j = 0; j < 5; ++j)
                Hout[(size_t)r * 40 + tx + 8 * j] = f2h(acc[i][j]);
        }
        float ps = 0.f, pd = 0.f;
#pragma unroll
        for (int j = 0; j < 5; ++j) {
            ps = fmaf(acc[i][j], asv[j], ps);
            pd = fmaf(acc[i][j], adv[j], pd);
        }
#pragma unroll
        for (int off = 1; off < 8; off <<= 1) {
            ps += __shfl_xor(ps, off);
            pd += __shfl_xor(pd, off);
        }
        if (valid && tx == 0) {
            als[r] = ps;
            ald[r] = pd;
        }
    }
}

// ---------------- agg128: one wave per node; 4-edge-parallel, 4-deep pipelined gather ----------------
__global__ __launch_bounds__(256) void agg128_kernel(
    const int* __restrict__ row_ptr, const int* __restrict__ csr_src,
    const unsigned int* __restrict__ Ht, const float* __restrict__ als, const float* __restrict__ ald,
    const float* __restrict__ bias, float* __restrict__ out) {
    __shared__ float s_p[4][256];
    __shared__ int s_u[4][64];
    int v = (blockIdx.x * blockDim.x + threadIdx.x) >> 6;
    v = __builtin_amdgcn_readfirstlane(v);
    int lane = threadIdx.x & 63;
    int wslot = threadIdx.x >> 6;
    if (v >= N_NODES) return;
    int beg = row_ptr[v], end = row_ptr[v + 1];
    float4 ad4 = *(const float4*)(ald + (size_t)v * 4);
    const int g = lane >> 4;
    const int li = lane & 15;
    const int hh = li >> 2;
    float m0 = -1e30f, m1 = -1e30f, m2 = -1e30f, m3 = -1e30f;
    float t0 = 0.f, t1 = 0.f, t2 = 0.f, t3 = 0.f;
    float acc[8];
#pragma unroll
    for (int j = 0; j < 8; ++j) acc[j] = 0.f;

    for (int cbeg = beg; cbeg < end; cbeg += 64) {
        int cnt = min(64, end - cbeg);
        bool act = lane < cnt;
        int u = act ? csr_src[cbeg + lane] : 0;
        float e0, e1, e2, e3;
        if (act) {
            float4 s4 = *(const float4*)(als + (size_t)u * 4);
            e0 = lrelu(s4.x + ad4.x);
            e1 = lrelu(s4.y + ad4.y);
            e2 = lrelu(s4.z + ad4.z);
            e3 = lrelu(s4.w + ad4.w);
        } else {
            e0 = e1 = e2 = e3 = -1e30f;
        }
        float c0 = e0, c1 = e1, c2 = e2, c3 = e3;
#pragma unroll
        for (int off = 1; off < 64; off <<= 1) {
            c0 = fmaxf(c0, __shfl_xor(c0, off));
            c1 = fmaxf(c1, __shfl_xor(c1, off));
            c2 = fmaxf(c2, __shfl_xor(c2, off));
            c3 = fmaxf(c3, __shfl_xor(c3, off));
        }
        float n0 = fmaxf(m0, c0), n1 = fmaxf(m1, c1), n2 = fmaxf(m2, c2), n3 = fmaxf(m3, c3);
        float r0 = __expf(m0 - n0), r1 = __expf(m1 - n1), r2 = __expf(m2 - n2), r3 = __expf(m3 - n3);
        float p0 = act ? __expf(e0 - n0) : 0.f;
        float p1 = act ? __expf(e1 - n1) : 0.f;
        float p2 = act ? __expf(e2 - n2) : 0.f;
        float p3 = act ? __expf(e3 - n3) : 0.f;
        float q0 = p0, q1 = p1, q2 = p2, q3 = p3;
#pragma unroll
        for (int off = 1; off < 64; off <<= 1) {
            q0 += __shfl_xor(q0, off);
            q1 += __shfl_xor(q1, off);
            q2 += __shfl_xor(q2, off);
            q3 += __shfl_xor(q3, off);
        }
        t0 = t0 * r0 + q0;
        t1 = t1 * r1 + q1;
        t2 = t2 * r2 + q2;
        t3 = t3 * r3 + q3;
        float sc = sel4(hh, r0, r1, r2, r3);
#pragma unroll
        for (int j = 0; j < 8; ++j) acc[j] *= sc;
        m0 = n0; m1 = n1; m2 = n2; m3 = n3;
        s_u[wslot][lane] = u;
        float4 pv = {p0, p1, p2, p3};
        *(float4*)&s_p[wslot][lane * 4] = pv;
        // 4-deep pipelined gather: 16 edges per step, 4 loads in flight per lane.
        // s_u/s_p are staged for all 64 slots (u=0, p=0 beyond cnt) -> over-read is safe.
        for (int i = 0; i < cnt; i += 16) {
            int u0 = s_u[wslot][i + g];
            int u1 = s_u[wslot][i + 4 + g];
            int u2 = s_u[wslot][i + 8 + g];
            int u3 = s_u[wslot][i + 12 + g];
            float pa = s_p[wslot][(i + g) * 4 + hh];
            float pb = s_p[wslot][(i + 4 + g) * 4 + hh];
            float pc = s_p[wslot][(i + 8 + g) * 4 + hh];
            float pd = s_p[wslot][(i + 12 + g) * 4 + hh];
            uint4 wa = *(const uint4*)(Ht + (size_t)u0 * 64 + li * 4);
            uint4 wb = *(const uint4*)(Ht + (size_t)u1 * 64 + li * 4);
            uint4 wc = *(const uint4*)(Ht + (size_t)u2 * 64 + li * 4);
            uint4 wd = *(const uint4*)(Ht + (size_t)u3 * 64 + li * 4);
            fma8(acc, wa, pa);
            fma8(acc, wb, pb);
            fma8(acc, wc, pc);
            fma8(acc, wd, pd);
        }
    }
#pragma unroll
    for (int j = 0; j < 8; ++j) {
        acc[j] += __shfl_xor(acc[j], 16);
        acc[j] += __shfl_xor(acc[j], 32);
    }
    float th = sel4(hh, t0, t1, t2, t3);
    float inv = 1.f / (th + 1e-16f);
    if (g == 0) {
        float4 b0 = *(const float4*)(bias + 8 * li);
        float4 b1 = *(const float4*)(bias + 8 * li + 4);
        float4 o0 = {acc[0] * inv + b0.x, acc[1] * inv + b0.y, acc[2] * inv + b0.z, acc[3] * inv + b0.w};
        float4 o1 = {acc[4] * inv + b1.x, acc[5] * inv + b1.y, acc[6] * inv + b1.z, acc[7] * inv + b1.w};
        *(float4*)(out + (size_t)v * DHID + 8 * li) = o0;
        *(float4*)(out + (size_t)v * DHID + 8 * li + 4) = o1;
    }
}

// ---------------- agg40: one wave per node; 2-edge-parallel, 4-deep pipelined gather ----------------
__global__ __launch_bounds__(256) void agg40_kernel(
    const int* __restrict__ row_ptr, const int* __restrict__ csr_src,
    const unsigned int* __restrict__ HtU, const float* __restrict__ als, const float* __restrict__ ald,
    const float* __restrict__ bias, float* __restrict__ out) {
    __shared__ float s_p[4][64];
    __shared__ int s_u[4][64];
    int v = (blockIdx.x * blockDim.x + threadIdx.x) >> 6;
    v = __builtin_amdgcn_readfirstlane(v);
    int lane = threadIdx.x & 63;
    int wslot = threadIdx.x >> 6;
    if (v >= N_NODES) return;
    int beg = row_ptr[v], end = row_ptr[v + 1];
    float adv = ald[v];
    const int g = lane >> 5;
    const int li = lane & 31;
    const bool own = li < 20;
    float m = -1e30f, t = 0.f;
    float a0 = 0.f, a1 = 0.f;
    for (int cbeg = beg; cbeg < end; cbeg += 64) {
        int cnt = min(64, end - cbeg);
        bool act = lane < cnt;
        int u = act ? csr_src[cbeg + lane] : 0;
        float e = act ? lrelu(als[u] + adv) : -1e30f;
        float c = e;
#pragma unroll
        for (int off = 1; off < 64; off <<= 1) c = fmaxf(c, __shfl_xor(c, off));
        float n = fmaxf(m, c);
        float r = __expf(m - n);
        float p = act ? __expf(e - n) : 0.f;
        float q = p;
#pragma unroll
        for (int off = 1; off < 64; off <<= 1) q += __shfl_xor(q, off);
        t = t * r + q;
        a0 *= r;
        a1 *= r;
        m = n;
        s_u[wslot][lane] = u;
        s_p[wslot][lane] = p;
        // 4-deep pipelined gather: 8 edges per step (2 per sub-step via g)
        for (int i = 0; i < cnt; i += 8) {
            int u0 = s_u[wslot][i + g];
            int u1 = s_u[wslot][i + 2 + g];
            int u2 = s_u[wslot][i + 4 + g];
            int u3 = s_u[wslot][i + 6 + g];
            float pa = s_p[wslot][i + g];
            float pb = s_p[wslot][i + 2 + g];
            float pc = s_p[wslot][i + 4 + g];
            float pd = s_p[wslot][i + 6 + g];
            unsigned int w0 = own ? HtU[(size_t)u0 * 20 + li] : 0u;
            unsigned int w1 = own ? HtU[(size_t)u1 * 20 + li] : 0u;
            unsigned int w2 = own ? HtU[(size_t)u2 * 20 + li] : 0u;
            unsigned int w3 = own ? HtU[(size_t)u3 * 20 + li] : 0u;
            union { unsigned int u; _Float16 h[2]; } c0, c1, c2, c3;
            c0.u = w0; c1.u = w1; c2.u = w2; c3.u = w3;
            a0 = fmaf((float)c0.h[0], pa, a0);
            a1 = fmaf((float)c0.h[1], pa, a1);
            a0 = fmaf((float)c1.h[0], pb, a0);
            a1 = fmaf((float)c1.h[1], pb, a1);
            a0 = fmaf((float)c2.h[0], pc, a0);
            a1 = fmaf((float)c2.h[1], pc, a1);
            a0 = fmaf((float)c3.h[0], pd, a0);
            a1 = fmaf((float)c3.h[1], pd, a1);
        }
    }
    a0 += __shfl_xor(a0, 32);
    a1 += __shfl_xor(a1, 32);
    float inv = 1.f / (t + 1e-16f);
    float z0 = own ? (a0 * inv + bias[2 * li]) : -1e30f;
    float z1 = own ? (a1 * inv + bias[2 * li + 1]) : -1e30f;
    float zm = fmaxf(z0, z1);
#pragma unroll
    for (int off = 1; off < 32; off <<= 1) zm = fmaxf(zm, __shfl_xor(zm, off));
    float se = own ? (__expf(z0 - zm) + __expf(z1 - zm)) : 0.f;
#pragma unroll
    for (int off = 1; off < 32; off <<= 1) se += __shfl_xor(se, off);
    float ls = zm + logf(se);
    if (own && g == 0) {
        float2 o = {z0 - ls, z1 - ls};
        *(float2*)(out + (size_t)v * DOUT + 2 * li) = o;
    }
}

// ---------------- batch norm stats ----------------
__global__ __launch_bounds__(256) void bn_stats_kernel(const float* __restrict__ X,
                                                       float* __restrict__ sums, float* __restrict__ sqs) {
    int f = threadIdx.x & 127;
    int sub = threadIdx.x >> 7;
    int rbeg = blockIdx.x * 100;
    float s = 0.f, q = 0.f;
    for (int r = rbeg + sub; r < rbeg + 100; r += 2) {
        float x = X[(size_t)r * DHID + f];
        s += x;
        q += x * x;
    }
    __shared__ float ls[256], lq[256];
    ls[threadIdx.x] = s;
    lq[threadIdx.x] = q;
    __syncthreads();
    if (threadIdx.x < 128) {
        s = ls[threadIdx.x] + ls[threadIdx.x + 128];
        q = lq[threadIdx.x] + lq[threadIdx.x + 128];
        atomicAdd(&sums[f], s);
        atomicAdd(&sqs[f], q);
    }
}

__global__ void bn_finalize_kernel(const float* __restrict__ sums, const float* __restrict__ sqs,
                                   const float* __restrict__ gamma, const float* __restrict__ beta,
                                   float* __restrict__ scale, float* __restrict__ shift) {
    int f = threadIdx.x;
    if (f < DHID) {
        float mu = sums[f] * (1.f / N_NODES);
        float var = sqs[f] * (1.f / N_NODES) - mu * mu;
        float sc = gamma[f] * rsqrtf(var + 1e-5f);
        scale[f] = sc;
        shift[f] = beta[f] - mu * sc;
    }
}

// ---------------- launch ----------------
extern "C" void kernel_launch(void* const* d_in, const int* in_sizes, int n_in,
                              void* d_out, int out_size, void* d_ws, size_t ws_size,
                              hipStream_t stream) {
    (void)in_sizes; (void)n_in; (void)out_size; (void)ws_size;
    const float* x = (const float*)d_in[0];
    const int* ei = (const int*)d_in[1];
    const float* W0 = (const float*)d_in[2];
    const float* as0 = (const float*)d_in[3];
    const float* ad0 = (const float*)d_in[4];
    const float* b0 = (const float*)d_in[5];
    const float* W1 = (const float*)d_in[6];
    const float* as1 = (const float*)d_in[7];
    const float* ad1 = (const float*)d_in[8];
    const float* b1 = (const float*)d_in[9];
    const float* W2 = (const float*)d_in[10];
    const float* as2 = (const float*)d_in[11];
    const float* ad2 = (const float*)d_in[12];
    const float* b2 = (const float*)d_in[13];
    const float* g_bn0 = (const float*)d_in[14];
    const float* be_bn0 = (const float*)d_in[15];
    const float* g_bn1 = (const float*)d_in[16];
    const float* be_bn1 = (const float*)d_in[17];
    float* out = (float*)d_out;

    const int* srcv = ei;
    const int* dstv = ei + N_EDGES;

    char* p = (char*)d_ws;
    auto carve = [&](size_t bytes) {
        char* q = p;
        p += (bytes + 255) & ~(size_t)255;
        return q;
    };
    unsigned int* h_bf = (unsigned int*)carve((size_t)N_NODES * 64 * 4);  // f16 h (also as [N,40] ushort rows)
    float* agg   = (float*)carve((size_t)N_NODES * DHID * 4);
    float* als   = (float*)carve((size_t)N_NODES * NH * 4);
    float* ald   = (float*)carve((size_t)N_NODES * NH * 4);
    int* row_ptr = (int*)carve((size_t)(N_NODES + 1) * 4);
    int* csr_src = (int*)carve((size_t)N_EDGES * 4);
    uint2* part  = (uint2*)carve((size_t)N_EDGES * 8);
    int* bhist   = (int*)carve(PB * 4);
    int* bucket_base = (int*)carve((PB + 1) * 4);
    int* cursor  = (int*)carve(PB * 4);
    float* sums  = (float*)carve(256 * 4);
    float* sqs   = sums + 128;
    float* scale = (float*)carve(DHID * 4);
    float* shift = (float*)carve(DHID * 4);

    const float bs0 = 1.0f + 1.0f / 25.001f;
    const float bs1 = 1.0f + 0.5f / 25.001f;

    const int RT64 = (N_NODES + 63) / 64;      // 782
    const int G128B = RT64 * 2;                // 1564
    const int G40B = RT64;                     // 782
    const int AB = (N_NODES * 64 + 255) / 256; // 12500
    const int PARTB = (N_EDGES + 4095) / 4096; // 196

    // ---- bucketed CSR build ----
    hipMemsetAsync(bhist, 0, PB * 4, stream);
    bucket_hist_kernel<<<400, 256, 0, stream>>>(dstv, bhist);
    bucket_scan_kernel<<<1, PB, 0, stream>>>(bhist, bucket_base, cursor);
    partition_kernel<<<PARTB, 256, 0, stream>>>(srcv, dstv, cursor, part);
    bucket_csr_kernel<<<PB, 256, 0, stream>>>(part, bucket_base, row_ptr, csr_src);

    // ---- layer 0 ----
    gemm128_kernel<<<G128B, 256, 0, stream>>>(x, W0, as0, ad0, nullptr, nullptr, 1.f, 0, h_bf, als, ald);
    agg128_kernel<<<AB, 256, 0, stream>>>(row_ptr, csr_src, h_bf, als, ald, b0, agg);
    hipMemsetAsync(sums, 0, 256 * 4, stream);
    bn_stats_kernel<<<500, 256, 0, stream>>>(agg, sums, sqs);
    bn_finalize_kernel<<<1, 128, 0, stream>>>(sums, sqs, g_bn0, be_bn0, scale, shift);

    // ---- layer 1 (BN0+ELU fused into gemm staging) ----
    gemm128_kernel<<<G128B, 256, 0, stream>>>(agg, W1, as1, ad1, scale, shift, bs0, 1, h_bf, als, ald);
    agg128_kernel<<<AB, 256, 0, stream>>>(row_ptr, csr_src, h_bf, als, ald, b1, agg);
    hipMemsetAsync(sums, 0, 256 * 4, stream);
    bn_stats_kernel<<<500, 256, 0, stream>>>(agg, sums, sqs);
    bn_finalize_kernel<<<1, 128, 0, stream>>>(sums, sqs, g_bn1, be_bn1, scale, shift);

    // ---- layer 2 (BN1+ELU fused) + log_softmax ----
    gemm40_kernel<<<G40B, 256, 0, stream>>>(agg, W2, as2, ad2, scale, shift, bs1, (unsigned short*)h_bf, als, ald);
    agg40_kernel<<<AB, 256, 0, stream>>>(row_ptr, csr_src, h_bf, als, ald, b2, out);
}

// Round 9
// 306.625 us; speedup vs baseline: 1.8624x; 1.0253x over previous
//
#include <hip/hip_runtime.h>
#include <math.h>

#define N_NODES 50000
#define N_EDGES 800000
#define DIN 128
#define DHID 128   /* H*HID */
#define NH 4
#define HID 32
#define DOUT 40

#define PB 128      /* dst buckets */
#define NPB 391     /* nodes per bucket: 391*128 = 50048 >= 50000 */

typedef __fp16 fp16x2 __attribute__((ext_vector_type(2)));

static __device__ __forceinline__ float lrelu(float x) { return x > 0.f ? x : 0.2f * x; }

static __device__ __forceinline__ float sel4(int h, float a, float b, float c, float d) {
    float ab = (h & 1) ? b : a;
    float cd = (h & 1) ? d : c;
    return (h & 2) ? cd : ab;
}

// pack two floats to f16x2 (v_cvt_pkrtz_f16_f32, single instruction)
static __device__ __forceinline__ unsigned int pkh(float a, float b) {
    union { fp16x2 h2; unsigned int u; } cv;
    cv.h2 = __builtin_amdgcn_cvt_pkrtz(a, b);
    return cv.u;
}
static __device__ __forceinline__ unsigned short f2h(float a) {
    union { _Float16 h; unsigned short s; } cv;
    cv.h = (_Float16)a;
    return cv.s;
}

// acc[0..7] += p * f16x8(w)  — unpack via f16->f32 (fuses to v_fma_mix)
static __device__ __forceinline__ void fma8(float* acc, uint4 w, float p) {
    union { unsigned int u; _Float16 h[2]; } c0, c1, c2, c3;
    c0.u = w.x; c1.u = w.y; c2.u = w.z; c3.u = w.w;
    acc[0] = fmaf((float)c0.h[0], p, acc[0]);
    acc[1] = fmaf((float)c0.h[1], p, acc[1]);
    acc[2] = fmaf((float)c1.h[0], p, acc[2]);
    acc[3] = fmaf((float)c1.h[1], p, acc[3]);
    acc[4] = fmaf((float)c2.h[0], p, acc[4]);
    acc[5] = fmaf((float)c2.h[1], p, acc[5]);
    acc[6] = fmaf((float)c3.h[0], p, acc[6]);
    acc[7] = fmaf((float)c3.h[1], p, acc[7]);
}

static __device__ __forceinline__ float4 bnelu4(float4 x, float4 sc, float4 sh, float bs) {
    float y0 = fmaf(x.x, sc.x, sh.x);
    float y1 = fmaf(x.y, sc.y, sh.y);
    float y2 = fmaf(x.z, sc.z, sh.z);
    float y3 = fmaf(x.w, sc.w, sh.w);
    y0 = (y0 > 0.f ? y0 : __expf(y0) - 1.f) * bs;
    y1 = (y1 > 0.f ? y1 : __expf(y1) - 1.f) * bs;
    y2 = (y2 > 0.f ? y2 : __expf(y2) - 1.f) * bs;
    y3 = (y3 > 0.f ? y3 : __expf(y3) - 1.f) * bs;
    return {y0, y1, y2, y3};
}

// ================= bucketed CSR build (XCD-local writes) =================
__global__ __launch_bounds__(256) void bucket_hist_kernel(const int* __restrict__ dstv, int* __restrict__ bhist) {
    __shared__ int h[PB];
    if (threadIdx.x < PB) h[threadIdx.x] = 0;
    __syncthreads();
    for (int i = blockIdx.x * blockDim.x + threadIdx.x; i < N_EDGES; i += gridDim.x * blockDim.x)
        atomicAdd(&h[(unsigned)dstv[i] / NPB], 1);
    __syncthreads();
    if (threadIdx.x < PB) atomicAdd(&bhist[threadIdx.x], h[threadIdx.x]);
}

__global__ __launch_bounds__(128) void bucket_scan_kernel(const int* __restrict__ bhist,
                                                          int* __restrict__ bucket_base, int* __restrict__ cursor) {
    __shared__ int sA[PB], sB[PB];
    int t = threadIdx.x;
    sA[t] = bhist[t];
    __syncthreads();
    int* s = sA; int* d2 = sB;
    for (int off = 1; off < PB; off <<= 1) {
        d2[t] = s[t] + (t >= off ? s[t - off] : 0);
        __syncthreads();
        int* tmp = s; s = d2; d2 = tmp;
    }
    int excl = s[t] - bhist[t];
    bucket_base[t] = excl;
    cursor[t] = excl;
    if (t == PB - 1) bucket_base[PB] = s[t];
}

__global__ __launch_bounds__(256) void partition_kernel(const int* __restrict__ srcv, const int* __restrict__ dstv,
                                                        int* __restrict__ cursor, uint2* __restrict__ part) {
    __shared__ uint2 rec[2048];
    __shared__ int cnt[PB], lofs[PB], gbase[PB];
    __shared__ int sA[PB], sB[PB];
    __shared__ int tot_s;
    const int t = threadIdx.x;
    const int base0 = blockIdx.x * 4096;
    for (int round = 0; round < 2; ++round) {
        int rbase = base0 + round * 2048;
        if (t < PB) cnt[t] = 0;
        __syncthreads();
        int myb[8]; int myr[8]; uint2 myrec[8];
#pragma unroll
        for (int i = 0; i < 8; ++i) {
            int e = rbase + i * 256 + t;
            bool valid = e < N_EDGES;
            int sv = valid ? srcv[e] : 0;
            int dv = valid ? dstv[e] : 0;
            myrec[i].x = (unsigned)sv;
            myrec[i].y = (unsigned)dv;
            int b = (unsigned)dv / NPB;
            myb[i] = valid ? b : -1;
            myr[i] = valid ? atomicAdd(&cnt[b], 1) : 0;
        }
        __syncthreads();
        if (t < PB) sA[t] = cnt[t];
        __syncthreads();
        int* s = sA; int* d2 = sB;
        for (int off = 1; off < PB; off <<= 1) {
            if (t < PB) d2[t] = s[t] + (t >= off ? s[t - off] : 0);
            __syncthreads();
            int* tmp = s; s = d2; d2 = tmp;
        }
        if (t < PB) {
            int c = cnt[t];
            lofs[t] = s[t] - c;
            gbase[t] = c > 0 ? atomicAdd(&cursor[t], c) : 0;
            if (t == PB - 1) tot_s = s[t];
        }
        __syncthreads();
#pragma unroll
        for (int i = 0; i < 8; ++i)
            if (myb[i] >= 0) rec[lofs[myb[i]] + myr[i]] = myrec[i];
        __syncthreads();
        int tot = tot_s;
#pragma unroll
        for (int i = 0; i < 8; ++i) {
            int lp = i * 256 + t;
            if (lp < tot) {
                uint2 r = rec[lp];
                int b = r.y / NPB;
                part[gbase[b] + (lp - lofs[b])] = r;
            }
        }
        __syncthreads();
    }
}

__global__ __launch_bounds__(256) void bucket_csr_kernel(const uint2* __restrict__ part, const int* __restrict__ bucket_base,
                                                         int* __restrict__ row_ptr, int* __restrict__ csr_src) {
    __shared__ int hist[512], sA[512], sB[512], cur[NPB];
    const int b = blockIdx.x, t = threadIdx.x;
    const int base = bucket_base[b];
    const int n = bucket_base[b + 1] - base;
    hist[t] = 0; hist[t + 256] = 0;
    __syncthreads();
    for (int i = t; i < n; i += 256)
        atomicAdd(&hist[part[base + i].y - b * NPB], 1);
    __syncthreads();
    sA[t] = hist[t]; sA[t + 256] = hist[t + 256];
    __syncthreads();
    int* s = sA; int* d2 = sB;
    for (int off = 1; off < 512; off <<= 1) {
        d2[t] = s[t] + (t >= off ? s[t - off] : 0);
        int u = t + 256;
        d2[u] = s[u] + (u >= off ? s[u - off] : 0);
        __syncthreads();
        int* tmp = s; s = d2; d2 = tmp;
    }
    for (int j = t; j < NPB; j += 256) {
        int node = b * NPB + j;
        int excl = s[j] - hist[j];
        if (node < N_NODES) row_ptr[node] = base + excl;
        cur[j] = excl;
    }
    if (b == PB - 1 && t == 0) row_ptr[N_NODES] = N_EDGES;
    __syncthreads();
    for (int i = t; i < n; i += 256) {
        uint2 r = part[base + i];
        int loc = r.y - b * NPB;
        int p = atomicAdd(&cur[loc], 1);
        csr_src[base + p] = (int)r.x;
    }
}

// ---------------- gemm128: [N,128]@[128,128] (+ fused BN/ELU on X) + als/ald epilogue ----------------
__global__ __launch_bounds__(256) void gemm128_kernel(
    const float* __restrict__ X, const float* __restrict__ W,
    const float* __restrict__ a_src, const float* __restrict__ a_dst,
    const float* __restrict__ scale, const float* __restrict__ shift, float bscale, int apply_bn,
    unsigned int* __restrict__ Hout, float* __restrict__ als, float* __restrict__ ald) {
    __shared__ float Xs[32][68];
    __shared__ float Ws[32][64];
    const int t = threadIdx.x;
    const int tx = t & 15, ty = t >> 4;
    const int r0 = (blockIdx.x >> 1) * 64;
    const int c0 = (blockIdx.x & 1) * 64;
    const int sr = t >> 2, sa = t & 3;
    const int wk = t >> 4, wc = (t & 15) * 4;

    int gr = r0 + sr; gr = gr < N_NODES ? gr : N_NODES - 1;
    const float* Xrow = X + (size_t)gr * 128;
    float4 xpreA = *(const float4*)(Xrow + 8 * sa);
    float4 xpreB = *(const float4*)(Xrow + 8 * sa + 4);
    if (apply_bn) {
        xpreA = bnelu4(xpreA, *(const float4*)(scale + 8 * sa), *(const float4*)(shift + 8 * sa), bscale);
        xpreB = bnelu4(xpreB, *(const float4*)(scale + 8 * sa + 4), *(const float4*)(shift + 8 * sa + 4), bscale);
    }
    float4 wpreA = *(const float4*)(W + (size_t)wk * 128 + c0 + wc);
    float4 wpreB = *(const float4*)(W + (size_t)(wk + 16) * 128 + c0 + wc);

    float acc[4][4];
#pragma unroll
    for (int i = 0; i < 4; ++i)
#pragma unroll
        for (int c = 0; c < 4; ++c) acc[i][c] = 0.f;

    for (int step = 0; step < 4; ++step) {
        __syncthreads();
        Xs[8 * sa + 0][sr] = xpreA.x;
        Xs[8 * sa + 1][sr] = xpreA.y;
        Xs[8 * sa + 2][sr] = xpreA.z;
        Xs[8 * sa + 3][sr] = xpreA.w;
        Xs[8 * sa + 4][sr] = xpreB.x;
        Xs[8 * sa + 5][sr] = xpreB.y;
        Xs[8 * sa + 6][sr] = xpreB.z;
        Xs[8 * sa + 7][sr] = xpreB.w;
        *(float4*)&Ws[wk][wc] = wpreA;
        *(float4*)&Ws[wk + 16][wc] = wpreB;
        if (step < 3) {
            int k0 = (step + 1) * 32;
            xpreA = *(const float4*)(Xrow + k0 + 8 * sa);
            xpreB = *(const float4*)(Xrow + k0 + 8 * sa + 4);
            if (apply_bn) {
                xpreA = bnelu4(xpreA, *(const float4*)(scale + k0 + 8 * sa), *(const float4*)(shift + k0 + 8 * sa), bscale);
                xpreB = bnelu4(xpreB, *(const float4*)(scale + k0 + 8 * sa + 4), *(const float4*)(shift + k0 + 8 * sa + 4), bscale);
            }
            wpreA = *(const float4*)(W + (size_t)(k0 + wk) * 128 + c0 + wc);
            wpreB = *(const float4*)(W + (size_t)(k0 + wk + 16) * 128 + c0 + wc);
        }
        __syncthreads();
#pragma unroll
        for (int kk = 0; kk < 32; ++kk) {
            float4 xv = *(const float4*)&Xs[kk][4 * ty];
            float4 wv = *(const float4*)&Ws[kk][4 * tx];
            float xr[4] = {xv.x, xv.y, xv.z, xv.w};
            float wr[4] = {wv.x, wv.y, wv.z, wv.w};
#pragma unroll
            for (int i = 0; i < 4; ++i)
#pragma unroll
                for (int c = 0; c < 4; ++c)
                    acc[i][c] = fmaf(xr[i], wr[c], acc[i][c]);
        }
    }
    const int head = (c0 >> 5) + (tx >> 3);
    float asv[4], adv[4];
#pragma unroll
    for (int c = 0; c < 4; ++c) {
        asv[c] = a_src[(head & 1) * 32 + (4 * tx + c) % 32 + (head >> 1) * 64];
        adv[c] = a_dst[(head & 1) * 32 + (4 * tx + c) % 32 + (head >> 1) * 64];
    }
#pragma unroll
    for (int i = 0; i < 4; ++i) {
        int r = r0 + 4 * ty + i;
        bool valid = r < N_NODES;
        if (valid) {
            uint2 pk = {pkh(acc[i][0], acc[i][1]), pkh(acc[i][2], acc[i][3])};
            *(uint2*)(Hout + (size_t)r * 64 + (c0 >> 1) + 2 * tx) = pk;
        }
        float ps = 0.f, pd = 0.f;
#pragma unroll
        for (int c = 0; c < 4; ++c) {
            ps = fmaf(acc[i][c], asv[c], ps);
            pd = fmaf(acc[i][c], adv[c], pd);
        }
#pragma unroll
        for (int off = 1; off < 8; off <<= 1) {
            ps += __shfl_xor(ps, off);
            pd += __shfl_xor(pd, off);
        }
        if (valid && (tx & 7) == 0) {
            als[r * 4 + head] = ps;
            ald[r * 4 + head] = pd;
        }
    }
}

// ---------------- gemm40: [N,128]@[128,40] (+ fused BN/ELU on X) + als/ald, f16 h out ----------------
__global__ __launch_bounds__(256) void gemm40_kernel(
    const float* __restrict__ X, const float* __restrict__ W,
    const float* __restrict__ a_src, const float* __restrict__ a_dst,
    const float* __restrict__ scale, const float* __restrict__ shift, float bscale,
    unsigned short* __restrict__ Hout, float* __restrict__ als, float* __restrict__ ald) {
    __shared__ float Xs[64][36];
    __shared__ float Ws[40][36];
    const int t = threadIdx.x;
    const int tx = t & 7, ty = t >> 3;
    const int r0 = blockIdx.x * 64;
    const int sr = t >> 2, sa = t & 3;

    int gr = r0 + sr; gr = gr < N_NODES ? gr : N_NODES - 1;
    const float* Xrow = X + (size_t)gr * 128;
    float4 xpreA = bnelu4(*(const float4*)(Xrow + 8 * sa),
                          *(const float4*)(scale + 8 * sa), *(const float4*)(shift + 8 * sa), bscale);
    float4 xpreB = bnelu4(*(const float4*)(Xrow + 8 * sa + 4),
                          *(const float4*)(scale + 8 * sa + 4), *(const float4*)(shift + 8 * sa + 4), bscale);
    float wpre[5];
#pragma unroll
    for (int i = 0; i < 5; ++i) wpre[i] = W[t + 256 * i];

    float acc[2][5];
#pragma unroll
    for (int i = 0; i < 2; ++i)
#pragma unroll
        for (int j = 0; j < 5; ++j) acc[i][j] = 0.f;

    for (int step = 0; step < 4; ++step) {
        __syncthreads();
        *(float4*)&Xs[sr][8 * sa] = xpreA;
        *(float4*)&Xs[sr][8 * sa + 4] = xpreB;
#pragma unroll
        for (int i = 0; i < 5; ++i) {
            int idx = t + 256 * i;
            Ws[idx % 40][idx / 40] = wpre[i];
        }
        if (step < 3) {
            int k0 = (step + 1) * 32;
            xpreA = bnelu4(*(const float4*)(Xrow + k0 + 8 * sa),
                           *(const float4*)(scale + k0 + 8 * sa), *(const float4*)(shift + k0 + 8 * sa), bscale);
            xpreB = bnelu4(*(const float4*)(Xrow + k0 + 8 * sa + 4),
                           *(const float4*)(scale + k0 + 8 * sa + 4), *(const float4*)(shift + k0 + 8 * sa + 4), bscale);
#pragma unroll
            for (int i = 0; i < 5; ++i) wpre[i] = W[k0 * 40 + t + 256 * i];
        }
        __syncthreads();
#pragma unroll
        for (int kk4 = 0; kk4 < 8; ++kk4) {
            float4 xa = *(const float4*)&Xs[2 * ty][4 * kk4];
            float4 xb = *(const float4*)&Xs[2 * ty + 1][4 * kk4];
#pragma unroll
            for (int j = 0; j < 5; ++j) {
                float4 wv = *(const float4*)&Ws[tx + 8 * j][4 * kk4];
                acc[0][j] = fmaf(xa.x, wv.x, acc[0][j]);
                acc[0][j] = fmaf(xa.y, wv.y, acc[0][j]);
                acc[0][j] = fmaf(xa.z, wv.z, acc[0][j]);
                acc[0][j] = fmaf(xa.w, wv.w, acc[0][j]);
                acc[1][j] = fmaf(xb.x, wv.x, acc[1][j]);
                acc[1][j] = fmaf(xb.y, wv.y, acc[1][j]);
                acc[1][j] = fmaf(xb.z, wv.z, acc[1][j]);
                acc[1][j] = fmaf(xb.w, wv.w, acc[1][j]);
            }
        }
    }
    float asv[5], adv[5];
#pragma unroll
    for (int j = 0; j < 5; ++j) {
        asv[j] = a_src[tx + 8 * j];
        adv[j] = a_dst[tx + 8 * j];
    }
#pragma unroll
    for (int i = 0; i < 2; ++i) {
        int r = r0 + 2 * ty + i;
        bool valid = r < N_NODES;
        if (valid) {
#pragma unroll
            for (int j = 0; j < 5; ++j)
                Hout[(size_t)r * 40 + tx + 8 * j] = f2h(acc[i][j]);
        }
        float ps = 0.f, pd = 0.f;
#pragma unroll
        for (int j = 0; j < 5; ++j) {
            ps = fmaf(acc[i][j], asv[j], ps);
            pd = fmaf(acc[i][j], adv[j], pd);
        }
#pragma unroll
        for (int off = 1; off < 8; off <<= 1) {
            ps += __shfl_xor(ps, off);
            pd += __shfl_xor(pd, off);
        }
        if (valid && tx == 0) {
            als[r] = ps;
            ald[r] = pd;
        }
    }
}

// ---------------- agg128: one wave per node; no-max softmax (exp(e) safe in f32) ----------------
__global__ __launch_bounds__(256) void agg128_kernel(
    const int* __restrict__ row_ptr, const int* __restrict__ csr_src,
    const unsigned int* __restrict__ Ht, const float* __restrict__ als, const float* __restrict__ ald,
    const float* __restrict__ bias, float* __restrict__ out) {
    __shared__ float s_p[4][256];
    __shared__ int s_u[4][64];
    int v = (blockIdx.x * blockDim.x + threadIdx.x) >> 6;
    v = __builtin_amdgcn_readfirstlane(v);
    int lane = threadIdx.x & 63;
    int wslot = threadIdx.x >> 6;
    if (v >= N_NODES) return;
    int beg = row_ptr[v], end = row_ptr[v + 1];
    float4 ad4 = *(const float4*)(ald + (size_t)v * 4);
    const int g = lane >> 4;     // gather group: edge i+g
    const int li = lane & 15;    // owns feats 8li..8li+7 (uints 4li..4li+3), head li>>2
    const int hh = li >> 2;
    float t0 = 0.f, t1 = 0.f, t2 = 0.f, t3 = 0.f;
    float acc[8];
#pragma unroll
    for (int j = 0; j < 8; ++j) acc[j] = 0.f;

    for (int cbeg = beg; cbeg < end; cbeg += 64) {
        int cnt = min(64, end - cbeg);
        bool act = lane < cnt;
        int u = act ? csr_src[cbeg + lane] : 0;
        float p0, p1, p2, p3;
        if (act) {
            float4 s4 = *(const float4*)(als + (size_t)u * 4);
            p0 = __expf(lrelu(s4.x + ad4.x));
            p1 = __expf(lrelu(s4.y + ad4.y));
            p2 = __expf(lrelu(s4.z + ad4.z));
            p3 = __expf(lrelu(s4.w + ad4.w));
        } else {
            p0 = p1 = p2 = p3 = 0.f;
        }
        float q0 = p0, q1 = p1, q2 = p2, q3 = p3;
#pragma unroll
        for (int off = 1; off < 64; off <<= 1) {
            q0 += __shfl_xor(q0, off);
            q1 += __shfl_xor(q1, off);
            q2 += __shfl_xor(q2, off);
            q3 += __shfl_xor(q3, off);
        }
        t0 += q0;
        t1 += q1;
        t2 += q2;
        t3 += q3;
        s_u[wslot][lane] = u;
        float4 pv = {p0, p1, p2, p3};
        *(float4*)&s_p[wslot][lane * 4] = pv;
        // 4-edge-parallel gather (groups g=0..3 take edges i+g); over-read safe (p=0, u=0)
        for (int i = 0; i < cnt; i += 4) {
            int e = i + g;
            int uu = s_u[wslot][e];
            float p = s_p[wslot][e * 4 + hh];
            uint4 w4 = *(const uint4*)(Ht + (size_t)uu * 64 + li * 4);
            fma8(acc, w4, p);
        }
    }
#pragma unroll
    for (int j = 0; j < 8; ++j) {
        acc[j] += __shfl_xor(acc[j], 16);
        acc[j] += __shfl_xor(acc[j], 32);
    }
    float th = sel4(hh, t0, t1, t2, t3);
    float inv = 1.f / (th + 1e-16f);
    if (g == 0) {
        float4 b0 = *(const float4*)(bias + 8 * li);
        float4 b1 = *(const float4*)(bias + 8 * li + 4);
        float4 o0 = {acc[0] * inv + b0.x, acc[1] * inv + b0.y, acc[2] * inv + b0.z, acc[3] * inv + b0.w};
        float4 o1 = {acc[4] * inv + b1.x, acc[5] * inv + b1.y, acc[6] * inv + b1.z, acc[7] * inv + b1.w};
        *(float4*)(out + (size_t)v * DHID + 8 * li) = o0;
        *(float4*)(out + (size_t)v * DHID + 8 * li + 4) = o1;
    }
}

// ---------------- agg40: one wave per node; no-max softmax + log_softmax ----------------
__global__ __launch_bounds__(256) void agg40_kernel(
    const int* __restrict__ row_ptr, const int* __restrict__ csr_src,
    const unsigned int* __restrict__ HtU, const float* __restrict__ als, const float* __restrict__ ald,
    const float* __restrict__ bias, float* __restrict__ out) {
    __shared__ float s_p[4][64];
    __shared__ int s_u[4][64];
    int v = (blockIdx.x * blockDim.x + threadIdx.x) >> 6;
    v = __builtin_amdgcn_readfirstlane(v);
    int lane = threadIdx.x & 63;
    int wslot = threadIdx.x >> 6;
    if (v >= N_NODES) return;
    int beg = row_ptr[v], end = row_ptr[v + 1];
    float adv = ald[v];
    const int g = lane >> 5;
    const int li = lane & 31;
    const bool own = li < 20;
    float t = 0.f;
    float a0 = 0.f, a1 = 0.f;
    for (int cbeg = beg; cbeg < end; cbeg += 64) {
        int cnt = min(64, end - cbeg);
        bool act = lane < cnt;
        int u = act ? csr_src[cbeg + lane] : 0;
        float p = act ? __expf(lrelu(als[u] + adv)) : 0.f;
        float q = p;
#pragma unroll
        for (int off = 1; off < 64; off <<= 1) q += __shfl_xor(q, off);
        t += q;
        s_u[wslot][lane] = u;
        s_p[wslot][lane] = p;
        for (int i = 0; i < cnt; i += 2) {
            int e2 = i + g;
            int uu = s_u[wslot][e2];
            float pp = s_p[wslot][e2];
            unsigned int w = own ? HtU[(size_t)uu * 20 + li] : 0u;
            union { unsigned int u; _Float16 h[2]; } cv;
            cv.u = w;
            a0 = fmaf((float)cv.h[0], pp, a0);
            a1 = fmaf((float)cv.h[1], pp, a1);
        }
    }
    a0 += __shfl_xor(a0, 32);
    a1 += __shfl_xor(a1, 32);
    float inv = 1.f / (t + 1e-16f);
    float z0 = own ? (a0 * inv + bias[2 * li]) : -1e30f;
    float z1 = own ? (a1 * inv + bias[2 * li + 1]) : -1e30f;
    float zm = fmaxf(z0, z1);
#pragma unroll
    for (int off = 1; off < 32; off <<= 1) zm = fmaxf(zm, __shfl_xor(zm, off));
    float se = own ? (__expf(z0 - zm) + __expf(z1 - zm)) : 0.f;
#pragma unroll
    for (int off = 1; off < 32; off <<= 1) se += __shfl_xor(se, off);
    float ls = zm + logf(se);
    if (own && g == 0) {
        float2 o = {z0 - ls, z1 - ls};
        *(float2*)(out + (size_t)v * DOUT + 2 * li) = o;
    }
}

// ---------------- batch norm stats ----------------
__global__ __launch_bounds__(256) void bn_stats_kernel(const float* __restrict__ X,
                                                       float* __restrict__ sums, float* __restrict__ sqs) {
    int f = threadIdx.x & 127;
    int sub = threadIdx.x >> 7;
    int rbeg = blockIdx.x * 100;
    float s = 0.f, q = 0.f;
    for (int r = rbeg + sub; r < rbeg + 100; r += 2) {
        float x = X[(size_t)r * DHID + f];
        s += x;
        q += x * x;
    }
    __shared__ float ls[256], lq[256];
    ls[threadIdx.x] = s;
    lq[threadIdx.x] = q;
    __syncthreads();
    if (threadIdx.x < 128) {
        s = ls[threadIdx.x] + ls[threadIdx.x + 128];
        q = lq[threadIdx.x] + lq[threadIdx.x + 128];
        atomicAdd(&sums[f], s);
        atomicAdd(&sqs[f], q);
    }
}

__global__ void bn_finalize_kernel(const float* __restrict__ sums, const float* __restrict__ sqs,
                                   const float* __restrict__ gamma, const float* __restrict__ beta,
                                   float* __restrict__ scale, float* __restrict__ shift) {
    int f = threadIdx.x;
    if (f < DHID) {
        float mu = sums[f] * (1.f / N_NODES);
        float var = sqs[f] * (1.f / N_NODES) - mu * mu;
        float sc = gamma[f] * rsqrtf(var + 1e-5f);
        scale[f] = sc;
        shift[f] = beta[f] - mu * sc;
    }
}

// ---------------- launch ----------------
extern "C" void kernel_launch(void* const* d_in, const int* in_sizes, int n_in,
                              void* d_out, int out_size, void* d_ws, size_t ws_size,
                              hipStream_t stream) {
    (void)in_sizes; (void)n_in; (void)out_size; (void)ws_size;
    const float* x = (const float*)d_in[0];
    const int* ei = (const int*)d_in[1];
    const float* W0 = (const float*)d_in[2];
    const float* as0 = (const float*)d_in[3];
    const float* ad0 = (const float*)d_in[4];
    const float* b0 = (const float*)d_in[5];
    const float* W1 = (const float*)d_in[6];
    const float* as1 = (const float*)d_in[7];
    const float* ad1 = (const float*)d_in[8];
    const float* b1 = (const float*)d_in[9];
    const float* W2 = (const float*)d_in[10];
    const float* as2 = (const float*)d_in[11];
    const float* ad2 = (const float*)d_in[12];
    const float* b2 = (const float*)d_in[13];
    const float* g_bn0 = (const float*)d_in[14];
    const float* be_bn0 = (const float*)d_in[15];
    const float* g_bn1 = (const float*)d_in[16];
    const float* be_bn1 = (const float*)d_in[17];
    float* out = (float*)d_out;

    const int* srcv = ei;
    const int* dstv = ei + N_EDGES;

    char* p = (char*)d_ws;
    auto carve = [&](size_t bytes) {
        char* q = p;
        p += (bytes + 255) & ~(size_t)255;
        return q;
    };
    unsigned int* h_bf = (unsigned int*)carve((size_t)N_NODES * 64 * 4);  // f16 h (also as [N,40] ushort rows)
    float* agg   = (float*)carve((size_t)N_NODES * DHID * 4);
    float* als   = (float*)carve((size_t)N_NODES * NH * 4);
    float* ald   = (float*)carve((size_t)N_NODES * NH * 4);
    int* row_ptr = (int*)carve((size_t)(N_NODES + 1) * 4);
    int* csr_src = (int*)carve((size_t)N_EDGES * 4);
    uint2* part  = (uint2*)carve((size_t)N_EDGES * 8);
    int* bhist   = (int*)carve(PB * 4);
    int* bucket_base = (int*)carve((PB + 1) * 4);
    int* cursor  = (int*)carve(PB * 4);
    float* sums  = (float*)carve(256 * 4);
    float* sqs   = sums + 128;
    float* scale = (float*)carve(DHID * 4);
    float* shift = (float*)carve(DHID * 4);

    const float bs0 = 1.0f + 1.0f / 25.001f;
    const float bs1 = 1.0f + 0.5f / 25.001f;

    const int RT64 = (N_NODES + 63) / 64;      // 782
    const int G128B = RT64 * 2;                // 1564
    const int G40B = RT64;                     // 782
    const int AB = (N_NODES * 64 + 255) / 256; // 12500
    const int PARTB = (N_EDGES + 4095) / 4096; // 196

    // ---- bucketed CSR build ----
    hipMemsetAsync(bhist, 0, PB * 4, stream);
    bucket_hist_kernel<<<400, 256, 0, stream>>>(dstv, bhist);
    bucket_scan_kernel<<<1, PB, 0, stream>>>(bhist, bucket_base, cursor);
    partition_kernel<<<PARTB, 256, 0, stream>>>(srcv, dstv, cursor, part);
    bucket_csr_kernel<<<PB, 256, 0, stream>>>(part, bucket_base, row_ptr, csr_src);

    // ---- layer 0 ----
    gemm128_kernel<<<G128B, 256, 0, stream>>>(x, W0, as0, ad0, nullptr, nullptr, 1.f, 0, h_bf, als, ald);
    agg128_kernel<<<AB, 256, 0, stream>>>(row_ptr, csr_src, h_bf, als, ald, b0, agg);
    hipMemsetAsync(sums, 0, 256 * 4, stream);
    bn_stats_kernel<<<500, 256, 0, stream>>>(agg, sums, sqs);
    bn_finalize_kernel<<<1, 128, 0, stream>>>(sums, sqs, g_bn0, be_bn0, scale, shift);

    // ---- layer 1 (BN0+ELU fused into gemm staging) ----
    gemm128_kernel<<<G128B, 256, 0, stream>>>(agg, W1, as1, ad1, scale, shift, bs0, 1, h_bf, als, ald);
    agg128_kernel<<<AB, 256, 0, stream>>>(row_ptr, csr_src, h_bf, als, ald, b1, agg);
    hipMemsetAsync(sums, 0, 256 * 4, stream);
    bn_stats_kernel<<<500, 256, 0, stream>>>(agg, sums, sqs);
    bn_finalize_kernel<<<1, 128, 0, stream>>>(sums, sqs, g_bn1, be_bn1, scale, shift);

    // ---- layer 2 (BN1+ELU fused) + log_softmax ----
    gemm40_kernel<<<G40B, 256, 0, stream>>>(agg, W2, as2, ad2, scale, shift, bs1, (unsigned short*)h_bf, als, ald);
    agg40_kernel<<<AB, 256, 0, stream>>>(row_ptr, csr_src, h_bf, als, ald, b2, out);
}

// Round 10
// 302.204 us; speedup vs baseline: 1.8897x; 1.0146x over previous
//
#include <hip/hip_runtime.h>
#include <math.h>

#define N_NODES 50000
#define N_EDGES 800000
#define DIN 128
#define DHID 128   /* H*HID */
#define NH 4
#define HID 32
#define DOUT 40

#define PB 128      /* dst buckets */
#define NPB 391     /* nodes per bucket: 391*128 = 50048 >= 50000 */

typedef __fp16 fp16x2 __attribute__((ext_vector_type(2)));

static __device__ __forceinline__ float lrelu(float x) { return x > 0.f ? x : 0.2f * x; }

// pack two floats to f16x2 (v_cvt_pkrtz_f16_f32, single instruction)
static __device__ __forceinline__ unsigned int pkh(float a, float b) {
    union { fp16x2 h2; unsigned int u; } cv;
    cv.h2 = __builtin_amdgcn_cvt_pkrtz(a, b);
    return cv.u;
}
static __device__ __forceinline__ unsigned short f2h(float a) {
    union { _Float16 h; unsigned short s; } cv;
    cv.h = (_Float16)a;
    return cv.s;
}

// acc[0..7] += p * f16x8(w)  — unpack via f16->f32 (fuses to v_fma_mix)
static __device__ __forceinline__ void fma8(float* acc, uint4 w, float p) {
    union { unsigned int u; _Float16 h[2]; } c0, c1, c2, c3;
    c0.u = w.x; c1.u = w.y; c2.u = w.z; c3.u = w.w;
    acc[0] = fmaf((float)c0.h[0], p, acc[0]);
    acc[1] = fmaf((float)c0.h[1], p, acc[1]);
    acc[2] = fmaf((float)c1.h[0], p, acc[2]);
    acc[3] = fmaf((float)c1.h[1], p, acc[3]);
    acc[4] = fmaf((float)c2.h[0], p, acc[4]);
    acc[5] = fmaf((float)c2.h[1], p, acc[5]);
    acc[6] = fmaf((float)c3.h[0], p, acc[6]);
    acc[7] = fmaf((float)c3.h[1], p, acc[7]);
}

static __device__ __forceinline__ float4 bnelu4(float4 x, float4 sc, float4 sh, float bs) {
    float y0 = fmaf(x.x, sc.x, sh.x);
    float y1 = fmaf(x.y, sc.y, sh.y);
    float y2 = fmaf(x.z, sc.z, sh.z);
    float y3 = fmaf(x.w, sc.w, sh.w);
    y0 = (y0 > 0.f ? y0 : __expf(y0) - 1.f) * bs;
    y1 = (y1 > 0.f ? y1 : __expf(y1) - 1.f) * bs;
    y2 = (y2 > 0.f ? y2 : __expf(y2) - 1.f) * bs;
    y3 = (y3 > 0.f ? y3 : __expf(y3) - 1.f) * bs;
    return {y0, y1, y2, y3};
}

// ================= bucketed CSR build (XCD-local writes) =================
__global__ __launch_bounds__(256) void bucket_hist_kernel(const int* __restrict__ dstv, int* __restrict__ bhist) {
    __shared__ int h[PB];
    if (threadIdx.x < PB) h[threadIdx.x] = 0;
    __syncthreads();
    for (int i = blockIdx.x * blockDim.x + threadIdx.x; i < N_EDGES; i += gridDim.x * blockDim.x)
        atomicAdd(&h[(unsigned)dstv[i] / NPB], 1);
    __syncthreads();
    if (threadIdx.x < PB) atomicAdd(&bhist[threadIdx.x], h[threadIdx.x]);
}

__global__ __launch_bounds__(128) void bucket_scan_kernel(const int* __restrict__ bhist,
                                                          int* __restrict__ bucket_base, int* __restrict__ cursor) {
    __shared__ int sA[PB], sB[PB];
    int t = threadIdx.x;
    sA[t] = bhist[t];
    __syncthreads();
    int* s = sA; int* d2 = sB;
    for (int off = 1; off < PB; off <<= 1) {
        d2[t] = s[t] + (t >= off ? s[t - off] : 0);
        __syncthreads();
        int* tmp = s; s = d2; d2 = tmp;
    }
    int excl = s[t] - bhist[t];
    bucket_base[t] = excl;
    cursor[t] = excl;
    if (t == PB - 1) bucket_base[PB] = s[t];
}

__global__ __launch_bounds__(256) void partition_kernel(const int* __restrict__ srcv, const int* __restrict__ dstv,
                                                        int* __restrict__ cursor, uint2* __restrict__ part) {
    __shared__ uint2 rec[2048];
    __shared__ int cnt[PB], lofs[PB], gbase[PB];
    __shared__ int sA[PB], sB[PB];
    __shared__ int tot_s;
    const int t = threadIdx.x;
    const int base0 = blockIdx.x * 4096;
    for (int round = 0; round < 2; ++round) {
        int rbase = base0 + round * 2048;
        if (t < PB) cnt[t] = 0;
        __syncthreads();
        int myb[8]; int myr[8]; uint2 myrec[8];
#pragma unroll
        for (int i = 0; i < 8; ++i) {
            int e = rbase + i * 256 + t;
            bool valid = e < N_EDGES;
            int sv = valid ? srcv[e] : 0;
            int dv = valid ? dstv[e] : 0;
            myrec[i].x = (unsigned)sv;
            myrec[i].y = (unsigned)dv;
            int b = (unsigned)dv / NPB;
            myb[i] = valid ? b : -1;
            myr[i] = valid ? atomicAdd(&cnt[b], 1) : 0;
        }
        __syncthreads();
        if (t < PB) sA[t] = cnt[t];
        __syncthreads();
        int* s = sA; int* d2 = sB;
        for (int off = 1; off < PB; off <<= 1) {
            if (t < PB) d2[t] = s[t] + (t >= off ? s[t - off] : 0);
            __syncthreads();
            int* tmp = s; s = d2; d2 = tmp;
        }
        if (t < PB) {
            int c = cnt[t];
            lofs[t] = s[t] - c;
            gbase[t] = c > 0 ? atomicAdd(&cursor[t], c) : 0;
            if (t == PB - 1) tot_s = s[t];
        }
        __syncthreads();
#pragma unroll
        for (int i = 0; i < 8; ++i)
            if (myb[i] >= 0) rec[lofs[myb[i]] + myr[i]] = myrec[i];
        __syncthreads();
        int tot = tot_s;
#pragma unroll
        for (int i = 0; i < 8; ++i) {
            int lp = i * 256 + t;
            if (lp < tot) {
                uint2 r = rec[lp];
                int b = r.y / NPB;
                part[gbase[b] + (lp - lofs[b])] = r;
            }
        }
        __syncthreads();
    }
}

__global__ __launch_bounds__(256) void bucket_csr_kernel(const uint2* __restrict__ part, const int* __restrict__ bucket_base,
                                                         int* __restrict__ row_ptr, int* __restrict__ csr_src) {
    __shared__ int hist[512], sA[512], sB[512], cur[NPB];
    const int b = blockIdx.x, t = threadIdx.x;
    const int base = bucket_base[b];
    const int n = bucket_base[b + 1] - base;
    hist[t] = 0; hist[t + 256] = 0;
    __syncthreads();
    for (int i = t; i < n; i += 256)
        atomicAdd(&hist[part[base + i].y - b * NPB], 1);
    __syncthreads();
    sA[t] = hist[t]; sA[t + 256] = hist[t + 256];
    __syncthreads();
    int* s = sA; int* d2 = sB;
    for (int off = 1; off < 512; off <<= 1) {
        d2[t] = s[t] + (t >= off ? s[t - off] : 0);
        int u = t + 256;
        d2[u] = s[u] + (u >= off ? s[u - off] : 0);
        __syncthreads();
        int* tmp = s; s = d2; d2 = tmp;
    }
    for (int j = t; j < NPB; j += 256) {
        int node = b * NPB + j;
        int excl = s[j] - hist[j];
        if (node < N_NODES) row_ptr[node] = base + excl;
        cur[j] = excl;
    }
    if (b == PB - 1 && t == 0) row_ptr[N_NODES] = N_EDGES;
    __syncthreads();
    for (int i = t; i < n; i += 256) {
        uint2 r = part[base + i];
        int loc = r.y - b * NPB;
        int p = atomicAdd(&cur[loc], 1);
        csr_src[base + p] = (int)r.x;
    }
}

// ---------------- gemm128: [N,128]@[128,128] (+ fused BN/ELU on X) + als/ald epilogue ----------------
__global__ __launch_bounds__(256) void gemm128_kernel(
    const float* __restrict__ X, const float* __restrict__ W,
    const float* __restrict__ a_src, const float* __restrict__ a_dst,
    const float* __restrict__ scale, const float* __restrict__ shift, float bscale, int apply_bn,
    unsigned int* __restrict__ Hout, float* __restrict__ als, float* __restrict__ ald) {
    __shared__ float Xs[32][68];
    __shared__ float Ws[32][64];
    const int t = threadIdx.x;
    const int tx = t & 15, ty = t >> 4;
    const int r0 = (blockIdx.x >> 1) * 64;
    const int c0 = (blockIdx.x & 1) * 64;
    const int sr = t >> 2, sa = t & 3;
    const int wk = t >> 4, wc = (t & 15) * 4;

    int gr = r0 + sr; gr = gr < N_NODES ? gr : N_NODES - 1;
    const float* Xrow = X + (size_t)gr * 128;
    float4 xpreA = *(const float4*)(Xrow + 8 * sa);
    float4 xpreB = *(const float4*)(Xrow + 8 * sa + 4);
    if (apply_bn) {
        xpreA = bnelu4(xpreA, *(const float4*)(scale + 8 * sa), *(const float4*)(shift + 8 * sa), bscale);
        xpreB = bnelu4(xpreB, *(const float4*)(scale + 8 * sa + 4), *(const float4*)(shift + 8 * sa + 4), bscale);
    }
    float4 wpreA = *(const float4*)(W + (size_t)wk * 128 + c0 + wc);
    float4 wpreB = *(const float4*)(W + (size_t)(wk + 16) * 128 + c0 + wc);

    float acc[4][4];
#pragma unroll
    for (int i = 0; i < 4; ++i)
#pragma unroll
        for (int c = 0; c < 4; ++c) acc[i][c] = 0.f;

    for (int step = 0; step < 4; ++step) {
        __syncthreads();
        Xs[8 * sa + 0][sr] = xpreA.x;
        Xs[8 * sa + 1][sr] = xpreA.y;
        Xs[8 * sa + 2][sr] = xpreA.z;
        Xs[8 * sa + 3][sr] = xpreA.w;
        Xs[8 * sa + 4][sr] = xpreB.x;
        Xs[8 * sa + 5][sr] = xpreB.y;
        Xs[8 * sa + 6][sr] = xpreB.z;
        Xs[8 * sa + 7][sr] = xpreB.w;
        *(float4*)&Ws[wk][wc] = wpreA;
        *(float4*)&Ws[wk + 16][wc] = wpreB;
        if (step < 3) {
            int k0 = (step + 1) * 32;
            xpreA = *(const float4*)(Xrow + k0 + 8 * sa);
            xpreB = *(const float4*)(Xrow + k0 + 8 * sa + 4);
            if (apply_bn) {
                xpreA = bnelu4(xpreA, *(const float4*)(scale + k0 + 8 * sa), *(const float4*)(shift + k0 + 8 * sa), bscale);
                xpreB = bnelu4(xpreB, *(const float4*)(scale + k0 + 8 * sa + 4), *(const float4*)(shift + k0 + 8 * sa + 4), bscale);
            }
            wpreA = *(const float4*)(W + (size_t)(k0 + wk) * 128 + c0 + wc);
            wpreB = *(const float4*)(W + (size_t)(k0 + wk + 16) * 128 + c0 + wc);
        }
        __syncthreads();
#pragma unroll
        for (int kk = 0; kk < 32; ++kk) {
            float4 xv = *(const float4*)&Xs[kk][4 * ty];
            float4 wv = *(const float4*)&Ws[kk][4 * tx];
            float xr[4] = {xv.x, xv.y, xv.z, xv.w};
            float wr[4] = {wv.x, wv.y, wv.z, wv.w};
#pragma unroll
            for (int i = 0; i < 4; ++i)
#pragma unroll
                for (int c = 0; c < 4; ++c)
                    acc[i][c] = fmaf(xr[i], wr[c], acc[i][c]);
        }
    }
    const int head = (c0 >> 5) + (tx >> 3);
    float asv[4], adv[4];
#pragma unroll
    for (int c = 0; c < 4; ++c) {
        asv[c] = a_src[(head & 1) * 32 + (4 * tx + c) % 32 + (head >> 1) * 64];
        adv[c] = a_dst[(head & 1) * 32 + (4 * tx + c) % 32 + (head >> 1) * 64];
    }
#pragma unroll
    for (int i = 0; i < 4; ++i) {
        int r = r0 + 4 * ty + i;
        bool valid = r < N_NODES;
        if (valid) {
            uint2 pk = {pkh(acc[i][0], acc[i][1]), pkh(acc[i][2], acc[i][3])};
            *(uint2*)(Hout + (size_t)r * 64 + (c0 >> 1) + 2 * tx) = pk;
        }
        float ps = 0.f, pd = 0.f;
#pragma unroll
        for (int c = 0; c < 4; ++c) {
            ps = fmaf(acc[i][c], asv[c], ps);
            pd = fmaf(acc[i][c], adv[c], pd);
        }
#pragma unroll
        for (int off = 1; off < 8; off <<= 1) {
            ps += __shfl_xor(ps, off);
            pd += __shfl_xor(pd, off);
        }
        if (valid && (tx & 7) == 0) {
            als[r * 4 + head] = ps;
            ald[r * 4 + head] = pd;
        }
    }
}

// ---------------- gemm40: [N,128]@[128,40] (+ fused BN/ELU on X) + als/ald, f16 h out ----------------
__global__ __launch_bounds__(256) void gemm40_kernel(
    const float* __restrict__ X, const float* __restrict__ W,
    const float* __restrict__ a_src, const float* __restrict__ a_dst,
    const float* __restrict__ scale, const float* __restrict__ shift, float bscale,
    unsigned short* __restrict__ Hout, float* __restrict__ als, float* __restrict__ ald) {
    __shared__ float Xs[64][36];
    __shared__ float Ws[40][36];
    const int t = threadIdx.x;
    const int tx = t & 7, ty = t >> 3;
    const int r0 = blockIdx.x * 64;
    const int sr = t >> 2, sa = t & 3;

    int gr = r0 + sr; gr = gr < N_NODES ? gr : N_NODES - 1;
    const float* Xrow = X + (size_t)gr * 128;
    float4 xpreA = bnelu4(*(const float4*)(Xrow + 8 * sa),
                          *(const float4*)(scale + 8 * sa), *(const float4*)(shift + 8 * sa), bscale);
    float4 xpreB = bnelu4(*(const float4*)(Xrow + 8 * sa + 4),
                          *(const float4*)(scale + 8 * sa + 4), *(const float4*)(shift + 8 * sa + 4), bscale);
    float wpre[5];
#pragma unroll
    for (int i = 0; i < 5; ++i) wpre[i] = W[t + 256 * i];

    float acc[2][5];
#pragma unroll
    for (int i = 0; i < 2; ++i)
#pragma unroll
        for (int j = 0; j < 5; ++j) acc[i][j] = 0.f;

    for (int step = 0; step < 4; ++step) {
        __syncthreads();
        *(float4*)&Xs[sr][8 * sa] = xpreA;
        *(float4*)&Xs[sr][8 * sa + 4] = xpreB;
#pragma unroll
        for (int i = 0; i < 5; ++i) {
            int idx = t + 256 * i;
            Ws[idx % 40][idx / 40] = wpre[i];
        }
        if (step < 3) {
            int k0 = (step + 1) * 32;
            xpreA = bnelu4(*(const float4*)(Xrow + k0 + 8 * sa),
                           *(const float4*)(scale + k0 + 8 * sa), *(const float4*)(shift + k0 + 8 * sa), bscale);
            xpreB = bnelu4(*(const float4*)(Xrow + k0 + 8 * sa + 4),
                           *(const float4*)(scale + k0 + 8 * sa + 4), *(const float4*)(shift + k0 + 8 * sa + 4), bscale);
#pragma unroll
            for (int i = 0; i < 5; ++i) wpre[i] = W[k0 * 40 + t + 256 * i];
        }
        __syncthreads();
#pragma unroll
        for (int kk4 = 0; kk4 < 8; ++kk4) {
            float4 xa = *(const float4*)&Xs[2 * ty][4 * kk4];
            float4 xb = *(const float4*)&Xs[2 * ty + 1][4 * kk4];
#pragma unroll
            for (int j = 0; j < 5; ++j) {
                float4 wv = *(const float4*)&Ws[tx + 8 * j][4 * kk4];
                acc[0][j] = fmaf(xa.x, wv.x, acc[0][j]);
                acc[0][j] = fmaf(xa.y, wv.y, acc[0][j]);
                acc[0][j] = fmaf(xa.z, wv.z, acc[0][j]);
                acc[0][j] = fmaf(xa.w, wv.w, acc[0][j]);
                acc[1][j] = fmaf(xb.x, wv.x, acc[1][j]);
                acc[1][j] = fmaf(xb.y, wv.y, acc[1][j]);
                acc[1][j] = fmaf(xb.z, wv.z, acc[1][j]);
                acc[1][j] = fmaf(xb.w, wv.w, acc[1][j]);
            }
        }
    }
    float asv[5], adv[5];
#pragma unroll
    for (int j = 0; j < 5; ++j) {
        asv[j] = a_src[tx + 8 * j];
        adv[j] = a_dst[tx + 8 * j];
    }
#pragma unroll
    for (int i = 0; i < 2; ++i) {
        int r = r0 + 2 * ty + i;
        bool valid = r < N_NODES;
        if (valid) {
#pragma unroll
            for (int j = 0; j < 5; ++j)
                Hout[(size_t)r * 40 + tx + 8 * j] = f2h(acc[i][j]);
        }
        float ps = 0.f, pd = 0.f;
#pragma unroll
        for (int j = 0; j < 5; ++j) {
            ps = fmaf(acc[i][j], asv[j], ps);
            pd = fmaf(acc[i][j], adv[j], pd);
        }
#pragma unroll
        for (int off = 1; off < 8; off <<= 1) {
            ps += __shfl_xor(ps, off);
            pd += __shfl_xor(pd, off);
        }
        if (valid && tx == 0) {
            als[r] = ps;
            ald[r] = pd;
        }
    }
}

// ---------------- agg128: one wave per node; denom fused into gather loop ----------------
__global__ __launch_bounds__(256) void agg128_kernel(
    const int* __restrict__ row_ptr, const int* __restrict__ csr_src,
    const unsigned int* __restrict__ Ht, const float* __restrict__ als, const float* __restrict__ ald,
    const float* __restrict__ bias, float* __restrict__ out) {
    __shared__ float s_p[4][256];
    __shared__ int s_u[4][64];
    int v = (blockIdx.x * blockDim.x + threadIdx.x) >> 6;
    v = __builtin_amdgcn_readfirstlane(v);
    int lane = threadIdx.x & 63;
    int wslot = threadIdx.x >> 6;
    if (v >= N_NODES) return;
    int beg = row_ptr[v], end = row_ptr[v + 1];
    float4 ad4 = *(const float4*)(ald + (size_t)v * 4);
    const int g = lane >> 4;     // gather group: edge i+g
    const int li = lane & 15;    // owns feats 8li..8li+7, head li>>2
    const int hh = li >> 2;
    float tsum = 0.f;            // per-lane partial denominator for head hh
    float acc[8];
#pragma unroll
    for (int j = 0; j < 8; ++j) acc[j] = 0.f;

    for (int cbeg = beg; cbeg < end; cbeg += 64) {
        int cnt = min(64, end - cbeg);
        bool act = lane < cnt;
        int u = act ? csr_src[cbeg + lane] : 0;
        float p0, p1, p2, p3;
        if (act) {
            float4 s4 = *(const float4*)(als + (size_t)u * 4);
            p0 = __expf(lrelu(s4.x + ad4.x));
            p1 = __expf(lrelu(s4.y + ad4.y));
            p2 = __expf(lrelu(s4.z + ad4.z));
            p3 = __expf(lrelu(s4.w + ad4.w));
        } else {
            p0 = p1 = p2 = p3 = 0.f;
        }
        s_u[wslot][lane] = u;
        float4 pv = {p0, p1, p2, p3};
        *(float4*)&s_p[wslot][lane * 4] = pv;
        // 4-edge-parallel gather; denom accumulated in-loop (overlaps loads).
        // over-read beyond cnt is safe (p=0, u=0).
        for (int i = 0; i < cnt; i += 4) {
            int e = i + g;
            int uu = s_u[wslot][e];
            float p = s_p[wslot][e * 4 + hh];
            uint4 w4 = *(const uint4*)(Ht + (size_t)uu * 64 + li * 4);
            tsum += p;
            fma8(acc, w4, p);
        }
    }
    // combine gather groups: acc over {16,32}; tsum identical across the 4 li of a head,
    // distinct across g -> reduce over {16,32} only.
#pragma unroll
    for (int j = 0; j < 8; ++j) {
        acc[j] += __shfl_xor(acc[j], 16);
        acc[j] += __shfl_xor(acc[j], 32);
    }
    tsum += __shfl_xor(tsum, 16);
    tsum += __shfl_xor(tsum, 32);
    float inv = 1.f / (tsum + 1e-16f);
    if (g == 0) {
        float4 b0 = *(const float4*)(bias + 8 * li);
        float4 b1 = *(const float4*)(bias + 8 * li + 4);
        float4 o0 = {acc[0] * inv + b0.x, acc[1] * inv + b0.y, acc[2] * inv + b0.z, acc[3] * inv + b0.w};
        float4 o1 = {acc[4] * inv + b1.x, acc[5] * inv + b1.y, acc[6] * inv + b1.z, acc[7] * inv + b1.w};
        *(float4*)(out + (size_t)v * DHID + 8 * li) = o0;
        *(float4*)(out + (size_t)v * DHID + 8 * li + 4) = o1;
    }
}

// ---------------- agg40: one wave per node; denom fused into gather + log_softmax ----------------
__global__ __launch_bounds__(256) void agg40_kernel(
    const int* __restrict__ row_ptr, const int* __restrict__ csr_src,
    const unsigned int* __restrict__ HtU, const float* __restrict__ als, const float* __restrict__ ald,
    const float* __restrict__ bias, float* __restrict__ out) {
    __shared__ float s_p[4][64];
    __shared__ int s_u[4][64];
    int v = (blockIdx.x * blockDim.x + threadIdx.x) >> 6;
    v = __builtin_amdgcn_readfirstlane(v);
    int lane = threadIdx.x & 63;
    int wslot = threadIdx.x >> 6;
    if (v >= N_NODES) return;
    int beg = row_ptr[v], end = row_ptr[v + 1];
    float adv = ald[v];
    const int g = lane >> 5;
    const int li = lane & 31;
    const bool own = li < 20;
    float tsum = 0.f;
    float a0 = 0.f, a1 = 0.f;
    for (int cbeg = beg; cbeg < end; cbeg += 64) {
        int cnt = min(64, end - cbeg);
        bool act = lane < cnt;
        int u = act ? csr_src[cbeg + lane] : 0;
        float p = act ? __expf(lrelu(als[u] + adv)) : 0.f;
        s_u[wslot][lane] = u;
        s_p[wslot][lane] = p;
        for (int i = 0; i < cnt; i += 2) {
            int e2 = i + g;
            int uu = s_u[wslot][e2];
            float pp = s_p[wslot][e2];
            unsigned int w = own ? HtU[(size_t)uu * 20 + li] : 0u;
            union { unsigned int u; _Float16 h[2]; } cv;
            cv.u = w;
            tsum += pp;
            a0 = fmaf((float)cv.h[0], pp, a0);
            a1 = fmaf((float)cv.h[1], pp, a1);
        }
    }
    a0 += __shfl_xor(a0, 32);
    a1 += __shfl_xor(a1, 32);
    tsum += __shfl_xor(tsum, 32);   // pp identical across li; residues split by g only
    float inv = 1.f / (tsum + 1e-16f);
    float z0 = own ? (a0 * inv + bias[2 * li]) : -1e30f;
    float z1 = own ? (a1 * inv + bias[2 * li + 1]) : -1e30f;
    float zm = fmaxf(z0, z1);
#pragma unroll
    for (int off = 1; off < 32; off <<= 1) zm = fmaxf(zm, __shfl_xor(zm, off));
    float se = own ? (__expf(z0 - zm) + __expf(z1 - zm)) : 0.f;
#pragma unroll
    for (int off = 1; off < 32; off <<= 1) se += __shfl_xor(se, off);
    float ls = zm + logf(se);
    if (own && g == 0) {
        float2 o = {z0 - ls, z1 - ls};
        *(float2*)(out + (size_t)v * DOUT + 2 * li) = o;
    }
}

// ---------------- batch norm stats ----------------
__global__ __launch_bounds__(256) void bn_stats_kernel(const float* __restrict__ X,
                                                       float* __restrict__ sums, float* __restrict__ sqs) {
    int f = threadIdx.x & 127;
    int sub = threadIdx.x >> 7;
    int rbeg = blockIdx.x * 100;
    float s = 0.f, q = 0.f;
    for (int r = rbeg + sub; r < rbeg + 100; r += 2) {
        float x = X[(size_t)r * DHID + f];
        s += x;
        q += x * x;
    }
    __shared__ float ls[256], lq[256];
    ls[threadIdx.x] = s;
    lq[threadIdx.x] = q;
    __syncthreads();
    if (threadIdx.x < 128) {
        s = ls[threadIdx.x] + ls[threadIdx.x + 128];
        q = lq[threadIdx.x] + lq[threadIdx.x + 128];
        atomicAdd(&sums[f], s);
        atomicAdd(&sqs[f], q);
    }
}

__global__ void bn_finalize_kernel(const float* __restrict__ sums, const float* __restrict__ sqs,
                                   const float* __restrict__ gamma, const float* __restrict__ beta,
                                   float* __restrict__ scale, float* __restrict__ shift) {
    int f = threadIdx.x;
    if (f < DHID) {
        float mu = sums[f] * (1.f / N_NODES);
        float var = sqs[f] * (1.f / N_NODES) - mu * mu;
        float sc = gamma[f] * rsqrtf(var + 1e-5f);
        scale[f] = sc;
        shift[f] = beta[f] - mu * sc;
    }
}

// ---------------- launch ----------------
extern "C" void kernel_launch(void* const* d_in, const int* in_sizes, int n_in,
                              void* d_out, int out_size, void* d_ws, size_t ws_size,
                              hipStream_t stream) {
    (void)in_sizes; (void)n_in; (void)out_size; (void)ws_size;
    const float* x = (const float*)d_in[0];
    const int* ei = (const int*)d_in[1];
    const float* W0 = (const float*)d_in[2];
    const float* as0 = (const float*)d_in[3];
    const float* ad0 = (const float*)d_in[4];
    const float* b0 = (const float*)d_in[5];
    const float* W1 = (const float*)d_in[6];
    const float* as1 = (const float*)d_in[7];
    const float* ad1 = (const float*)d_in[8];
    const float* b1 = (const float*)d_in[9];
    const float* W2 = (const float*)d_in[10];
    const float* as2 = (const float*)d_in[11];
    const float* ad2 = (const float*)d_in[12];
    const float* b2 = (const float*)d_in[13];
    const float* g_bn0 = (const float*)d_in[14];
    const float* be_bn0 = (const float*)d_in[15];
    const float* g_bn1 = (const float*)d_in[16];
    const float* be_bn1 = (const float*)d_in[17];
    float* out = (float*)d_out;

    const int* srcv = ei;
    const int* dstv = ei + N_EDGES;

    char* p = (char*)d_ws;
    auto carve = [&](size_t bytes) {
        char* q = p;
        p += (bytes + 255) & ~(size_t)255;
        return q;
    };
    unsigned int* h_bf = (unsigned int*)carve((size_t)N_NODES * 64 * 4);  // f16 h (also as [N,40] ushort rows)
    float* agg   = (float*)carve((size_t)N_NODES * DHID * 4);
    float* als   = (float*)carve((size_t)N_NODES * NH * 4);
    float* ald   = (float*)carve((size_t)N_NODES * NH * 4);
    int* row_ptr = (int*)carve((size_t)(N_NODES + 1) * 4);
    int* csr_src = (int*)carve((size_t)N_EDGES * 4);
    uint2* part  = (uint2*)carve((size_t)N_EDGES * 8);
    int* bhist   = (int*)carve(PB * 4);
    int* bucket_base = (int*)carve((PB + 1) * 4);
    int* cursor  = (int*)carve(PB * 4);
    float* sums  = (float*)carve(256 * 4);
    float* sqs   = sums + 128;
    float* scale = (float*)carve(DHID * 4);
    float* shift = (float*)carve(DHID * 4);

    const float bs0 = 1.0f + 1.0f / 25.001f;
    const float bs1 = 1.0f + 0.5f / 25.001f;

    const int RT64 = (N_NODES + 63) / 64;      // 782
    const int G128B = RT64 * 2;                // 1564
    const int G40B = RT64;                     // 782
    const int AB = (N_NODES * 64 + 255) / 256; // 12500
    const int PARTB = (N_EDGES + 4095) / 4096; // 196

    // ---- bucketed CSR build ----
    hipMemsetAsync(bhist, 0, PB * 4, stream);
    bucket_hist_kernel<<<400, 256, 0, stream>>>(dstv, bhist);
    bucket_scan_kernel<<<1, PB, 0, stream>>>(bhist, bucket_base, cursor);
    partition_kernel<<<PARTB, 256, 0, stream>>>(srcv, dstv, cursor, part);
    bucket_csr_kernel<<<PB, 256, 0, stream>>>(part, bucket_base, row_ptr, csr_src);

    // ---- layer 0 ----
    gemm128_kernel<<<G128B, 256, 0, stream>>>(x, W0, as0, ad0, nullptr, nullptr, 1.f, 0, h_bf, als, ald);
    agg128_kernel<<<AB, 256, 0, stream>>>(row_ptr, csr_src, h_bf, als, ald, b0, agg);
    hipMemsetAsync(sums, 0, 256 * 4, stream);
    bn_stats_kernel<<<500, 256, 0, stream>>>(agg, sums, sqs);
    bn_finalize_kernel<<<1, 128, 0, stream>>>(sums, sqs, g_bn0, be_bn0, scale, shift);

    // ---- layer 1 (BN0+ELU fused into gemm staging) ----
    gemm128_kernel<<<G128B, 256, 0, stream>>>(agg, W1, as1, ad1, scale, shift, bs0, 1, h_bf, als, ald);
    agg128_kernel<<<AB, 256, 0, stream>>>(row_ptr, csr_src, h_bf, als, ald, b1, agg);
    hipMemsetAsync(sums, 0, 256 * 4, stream);
    bn_stats_kernel<<<500, 256, 0, stream>>>(agg, sums, sqs);
    bn_finalize_kernel<<<1, 128, 0, stream>>>(sums, sqs, g_bn1, be_bn1, scale, shift);

    // ---- layer 2 (BN1+ELU fused) + log_softmax ----
    gemm40_kernel<<<G40B, 256, 0, stream>>>(agg, W2, as2, ad2, scale, shift, bs1, (unsigned short*)h_bf, als, ald);
    agg40_kernel<<<AB, 256, 0, stream>>>(row_ptr, csr_src, h_bf, als, ald, b2, out);
}